// Round 1
// baseline (1856.913 us; speedup 1.0000x reference)
//
#include <hip/hip_runtime.h>

#define LRELU(v) ((v) > 0.f ? (v) : 0.2f * (v))

constexpr int TM = 64;
constexpr int KC = 64;

// C[n,o] = act( (sum_k Aval(n,k) * W[o*K+k]) + bias[o] )
// Aval(n,k) = (k<K1 ? A1[n*ldA1+k] : A2[n*ldA2+k-K1]) + (HAS_STATES ? states[n]*a0 : 0)
template<int FOUT, int ACT, bool HAS_BIAS, bool HAS_STATES>
__global__ __launch_bounds__(256) void gemm_kernel(
    const float* __restrict__ A1, int ldA1,
    const float* __restrict__ A2, int ldA2, int K1,
    const float* __restrict__ W,
    const float* __restrict__ bias,
    const float* __restrict__ states, const float* __restrict__ a0p,
    float* __restrict__ C, int N, int K)
{
  constexpr int RN = FOUT / 16;                 // 8 (FOUT=128) or 12 (FOUT=192)
  __shared__ __align__(16) float As[KC][TM];    // As[k][m]
  __shared__ __align__(16) float Ws[KC][FOUT + 4]; // Ws[k][o]
  const int tid = threadIdx.x;
  const int tx = tid & 15;
  const int ty = tid >> 4;
  const int m0 = blockIdx.x * TM;
  const float a0 = HAS_STATES ? a0p[0] : 0.f;

  float acc[4][RN];
#pragma unroll
  for (int i = 0; i < 4; i++)
#pragma unroll
    for (int j = 0; j < RN; j++) acc[i][j] = 0.f;

  for (int kk = 0; kk < K; kk += KC) {
    const float* Ap; int ldA, koff;
    if (kk < K1) { Ap = A1; ldA = ldA1; koff = kk; }
    else         { Ap = A2; ldA = ldA2; koff = kk - K1; }
    // stage A chunk (64 rows x 64 k), transposed into LDS
#pragma unroll
    for (int j = 0; j < 4; ++j) {
      int i4 = tid + j * 256;
      int m  = i4 >> 4;
      int k4 = (i4 & 15) << 2;
      int n  = m0 + m;
      float4 v = make_float4(0.f, 0.f, 0.f, 0.f);
      if (n < N) {
        v = *(const float4*)(Ap + (size_t)n * ldA + koff + k4);
        if (HAS_STATES) {
          float sa = states[n] * a0;
          v.x += sa; v.y += sa; v.z += sa; v.w += sa;
        }
      }
      As[k4 + 0][m] = v.x; As[k4 + 1][m] = v.y;
      As[k4 + 2][m] = v.z; As[k4 + 3][m] = v.w;
    }
    // stage W chunk (FOUT x 64 k), transposed into LDS
#pragma unroll
    for (int j = 0; j < (16 * FOUT) / 256; ++j) {
      int i4 = tid + j * 256;
      int o  = i4 >> 4;
      int k4 = (i4 & 15) << 2;
      float4 v = *(const float4*)(W + (size_t)o * K + kk + k4);
      Ws[k4 + 0][o] = v.x; Ws[k4 + 1][o] = v.y;
      Ws[k4 + 2][o] = v.z; Ws[k4 + 3][o] = v.w;
    }
    __syncthreads();
#pragma unroll 4
    for (int k = 0; k < KC; ++k) {
      float4 a = *(const float4*)&As[k][ty << 2];
      float wv[RN];
#pragma unroll
      for (int j4 = 0; j4 < RN / 4; ++j4) {
        float4 t4 = *((const float4*)&Ws[k][tx * RN] + j4);
        wv[j4 * 4 + 0] = t4.x; wv[j4 * 4 + 1] = t4.y;
        wv[j4 * 4 + 2] = t4.z; wv[j4 * 4 + 3] = t4.w;
      }
#pragma unroll
      for (int j = 0; j < RN; ++j) {
        acc[0][j] += a.x * wv[j];
        acc[1][j] += a.y * wv[j];
        acc[2][j] += a.z * wv[j];
        acc[3][j] += a.w * wv[j];
      }
    }
    __syncthreads();
  }
#pragma unroll
  for (int i = 0; i < 4; ++i) {
    int n = m0 + (ty << 2) + i;
    if (n >= N) continue;
#pragma unroll
    for (int j = 0; j < RN; ++j) {
      int o = tx * RN + j;
      float v = acc[i][j];
      if (HAS_BIAS) v += bias[o];
      if (ACT) v = LRELU(v);
      C[(size_t)n * FOUT + o] = v;
    }
  }
}

// split x into x1/x2, zero accumulators
__global__ void init_kernel(const float* __restrict__ x,
                            float* __restrict__ x1, float* __restrict__ x2,
                            float* __restrict__ x1s, float* __restrict__ x2s, int n)
{
  int idx = blockIdx.x * blockDim.x + threadIdx.x;
  int total = n * 32;  // float4 per half-row
  for (; idx < total; idx += gridDim.x * blockDim.x) {
    int r = idx >> 5, c = idx & 31;
    float4 v1 = ((const float4*)(x + (size_t)r * 256))[c];
    float4 v2 = ((const float4*)(x + (size_t)r * 256 + 128))[c];
    ((float4*)(x1 + (size_t)r * 128))[c] = v1;
    ((float4*)(x2 + (size_t)r * 128))[c] = v2;
    float4 z = make_float4(0.f, 0.f, 0.f, 0.f);
    ((float4*)(x1s + (size_t)r * 128))[c] = z;
    ((float4*)(x2s + (size_t)r * 128))[c] = z;
  }
}

__global__ void hist_kernel(const int* __restrict__ s0, const int* __restrict__ s1,
                            int* __restrict__ cnt0, int* __restrict__ cnt1, int E_)
{
  int e = blockIdx.x * blockDim.x + threadIdx.x;
  if (e >= E_) return;
  atomicAdd(&cnt0[s0[e]], 1);
  atomicAdd(&cnt1[s1[e]], 1);
}

__global__ void scan_kernel(const int* __restrict__ cnt, int* __restrict__ rowstart, int n)
{
  __shared__ int sdata[1024];
  __shared__ int carry;
  int tid = threadIdx.x;
  if (tid == 0) carry = 0;
  __syncthreads();
  for (int base = 0; base < n; base += 1024) {
    int i = base + tid;
    int v = (i < n) ? cnt[i] : 0;
    sdata[tid] = v;
    __syncthreads();
    for (int off = 1; off < 1024; off <<= 1) {
      int t = (tid >= off) ? sdata[tid - off] : 0;
      __syncthreads();
      sdata[tid] += t;
      __syncthreads();
    }
    int incl = sdata[tid];
    if (i < n) rowstart[i] = carry + incl - v;  // exclusive scan
    __syncthreads();
    if (tid == 1023) carry += incl;
    __syncthreads();
  }
  if (tid == 0) rowstart[n] = carry;
}

// fill CSR slots with (other endpoint, weight) pairs
__global__ void fill_kernel(const int* __restrict__ s0, const int* __restrict__ s1,
                            const float* __restrict__ ew,
                            const int* __restrict__ row0, const int* __restrict__ row1,
                            int* __restrict__ cur0, int* __restrict__ cur1,
                            int* __restrict__ other0, float* __restrict__ w0,
                            int* __restrict__ other1, float* __restrict__ w1, int E_)
{
  int e = blockIdx.x * blockDim.x + threadIdx.x;
  if (e >= E_) return;
  int d0 = s0[e], d1 = s1[e];
  float w = ew[e];
  int p0 = row0[d0] + atomicAdd(&cur0[d0], 1);
  other0[p0] = d1; w0[p0] = w;
  int p1 = row1[d1] + atomicAdd(&cur1[d1], 1);
  other1[p1] = d0; w1[p1] = w;
}

// per-node gather-reduce (replaces segment_sum); fused lrelu + running accumulation
__global__ void gather_kernel(const int* __restrict__ rowstart,
                              const int* __restrict__ other,
                              const float* __restrict__ wcs,
                              const float* __restrict__ h,
                              float* __restrict__ xout, float* __restrict__ xsum, int n)
{
  int wave = blockIdx.x * (blockDim.x >> 6) + (threadIdx.x >> 6);
  int lane = threadIdx.x & 63;
  if (wave >= n) return;
  int beg = rowstart[wave], end = rowstart[wave + 1];
  float acc0 = 0.f, acc1 = 0.f;
  for (int p = beg; p < end; ++p) {
    float w = wcs[p];
    int s = other[p];
    const float* hr = h + (size_t)s * 128;
    acc0 += w * hr[lane];
    acc1 += w * hr[lane + 64];
  }
  float v0 = LRELU(acc0);
  float v1 = LRELU(acc1);
  size_t o = (size_t)wave * 128;
  xout[o + lane] = v0;       xout[o + 64 + lane] = v1;
  xsum[o + lane] += v0;      xsum[o + 64 + lane] += v1;
}

// per-graph segment sums of xc (batch is sorted)
__global__ void segsum_kernel(const float* __restrict__ xc, const int* __restrict__ batch,
                              const float* __restrict__ states,
                              float* __restrict__ gsel, float* __restrict__ gsum, int n)
{
  int f = threadIdx.x;  // 128 threads
  int r0 = blockIdx.x * 256;
  int r1 = min(r0 + 256, n);
  float asel = 0.f, asum = 0.f;
  int cur = batch[r0];
  for (int r = r0; r < r1; ++r) {
    int b = batch[r];
    if (b != cur) {
      atomicAdd(&gsel[cur * 128 + f], asel);
      atomicAdd(&gsum[cur * 128 + f], asum);
      asel = asum = 0.f;
      cur = b;
    }
    float v = xc[(size_t)r * 128 + f];
    asum += v;
    if (states[r] == 1.0f) asel += v;
  }
  atomicAdd(&gsel[cur * 128 + f], asel);
  atomicAdd(&gsum[cur * 128 + f], asum);
}

// hcat[n] = [wbuf[n] (128), A16[batch[n]] (128), B16[batch[n]] (128)]
__global__ void hcat_kernel(const float* __restrict__ wbuf, const float* __restrict__ A16,
                            const float* __restrict__ B16, const int* __restrict__ batch,
                            float* __restrict__ hcat, int n)
{
  int idx = blockIdx.x * blockDim.x + threadIdx.x;
  int total = n * 96;
  for (; idx < total; idx += gridDim.x * blockDim.x) {
    int r = idx / 96, c4 = idx % 96;
    float4 v;
    if (c4 < 32) {
      v = ((const float4*)(wbuf + (size_t)r * 128))[c4];
    } else {
      int b = batch[r];
      if (c4 < 64) v = ((const float4*)(A16 + (size_t)b * 128))[c4 - 32];
      else         v = ((const float4*)(B16 + (size_t)b * 128))[c4 - 64];
    }
    ((float4*)(hcat + (size_t)r * 384))[c4] = v;
  }
}

// out[n] = z[n] . g4W + g4b  (z already lrelu'd)
__global__ void final_kernel(const float* __restrict__ z, const float* __restrict__ g4W,
                             const float* __restrict__ g4b, float* __restrict__ out, int n)
{
  int wave = blockIdx.x * (blockDim.x >> 6) + (threadIdx.x >> 6);
  int lane = threadIdx.x & 63;
  if (wave >= n) return;
  const float* zr = z + (size_t)wave * 192;
  float acc = zr[lane] * g4W[lane] + zr[lane + 64] * g4W[lane + 64]
            + zr[lane + 128] * g4W[lane + 128];
  for (int off = 32; off; off >>= 1) acc += __shfl_down(acc, off, 64);
  if (lane == 0) out[wave] = acc + g4b[0];
}

extern "C" void kernel_launch(void* const* d_in, const int* in_sizes, int n_in,
                              void* d_out, int out_size, void* d_ws, size_t ws_size,
                              hipStream_t stream)
{
  const int N = 50000, F = 128, E = 800000, G = 16, T = 3;
  const float* x      = (const float*)d_in[0];
  const int*   ei     = (const int*)d_in[1];
  const int*   s0     = ei;
  const int*   s1     = ei + E;
  const float* ew     = (const float*)d_in[2];
  const int*   batch  = (const int*)d_in[3];
  const float* states = (const float*)d_in[4];
  const float* p_a0[2]   = {(const float*)d_in[5],  (const float*)d_in[10]};
  const float* p_a1W[2]  = {(const float*)d_in[6],  (const float*)d_in[11]};
  const float* p_a1b[2]  = {(const float*)d_in[7],  (const float*)d_in[12]};
  const float* p_linW[2] = {(const float*)d_in[8],  (const float*)d_in[13]};
  const float* p_linb[2] = {(const float*)d_in[9],  (const float*)d_in[14]};
  const float* beta0W = (const float*)d_in[15];
  const float* beta1W = (const float*)d_in[16];
  const float* beta2W = (const float*)d_in[17];
  const float* beta2b = (const float*)d_in[18];
  const float* g0W = (const float*)d_in[19];
  const float* g1W = (const float*)d_in[20];
  const float* g2W = (const float*)d_in[21];
  const float* g3W = (const float*)d_in[22];
  const float* g4W = (const float*)d_in[23];
  const float* g4b = (const float*)d_in[24];
  float* out = (float*)d_out;

  char* p = (char*)d_ws;
  auto alloc = [&](size_t bytes) {
    char* r = p;
    p += (bytes + 255) & ~(size_t)255;
    return r;
  };
  const size_t NFb = (size_t)N * F * sizeof(float);  // 25.6 MB, multiple of 256
  float* buf0 = (float*)alloc(NFb);  // x1 -> xc -> z (with buf1)
  float* buf1 = (float*)alloc(NFb);  // x2 -> wbuf
  float* buf2 = (float*)alloc(NFb);  // x1s -> hcat (with buf3,buf4)
  float* buf3 = (float*)alloc(NFb);  // x2s
  float* buf4 = (float*)alloc(NFb);  // tmp / u
  float* buf5 = (float*)alloc(NFb);  // h / v
  int*   row0 = (int*)alloc((size_t)(N + 1) * 4);
  int*   row1 = (int*)alloc((size_t)(N + 1) * 4);
  int*   cnt0 = (int*)alloc((size_t)N * 4);
  int*   cnt1 = (int*)alloc((size_t)N * 4);
  int*   other0 = (int*)alloc((size_t)E * 4);
  float* w0c    = (float*)alloc((size_t)E * 4);
  int*   other1 = (int*)alloc((size_t)E * 4);
  float* w1c    = (float*)alloc((size_t)E * 4);
  float* gsel = (float*)alloc((size_t)G * F * 4);
  float* gsum = (float*)alloc((size_t)G * F * 4);
  float* A16  = (float*)alloc((size_t)G * F * 4);
  float* B16  = (float*)alloc((size_t)G * F * 4);
  float* hcat = buf2;  // N x 384 overlays buf2..buf4 (dead by then)
  float* zbuf = buf0;  // N x 192 overlays buf0..buf1 (dead by then)

  const dim3 blk256(256);
  const dim3 gemm_grid((N + TM - 1) / TM);
  const dim3 edge_grid((E + 255) / 256);

  // ---- CSR build (per launch; deterministic work) ----
  hipMemsetAsync(cnt0, 0, (size_t)N * 4, stream);
  hipMemsetAsync(cnt1, 0, (size_t)N * 4, stream);
  hist_kernel<<<edge_grid, blk256, 0, stream>>>(s0, s1, cnt0, cnt1, E);
  scan_kernel<<<1, 1024, 0, stream>>>(cnt0, row0, N);
  scan_kernel<<<1, 1024, 0, stream>>>(cnt1, row1, N);
  hipMemsetAsync(cnt0, 0, (size_t)N * 4, stream);
  hipMemsetAsync(cnt1, 0, (size_t)N * 4, stream);
  fill_kernel<<<edge_grid, blk256, 0, stream>>>(s0, s1, ew, row0, row1, cnt0, cnt1,
                                                other0, w0c, other1, w1c, E);

  // ---- init x1/x2/x1s/x2s ----
  init_kernel<<<6250, blk256, 0, stream>>>(x, buf0, buf1, buf2, buf3, N);

  // ---- T-loop ----
  for (int t = 0; t < T; ++t) {
    // p1: src=s1, dst=s0  (CSR0)
    gemm_kernel<128, 1, true, true><<<gemm_grid, blk256, 0, stream>>>(
        buf0, 128, buf0, 128, 128, p_a1W[0] + (size_t)t * F * F, p_a1b[0] + t * F,
        states, p_a0[0] + t, buf4, N, 128);
    gemm_kernel<128, 0, true, false><<<gemm_grid, blk256, 0, stream>>>(
        buf4, 128, buf4, 128, 128, p_linW[0] + (size_t)t * F * F, p_linb[0] + t * F,
        nullptr, nullptr, buf5, N, 128);
    gather_kernel<<<(N + 3) / 4, blk256, 0, stream>>>(row0, other0, w0c, buf5, buf0, buf2, N);
    // p2: src=s0, dst=s1  (CSR1)
    gemm_kernel<128, 1, true, true><<<gemm_grid, blk256, 0, stream>>>(
        buf1, 128, buf1, 128, 128, p_a1W[1] + (size_t)t * F * F, p_a1b[1] + t * F,
        states, p_a0[1] + t, buf4, N, 128);
    gemm_kernel<128, 0, true, false><<<gemm_grid, blk256, 0, stream>>>(
        buf4, 128, buf4, 128, 128, p_linW[1] + (size_t)t * F * F, p_linb[1] + t * F,
        nullptr, nullptr, buf5, N, 128);
    gather_kernel<<<(N + 3) / 4, blk256, 0, stream>>>(row1, other1, w1c, buf5, buf1, buf3, N);
  }

  // ---- beta stage ----
  gemm_kernel<128, 0, false, false><<<gemm_grid, blk256, 0, stream>>>(
      buf2, 128, buf2, 128, 128, beta0W, nullptr, nullptr, nullptr, buf4, N, 128);  // u
  gemm_kernel<128, 0, false, false><<<gemm_grid, blk256, 0, stream>>>(
      buf3, 128, buf3, 128, 128, beta1W, nullptr, nullptr, nullptr, buf5, N, 128);  // v
  gemm_kernel<128, 1, true, false><<<gemm_grid, blk256, 0, stream>>>(
      buf4, 128, buf5, 128, 128, beta2W, beta2b, nullptr, nullptr, buf0, N, 256);   // xc

  // ---- per-graph sums + small GEMMs ----
  hipMemsetAsync(gsel, 0, (size_t)G * F * 4, stream);
  hipMemsetAsync(gsum, 0, (size_t)G * F * 4, stream);
  segsum_kernel<<<(N + 255) / 256, dim3(128), 0, stream>>>(buf0, batch, states, gsel, gsum, N);
  gemm_kernel<128, 0, false, false><<<dim3(1), blk256, 0, stream>>>(
      gsel, 128, gsel, 128, 128, g1W, nullptr, nullptr, nullptr, A16, G, 128);
  gemm_kernel<128, 0, false, false><<<dim3(1), blk256, 0, stream>>>(
      gsum, 128, gsum, 128, 128, g2W, nullptr, nullptr, nullptr, B16, G, 128);

  // ---- gamma stage ----
  gemm_kernel<128, 0, false, false><<<gemm_grid, blk256, 0, stream>>>(
      buf0, 128, buf0, 128, 128, g0W, nullptr, nullptr, nullptr, buf1, N, 128);     // wbuf
  hcat_kernel<<<18750, blk256, 0, stream>>>(buf1, A16, B16, batch, hcat, N);
  gemm_kernel<192, 1, false, false><<<gemm_grid, blk256, 0, stream>>>(
      hcat, 384, hcat, 384, 384, g3W, nullptr, nullptr, nullptr, zbuf, N, 384);     // z
  final_kernel<<<(N + 3) / 4, blk256, 0, stream>>>(zbuf, g4W, g4b, out, N);
}

// Round 2
// 1176.046 us; speedup vs baseline: 1.5789x; 1.5789x over previous
//
#include <hip/hip_runtime.h>

typedef short s8v __attribute__((ext_vector_type(8)));
typedef float f32x4 __attribute__((ext_vector_type(4)));

#define LRELU(v) ((v) > 0.f ? (v) : 0.2f * (v))

__device__ __forceinline__ float b2f(unsigned short b) {
  return __uint_as_float(((unsigned int)b) << 16);
}
__device__ __forceinline__ unsigned short f2b(float f) {
  unsigned int x = __float_as_uint(f);
  x += 0x7fffu + ((x >> 16) & 1u);
  return (unsigned short)(x >> 16);
}
__device__ __forceinline__ unsigned int pack2(float lo, float hi) {
  return ((unsigned int)f2b(hi) << 16) | (unsigned int)f2b(lo);
}

// ---------------- bf16 MFMA GEMM ----------------
// C[n,o] = act( A[n,:]@W[o,:] + bias[o] + states[n]*a0*rowsum[o] ), bf16 in/out
// A = concat(A1, A2) along k at K1. W row-major [FOUT][K] bf16.
template<int FOUT, int ACT, bool HAS_BIAS, bool HAS_STATES>
__global__ __launch_bounds__(256) void bgemm(
    const unsigned short* __restrict__ A1, int ldA1,
    const unsigned short* __restrict__ A2, int ldA2, int K1,
    const unsigned short* __restrict__ W,
    const float* __restrict__ bias,
    const float* __restrict__ states, const float* __restrict__ a0p,
    const float* __restrict__ rowsum,
    unsigned short* __restrict__ C, int N, int K)
{
  constexpr int NF = FOUT / 16;
  __shared__ __align__(16) unsigned short Ws[FOUT * 128];
  const int tid = threadIdx.x;
  const int lane = tid & 63;
  const int w = tid >> 6;
  const int l15 = lane & 15;
  const int g = lane >> 4;
  const int m0 = blockIdx.x * 128;

  f32x4 zero4 = {0.f, 0.f, 0.f, 0.f};
  f32x4 acc[2][NF];
#pragma unroll
  for (int mf = 0; mf < 2; ++mf)
#pragma unroll
    for (int nf = 0; nf < NF; ++nf) acc[mf][nf] = zero4;

  for (int kk = 0; kk < K; kk += 128) {
    // stage W chunk [FOUT][128] bf16 into LDS, 16B-chunk XOR swizzle
#pragma unroll
    for (int j = 0; j < NF; ++j) {
      int idx = tid + j * 256;
      int o = idx >> 4, c = idx & 15;
      uint4 v = *(const uint4*)(W + (size_t)o * K + kk + c * 8);
      *(uint4*)&Ws[o * 128 + (c ^ (o & 15)) * 8] = v;
    }
    // A fragments straight from global (row-coalesced at line granularity)
    const unsigned short* Ap; int ldA, koff;
    if (kk < K1) { Ap = A1; ldA = ldA1; koff = kk; }
    else         { Ap = A2; ldA = ldA2; koff = kk - K1; }
    s8v a[2][4];
#pragma unroll
    for (int mf = 0; mf < 2; ++mf) {
      int row = m0 + w * 32 + mf * 16 + l15;
      const unsigned short* ar = Ap + (size_t)row * ldA + koff + g * 8;
#pragma unroll
      for (int ks = 0; ks < 4; ++ks) {
        s8v t = {};
        if (row < N) t = *(const s8v*)(ar + ks * 32);
        a[mf][ks] = t;
      }
    }
    __syncthreads();
#pragma unroll
    for (int ks = 0; ks < 4; ++ks) {
#pragma unroll
      for (int nf = 0; nf < NF; ++nf) {
        int c = ks * 4 + g;
        s8v b = *(const s8v*)&Ws[(nf * 16 + l15) * 128 + (c ^ l15) * 8];
        acc[0][nf] = __builtin_amdgcn_mfma_f32_16x16x32_bf16(a[0][ks], b, acc[0][nf], 0, 0, 0);
        acc[1][nf] = __builtin_amdgcn_mfma_f32_16x16x32_bf16(a[1][ks], b, acc[1][nf], 0, 0, 0);
      }
    }
    if (kk + 128 < K) __syncthreads();
  }

  const float a0 = HAS_STATES ? a0p[0] : 0.f;
#pragma unroll
  for (int mf = 0; mf < 2; ++mf) {
#pragma unroll
    for (int r = 0; r < 4; ++r) {
      int row = m0 + w * 32 + mf * 16 + (lane >> 4) * 4 + r;
      if (row >= N) continue;
      float sa = HAS_STATES ? states[row] * a0 : 0.f;
      unsigned short* crow = C + (size_t)row * FOUT;
#pragma unroll
      for (int nf = 0; nf < NF; ++nf) {
        int col = nf * 16 + l15;
        float v = acc[mf][nf][r];
        if (HAS_BIAS) v += bias[col];
        if (HAS_STATES) v += sa * rowsum[col];
        if (ACT) v = LRELU(v);
        crow[col] = f2b(v);
      }
    }
  }
}

// ---------------- weight fp32 -> bf16 conversion ----------------
struct CJobs { const float* s[9]; unsigned short* d[9]; int n[9]; };
__global__ void convert_kernel(CJobs jb) {
  int j = blockIdx.y;
  int idx = (blockIdx.x * 256 + threadIdx.x) * 8;
  if (idx >= jb.n[j]) return;
  const float* s = jb.s[j] + idx;
  float4 p0 = *(const float4*)s;
  float4 p1 = *(const float4*)(s + 4);
  uint4 u;
  u.x = pack2(p0.x, p0.y); u.y = pack2(p0.z, p0.w);
  u.z = pack2(p1.x, p1.y); u.w = pack2(p1.z, p1.w);
  *(uint4*)(jb.d[j] + idx) = u;
}

// rowsums of the 6 a1W matrices (fp32, for the states*a0 epilogue trick)
__global__ void rowsum_kernel(const float* __restrict__ a1,
                              const float* __restrict__ a2, float* __restrict__ rs) {
  int j = blockIdx.x;  // p*3+t
  const float* src = (j < 3) ? (a1 + (size_t)j * 16384) : (a2 + (size_t)(j - 3) * 16384);
  int o = threadIdx.x;  // 128
  float s = 0.f;
  for (int k = 0; k < 128; ++k) s += src[o * 128 + k];
  rs[j * 128 + o] = s;
}

// split x into x1/x2 (bf16), zero accumulators
__global__ void init_kernel(const float* __restrict__ x,
                            unsigned short* __restrict__ x1, unsigned short* __restrict__ x2,
                            unsigned short* __restrict__ x1s, unsigned short* __restrict__ x2s,
                            int n)
{
  int idx = blockIdx.x * blockDim.x + threadIdx.x;
  int total = n * 16;
  for (; idx < total; idx += gridDim.x * blockDim.x) {
    int r = idx >> 4, c = idx & 15;
    const float* xr = x + (size_t)r * 256 + c * 8;
    float4 p0 = *(const float4*)xr;
    float4 p1 = *(const float4*)(xr + 4);
    uint4 u1;
    u1.x = pack2(p0.x, p0.y); u1.y = pack2(p0.z, p0.w);
    u1.z = pack2(p1.x, p1.y); u1.w = pack2(p1.z, p1.w);
    float4 q0 = *(const float4*)(xr + 128);
    float4 q1 = *(const float4*)(xr + 132);
    uint4 u2;
    u2.x = pack2(q0.x, q0.y); u2.y = pack2(q0.z, q0.w);
    u2.z = pack2(q1.x, q1.y); u2.w = pack2(q1.z, q1.w);
    ((uint4*)(x1 + (size_t)r * 128))[c] = u1;
    ((uint4*)(x2 + (size_t)r * 128))[c] = u2;
    uint4 z = make_uint4(0, 0, 0, 0);
    ((uint4*)(x1s + (size_t)r * 128))[c] = z;
    ((uint4*)(x2s + (size_t)r * 128))[c] = z;
  }
}

__global__ void hist_kernel(const int* __restrict__ s0, const int* __restrict__ s1,
                            int* __restrict__ cnt0, int* __restrict__ cnt1, int E_)
{
  int e = blockIdx.x * blockDim.x + threadIdx.x;
  if (e >= E_) return;
  atomicAdd(&cnt0[s0[e]], 1);
  atomicAdd(&cnt1[s1[e]], 1);
}

__global__ void scan_kernel(const int* __restrict__ cnt, int* __restrict__ rowstart, int n)
{
  __shared__ int sdata[1024];
  __shared__ int carry;
  int tid = threadIdx.x;
  if (tid == 0) carry = 0;
  __syncthreads();
  for (int base = 0; base < n; base += 1024) {
    int i = base + tid;
    int v = (i < n) ? cnt[i] : 0;
    sdata[tid] = v;
    __syncthreads();
    for (int off = 1; off < 1024; off <<= 1) {
      int t = (tid >= off) ? sdata[tid - off] : 0;
      __syncthreads();
      sdata[tid] += t;
      __syncthreads();
    }
    int incl = sdata[tid];
    if (i < n) rowstart[i] = carry + incl - v;
    __syncthreads();
    if (tid == 1023) carry += incl;
    __syncthreads();
  }
  if (tid == 0) rowstart[n] = carry;
}

__global__ void fill_kernel(const int* __restrict__ s0, const int* __restrict__ s1,
                            const float* __restrict__ ew,
                            const int* __restrict__ row0, const int* __restrict__ row1,
                            int* __restrict__ cur0, int* __restrict__ cur1,
                            int* __restrict__ other0, float* __restrict__ w0,
                            int* __restrict__ other1, float* __restrict__ w1, int E_)
{
  int e = blockIdx.x * blockDim.x + threadIdx.x;
  if (e >= E_) return;
  int d0 = s0[e], d1 = s1[e];
  float w = ew[e];
  int p0 = row0[d0] + atomicAdd(&cur0[d0], 1);
  other0[p0] = d1; w0[p0] = w;
  int p1 = row1[d1] + atomicAdd(&cur1[d1], 1);
  other1[p1] = d0; w1[p1] = w;
}

// per-node gather-reduce over bf16 h rows; fused lrelu + bf16 running sum
__global__ void gather_kernel(const int* __restrict__ rowstart,
                              const int* __restrict__ other,
                              const float* __restrict__ wcs,
                              const unsigned short* __restrict__ h,
                              unsigned short* __restrict__ xout,
                              unsigned short* __restrict__ xsum, int n)
{
  int node = blockIdx.x * (blockDim.x >> 6) + (threadIdx.x >> 6);
  int lane = threadIdx.x & 63;
  if (node >= n) return;
  int beg = rowstart[node], end = rowstart[node + 1];
  float a0 = 0.f, a1 = 0.f;
  for (int p = beg; p < end; ++p) {
    float wv = wcs[p];
    const unsigned int* hr = (const unsigned int*)(h + (size_t)other[p] * 128);
    unsigned int u = hr[lane];
    a0 += wv * b2f((unsigned short)u);
    a1 += wv * b2f((unsigned short)(u >> 16));
  }
  float v0 = LRELU(a0), v1 = LRELU(a1);
  unsigned int* xo = (unsigned int*)(xout + (size_t)node * 128);
  unsigned int* xs = (unsigned int*)(xsum + (size_t)node * 128);
  xo[lane] = pack2(v0, v1);
  unsigned int s = xs[lane];
  xs[lane] = pack2(b2f((unsigned short)s) + v0, b2f((unsigned short)(s >> 16)) + v1);
}

// per-graph segment sums of xc (bf16 in, fp32 out; batch sorted)
__global__ void segsum_kernel(const unsigned short* __restrict__ xc,
                              const int* __restrict__ batch,
                              const float* __restrict__ states,
                              float* __restrict__ gsel, float* __restrict__ gsum, int n)
{
  int f = threadIdx.x;  // 128
  int r0 = blockIdx.x * 256;
  int r1 = min(r0 + 256, n);
  float asel = 0.f, asum = 0.f;
  int cur = batch[r0];
  for (int r = r0; r < r1; ++r) {
    int b = batch[r];
    if (b != cur) {
      atomicAdd(&gsel[cur * 128 + f], asel);
      atomicAdd(&gsum[cur * 128 + f], asum);
      asel = asum = 0.f;
      cur = b;
    }
    float v = b2f(xc[(size_t)r * 128 + f]);
    asum += v;
    if (states[r] == 1.0f) asel += v;
  }
  atomicAdd(&gsel[cur * 128 + f], asel);
  atomicAdd(&gsum[cur * 128 + f], asum);
}

// A16 = gsel @ g1W^T, B16 = gsum @ g2W^T  (16x128, fp32 math, bf16 out)
__global__ void small16_kernel(const float* __restrict__ gsel, const float* __restrict__ gsum,
                               const float* __restrict__ g1W, const float* __restrict__ g2W,
                               unsigned short* __restrict__ A16, unsigned short* __restrict__ B16)
{
  int r = blockIdx.x, t = threadIdx.x, o = t & 127;
  const float* src = (t < 128) ? gsel : gsum;
  const float* Wm  = (t < 128) ? g1W : g2W;
  float acc = 0.f;
  for (int k = 0; k < 128; ++k) acc += src[r * 128 + k] * Wm[o * 128 + k];
  unsigned short* dst = (t < 128) ? A16 : B16;
  dst[r * 128 + o] = f2b(acc);
}

// hcat[n] = [wbuf[n], A16[batch[n]], B16[batch[n]]]  (bf16)
__global__ void hcat_kernel(const unsigned short* __restrict__ wbuf,
                            const unsigned short* __restrict__ A16,
                            const unsigned short* __restrict__ B16,
                            const int* __restrict__ batch,
                            unsigned short* __restrict__ hc, int n)
{
  int idx = blockIdx.x * blockDim.x + threadIdx.x;
  int total = n * 48;
  for (; idx < total; idx += gridDim.x * blockDim.x) {
    int r = idx / 48, c = idx % 48;
    uint4 v;
    if (c < 16) {
      v = ((const uint4*)(wbuf + (size_t)r * 128))[c];
    } else {
      int b = batch[r];
      if (c < 32) v = ((const uint4*)(A16 + (size_t)b * 128))[c - 16];
      else        v = ((const uint4*)(B16 + (size_t)b * 128))[c - 32];
    }
    ((uint4*)(hc + (size_t)r * 384))[c] = v;
  }
}

// out[n] = z[n] . g4W + g4b  (z bf16 192-wide, already lrelu'd)
__global__ void final_kernel(const unsigned short* __restrict__ z,
                             const float* __restrict__ g4W, const float* __restrict__ g4b,
                             float* __restrict__ out, int n)
{
  int node = blockIdx.x * (blockDim.x >> 6) + (threadIdx.x >> 6);
  int lane = threadIdx.x & 63;
  if (node >= n) return;
  const unsigned short* zr = z + (size_t)node * 192;
  float acc = b2f(zr[lane]) * g4W[lane]
            + b2f(zr[lane + 64]) * g4W[lane + 64]
            + b2f(zr[lane + 128]) * g4W[lane + 128];
  for (int off = 32; off; off >>= 1) acc += __shfl_down(acc, off, 64);
  if (lane == 0) out[node] = acc + g4b[0];
}

extern "C" void kernel_launch(void* const* d_in, const int* in_sizes, int n_in,
                              void* d_out, int out_size, void* d_ws, size_t ws_size,
                              hipStream_t stream)
{
  const int N = 50000, F = 128, E = 800000, G = 16, T = 3;
  const float* x      = (const float*)d_in[0];
  const int*   ei     = (const int*)d_in[1];
  const int*   s0     = ei;
  const int*   s1     = ei + E;
  const float* ew     = (const float*)d_in[2];
  const int*   batch  = (const int*)d_in[3];
  const float* states = (const float*)d_in[4];
  const float* p_a0[2]   = {(const float*)d_in[5],  (const float*)d_in[10]};
  const float* p_a1W[2]  = {(const float*)d_in[6],  (const float*)d_in[11]};
  const float* p_a1b[2]  = {(const float*)d_in[7],  (const float*)d_in[12]};
  const float* p_linW[2] = {(const float*)d_in[8],  (const float*)d_in[13]};
  const float* p_linb[2] = {(const float*)d_in[9],  (const float*)d_in[14]};
  const float* beta0W = (const float*)d_in[15];
  const float* beta1W = (const float*)d_in[16];
  const float* beta2W = (const float*)d_in[17];
  const float* beta2b = (const float*)d_in[18];
  const float* g0W = (const float*)d_in[19];
  const float* g1W = (const float*)d_in[20];
  const float* g2W = (const float*)d_in[21];
  const float* g3W = (const float*)d_in[22];
  const float* g4W = (const float*)d_in[23];
  const float* g4b = (const float*)d_in[24];
  float* out = (float*)d_out;

  char* p = (char*)d_ws;
  auto alloc = [&](size_t bytes) {
    char* r = p;
    p += (bytes + 255) & ~(size_t)255;
    return r;
  };
  const size_t NFb2 = (size_t)N * F * sizeof(unsigned short);  // 12.8 MB
  unsigned short* B0 = (unsigned short*)alloc(NFb2);  // x1 -> xc
  unsigned short* B1 = (unsigned short*)alloc(NFb2);  // x2 -> wbuf
  unsigned short* B2 = (unsigned short*)alloc(NFb2);  // x1s -> hcat (B2..B4)
  unsigned short* B3 = (unsigned short*)alloc(NFb2);  // x2s
  unsigned short* B4 = (unsigned short*)alloc(NFb2);  // tmp -> u
  unsigned short* B5 = (unsigned short*)alloc(NFb2);  // h -> v -> z (z spills into CSR area)
  int*   row0 = (int*)alloc((size_t)(N + 1) * 4);
  int*   row1 = (int*)alloc((size_t)(N + 1) * 4);
  int*   cnt0 = (int*)alloc((size_t)N * 4);
  int*   cnt1 = (int*)alloc((size_t)N * 4);
  int*   other0 = (int*)alloc((size_t)E * 4);
  float* w0c    = (float*)alloc((size_t)E * 4);
  int*   other1 = (int*)alloc((size_t)E * 4);
  float* w1c    = (float*)alloc((size_t)E * 4);
  float* gsel = (float*)alloc((size_t)G * F * 4);
  float* gsum = (float*)alloc((size_t)G * F * 4);
  unsigned short* A16b = (unsigned short*)alloc((size_t)G * F * 2);
  unsigned short* B16b = (unsigned short*)alloc((size_t)G * F * 2);
  unsigned short* wreg = (unsigned short*)alloc((size_t)352256 * 2);
  float* rs = (float*)alloc((size_t)6 * 128 * 4);

  // bf16 weight region offsets (ushorts)
  unsigned short* a1Wb[2]  = {wreg + 0,      wreg + 49152};
  unsigned short* linWb[2] = {wreg + 98304,  wreg + 147456};
  unsigned short* b0b = wreg + 196608;
  unsigned short* b1b = wreg + 212992;
  unsigned short* b2b = wreg + 229376;
  unsigned short* g0b = wreg + 262144;
  unsigned short* g3b = wreg + 278528;

  unsigned short* hc = B2;              // N x 384 over B2..B4
  unsigned short* zb = B5;              // N x 192 over B5 + CSR area (dead by then)

  const dim3 blk256(256);
  const dim3 gemm_grid((N + 127) / 128);
  const dim3 edge_grid((E + 255) / 256);
  const int KBIG = 1 << 30;

  // ---- CSR build ----
  hipMemsetAsync(cnt0, 0, (size_t)N * 4, stream);
  hipMemsetAsync(cnt1, 0, (size_t)N * 4, stream);
  hist_kernel<<<edge_grid, blk256, 0, stream>>>(s0, s1, cnt0, cnt1, E);
  scan_kernel<<<1, 1024, 0, stream>>>(cnt0, row0, N);
  scan_kernel<<<1, 1024, 0, stream>>>(cnt1, row1, N);
  hipMemsetAsync(cnt0, 0, (size_t)N * 4, stream);
  hipMemsetAsync(cnt1, 0, (size_t)N * 4, stream);
  fill_kernel<<<edge_grid, blk256, 0, stream>>>(s0, s1, ew, row0, row1, cnt0, cnt1,
                                                other0, w0c, other1, w1c, E);

  // ---- weight conversion + rowsums ----
  CJobs jb;
  jb.s[0] = p_a1W[0];  jb.d[0] = a1Wb[0];  jb.n[0] = 49152;
  jb.s[1] = p_a1W[1];  jb.d[1] = a1Wb[1];  jb.n[1] = 49152;
  jb.s[2] = p_linW[0]; jb.d[2] = linWb[0]; jb.n[2] = 49152;
  jb.s[3] = p_linW[1]; jb.d[3] = linWb[1]; jb.n[3] = 49152;
  jb.s[4] = beta0W;    jb.d[4] = b0b;      jb.n[4] = 16384;
  jb.s[5] = beta1W;    jb.d[5] = b1b;      jb.n[5] = 16384;
  jb.s[6] = beta2W;    jb.d[6] = b2b;      jb.n[6] = 32768;
  jb.s[7] = g0W;       jb.d[7] = g0b;      jb.n[7] = 16384;
  jb.s[8] = g3W;       jb.d[8] = g3b;      jb.n[8] = 73728;
  convert_kernel<<<dim3(36, 9), blk256, 0, stream>>>(jb);
  rowsum_kernel<<<6, 128, 0, stream>>>(p_a1W[0], p_a1W[1], rs);

  // ---- init ----
  init_kernel<<<3125, blk256, 0, stream>>>(x, B0, B1, B2, B3, N);

  // ---- T-loop ----
  for (int t = 0; t < T; ++t) {
    bgemm<128, 1, true, true><<<gemm_grid, blk256, 0, stream>>>(
        B0, 128, B0, 128, KBIG, a1Wb[0] + t * 16384, p_a1b[0] + t * F,
        states, p_a0[0] + t, rs + (0 * 3 + t) * 128, B4, N, 128);
    bgemm<128, 0, true, false><<<gemm_grid, blk256, 0, stream>>>(
        B4, 128, B4, 128, KBIG, linWb[0] + t * 16384, p_linb[0] + t * F,
        nullptr, nullptr, nullptr, B5, N, 128);
    gather_kernel<<<(N + 3) / 4, blk256, 0, stream>>>(row0, other0, w0c, B5, B0, B2, N);

    bgemm<128, 1, true, true><<<gemm_grid, blk256, 0, stream>>>(
        B1, 128, B1, 128, KBIG, a1Wb[1] + t * 16384, p_a1b[1] + t * F,
        states, p_a0[1] + t, rs + (1 * 3 + t) * 128, B4, N, 128);
    bgemm<128, 0, true, false><<<gemm_grid, blk256, 0, stream>>>(
        B4, 128, B4, 128, KBIG, linWb[1] + t * 16384, p_linb[1] + t * F,
        nullptr, nullptr, nullptr, B5, N, 128);
    gather_kernel<<<(N + 3) / 4, blk256, 0, stream>>>(row1, other1, w1c, B5, B1, B3, N);
  }

  // ---- beta stage ----
  bgemm<128, 0, false, false><<<gemm_grid, blk256, 0, stream>>>(
      B2, 128, B2, 128, KBIG, b0b, nullptr, nullptr, nullptr, nullptr, B4, N, 128);   // u
  bgemm<128, 0, false, false><<<gemm_grid, blk256, 0, stream>>>(
      B3, 128, B3, 128, KBIG, b1b, nullptr, nullptr, nullptr, nullptr, B5, N, 128);   // v
  bgemm<128, 1, true, false><<<gemm_grid, blk256, 0, stream>>>(
      B4, 128, B5, 128, 128, b2b, beta2b, nullptr, nullptr, nullptr, B0, N, 256);     // xc

  // ---- per-graph sums + 16-row GEMMs ----
  hipMemsetAsync(gsel, 0, (size_t)G * F * 4, stream);
  hipMemsetAsync(gsum, 0, (size_t)G * F * 4, stream);
  segsum_kernel<<<(N + 255) / 256, dim3(128), 0, stream>>>(B0, batch, states, gsel, gsum, N);
  small16_kernel<<<G, blk256, 0, stream>>>(gsel, gsum, g1W, g2W, A16b, B16b);

  // ---- gamma stage ----
  bgemm<128, 0, false, false><<<gemm_grid, blk256, 0, stream>>>(
      B0, 128, B0, 128, KBIG, g0b, nullptr, nullptr, nullptr, nullptr, B1, N, 128);   // wbuf
  hcat_kernel<<<9375, blk256, 0, stream>>>(B1, A16b, B16b, batch, hc, N);
  bgemm<192, 1, false, false><<<gemm_grid, blk256, 0, stream>>>(
      hc, 384, hc, 384, KBIG, g3b, nullptr, nullptr, nullptr, nullptr, zb, N, 384);   // z
  final_kernel<<<(N + 3) / 4, blk256, 0, stream>>>(zb, g4W, g4b, out, N);
}

// Round 3
// 1074.509 us; speedup vs baseline: 1.7281x; 1.0945x over previous
//
#include <hip/hip_runtime.h>

typedef short s8v __attribute__((ext_vector_type(8)));
typedef float f32x4 __attribute__((ext_vector_type(4)));

#define LRELU(v) ((v) > 0.f ? (v) : 0.2f * (v))

__device__ __forceinline__ float b2f(unsigned short b) {
  return __uint_as_float(((unsigned int)b) << 16);
}
__device__ __forceinline__ unsigned short f2b(float f) {
  unsigned int x = __float_as_uint(f);
  x += 0x7fffu + ((x >> 16) & 1u);
  return (unsigned short)(x >> 16);
}
__device__ __forceinline__ unsigned int pack2(float lo, float hi) {
  return ((unsigned int)f2b(hi) << 16) | (unsigned int)f2b(lo);
}

// ---------------- batched bf16 MFMA GEMM ----------------
struct BArgs {
  const unsigned short* A1[2];
  const unsigned short* A2[2];
  int ldA1, ldA2, K1;
  const unsigned short* W[2];
  const float* bias[2];
  const float* a0p[2];
  const float* rowsum[2];
  unsigned short* C[2];
  const float* states;
  int N, K;
};

template<int FOUT, int ACT, bool HAS_BIAS, bool HAS_STATES>
__global__ __launch_bounds__(256) void bgemm(BArgs ba)
{
  constexpr int NF = FOUT / 16;
  __shared__ __align__(16) unsigned short Ws[FOUT * 128];
  const int d = blockIdx.y;
  const unsigned short* __restrict__ A1 = ba.A1[d];
  const unsigned short* __restrict__ A2 = ba.A2[d];
  const unsigned short* __restrict__ W  = ba.W[d];
  unsigned short* __restrict__ C = ba.C[d];
  const int N = ba.N, K = ba.K, K1 = ba.K1, ldA1 = ba.ldA1, ldA2 = ba.ldA2;

  const int tid = threadIdx.x;
  const int lane = tid & 63;
  const int w = tid >> 6;
  const int l15 = lane & 15;
  const int g = lane >> 4;
  const int m0 = blockIdx.x * 128;

  f32x4 zero4 = {0.f, 0.f, 0.f, 0.f};
  f32x4 acc[2][NF];
#pragma unroll
  for (int mf = 0; mf < 2; ++mf)
#pragma unroll
    for (int nf = 0; nf < NF; ++nf) acc[mf][nf] = zero4;

  for (int kk = 0; kk < K; kk += 128) {
#pragma unroll
    for (int j = 0; j < NF; ++j) {
      int idx = tid + j * 256;
      int o = idx >> 4, c = idx & 15;
      uint4 v = *(const uint4*)(W + (size_t)o * K + kk + c * 8);
      *(uint4*)&Ws[o * 128 + (c ^ (o & 15)) * 8] = v;
    }
    const unsigned short* Ap; int ldA, koff;
    if (kk < K1) { Ap = A1; ldA = ldA1; koff = kk; }
    else         { Ap = A2; ldA = ldA2; koff = kk - K1; }
    s8v a[2][4];
#pragma unroll
    for (int mf = 0; mf < 2; ++mf) {
      int row = m0 + w * 32 + mf * 16 + l15;
      const unsigned short* ar = Ap + (size_t)row * ldA + koff + g * 8;
#pragma unroll
      for (int ks = 0; ks < 4; ++ks) {
        s8v t = {};
        if (row < N) t = *(const s8v*)(ar + ks * 32);
        a[mf][ks] = t;
      }
    }
    __syncthreads();
#pragma unroll
    for (int ks = 0; ks < 4; ++ks) {
#pragma unroll
      for (int nf = 0; nf < NF; ++nf) {
        int c = ks * 4 + g;
        s8v b = *(const s8v*)&Ws[(nf * 16 + l15) * 128 + (c ^ l15) * 8];
        acc[0][nf] = __builtin_amdgcn_mfma_f32_16x16x32_bf16(a[0][ks], b, acc[0][nf], 0, 0, 0);
        acc[1][nf] = __builtin_amdgcn_mfma_f32_16x16x32_bf16(a[1][ks], b, acc[1][nf], 0, 0, 0);
      }
    }
    if (kk + 128 < K) __syncthreads();
  }

  const float a0 = HAS_STATES ? ba.a0p[d][0] : 0.f;
#pragma unroll
  for (int mf = 0; mf < 2; ++mf) {
#pragma unroll
    for (int r = 0; r < 4; ++r) {
      int row = m0 + w * 32 + mf * 16 + g * 4 + r;
      if (row >= N) continue;
      float sa = HAS_STATES ? ba.states[row] * a0 : 0.f;
      unsigned short* crow = C + (size_t)row * FOUT;
#pragma unroll
      for (int nf = 0; nf < NF; ++nf) {
        int col = nf * 16 + l15;
        float v = acc[mf][nf][r];
        if (HAS_BIAS) v += ba.bias[d][col];
        if (HAS_STATES) v += sa * ba.rowsum[d][col];
        if (ACT) v = LRELU(v);
        crow[col] = f2b(v);
      }
    }
  }
}

// ---------------- g3 GEMM: A = [wbuf | A16[batch] | B16[batch]], fused final dot ----------------
__global__ __launch_bounds__(256) void g3_kernel(
    const unsigned short* __restrict__ wbuf,
    const unsigned short* __restrict__ A16,
    const unsigned short* __restrict__ B16,
    const int* __restrict__ batch,
    const unsigned short* __restrict__ W,   // g3W bf16 [192][384]
    const float* __restrict__ g4W,          // [192]
    const float* __restrict__ g4b,
    float* __restrict__ out, int N)
{
  constexpr int NF = 12;
  __shared__ __align__(16) unsigned short Ws[192 * 128];
  const int tid = threadIdx.x;
  const int lane = tid & 63;
  const int w = tid >> 6;
  const int l15 = lane & 15;
  const int g = lane >> 4;
  const int m0 = blockIdx.x * 128;

  f32x4 zero4 = {0.f, 0.f, 0.f, 0.f};
  f32x4 acc[2][NF];
#pragma unroll
  for (int mf = 0; mf < 2; ++mf)
#pragma unroll
    for (int nf = 0; nf < NF; ++nf) acc[mf][nf] = zero4;

  int brow[2];
#pragma unroll
  for (int mf = 0; mf < 2; ++mf) {
    int row = m0 + w * 32 + mf * 16 + l15;
    brow[mf] = (row < N) ? batch[row] : 0;
  }

  for (int kk = 0; kk < 384; kk += 128) {
#pragma unroll
    for (int j = 0; j < NF; ++j) {
      int idx = tid + j * 256;
      int o = idx >> 4, c = idx & 15;
      uint4 v = *(const uint4*)(W + (size_t)o * 384 + kk + c * 8);
      *(uint4*)&Ws[o * 128 + (c ^ (o & 15)) * 8] = v;
    }
    s8v a[2][4];
#pragma unroll
    for (int mf = 0; mf < 2; ++mf) {
      int row = m0 + w * 32 + mf * 16 + l15;
      const unsigned short* ar;
      if (kk == 0)        ar = wbuf + (size_t)row * 128 + g * 8;
      else if (kk == 128) ar = A16 + (size_t)brow[mf] * 128 + g * 8;
      else                ar = B16 + (size_t)brow[mf] * 128 + g * 8;
#pragma unroll
      for (int ks = 0; ks < 4; ++ks) {
        s8v t = {};
        if (row < N) t = *(const s8v*)(ar + ks * 32);
        a[mf][ks] = t;
      }
    }
    __syncthreads();
#pragma unroll
    for (int ks = 0; ks < 4; ++ks) {
#pragma unroll
      for (int nf = 0; nf < NF; ++nf) {
        int c = ks * 4 + g;
        s8v b = *(const s8v*)&Ws[(nf * 16 + l15) * 128 + (c ^ l15) * 8];
        acc[0][nf] = __builtin_amdgcn_mfma_f32_16x16x32_bf16(a[0][ks], b, acc[0][nf], 0, 0, 0);
        acc[1][nf] = __builtin_amdgcn_mfma_f32_16x16x32_bf16(a[1][ks], b, acc[1][nf], 0, 0, 0);
      }
    }
    if (kk < 256) __syncthreads();
  }

  float w4[NF];
#pragma unroll
  for (int nf = 0; nf < NF; ++nf) w4[nf] = g4W[nf * 16 + l15];
  const float gb = g4b[0];

#pragma unroll
  for (int mf = 0; mf < 2; ++mf) {
#pragma unroll
    for (int r = 0; r < 4; ++r) {
      int row = m0 + w * 32 + mf * 16 + g * 4 + r;
      float dot = 0.f;
#pragma unroll
      for (int nf = 0; nf < NF; ++nf) {
        float v = acc[mf][nf][r];
        v = LRELU(v);
        dot += v * w4[nf];
      }
#pragma unroll
      for (int m = 1; m < 16; m <<= 1) dot += __shfl_xor(dot, m, 16);
      if (l15 == 0 && row < N) out[row] = dot + gb;
    }
  }
}

// ---------------- weight fp32 -> bf16 conversion ----------------
struct CJobs { const float* s[9]; unsigned short* d[9]; int n[9]; };
__global__ void convert_kernel(CJobs jb) {
  int j = blockIdx.y;
  int idx = (blockIdx.x * 256 + threadIdx.x) * 8;
  if (idx >= jb.n[j]) return;
  const float* s = jb.s[j] + idx;
  float4 p0 = *(const float4*)s;
  float4 p1 = *(const float4*)(s + 4);
  uint4 u;
  u.x = pack2(p0.x, p0.y); u.y = pack2(p0.z, p0.w);
  u.z = pack2(p1.x, p1.y); u.w = pack2(p1.z, p1.w);
  *(uint4*)(jb.d[j] + idx) = u;
}

__global__ void rowsum_kernel(const float* __restrict__ a1,
                              const float* __restrict__ a2, float* __restrict__ rs) {
  int j = blockIdx.x;
  const float* src = (j < 3) ? (a1 + (size_t)j * 16384) : (a2 + (size_t)(j - 3) * 16384);
  int o = threadIdx.x;
  float s = 0.f;
  for (int k = 0; k < 128; ++k) s += src[o * 128 + k];
  rs[j * 128 + o] = s;
}

__global__ void init_kernel(const float* __restrict__ x,
                            unsigned short* __restrict__ x1, unsigned short* __restrict__ x2,
                            unsigned short* __restrict__ x1s, unsigned short* __restrict__ x2s,
                            int n)
{
  int idx = blockIdx.x * blockDim.x + threadIdx.x;
  int total = n * 16;
  for (; idx < total; idx += gridDim.x * blockDim.x) {
    int r = idx >> 4, c = idx & 15;
    const float* xr = x + (size_t)r * 256 + c * 8;
    float4 p0 = *(const float4*)xr;
    float4 p1 = *(const float4*)(xr + 4);
    uint4 u1;
    u1.x = pack2(p0.x, p0.y); u1.y = pack2(p0.z, p0.w);
    u1.z = pack2(p1.x, p1.y); u1.w = pack2(p1.z, p1.w);
    float4 q0 = *(const float4*)(xr + 128);
    float4 q1 = *(const float4*)(xr + 132);
    uint4 u2;
    u2.x = pack2(q0.x, q0.y); u2.y = pack2(q0.z, q0.w);
    u2.z = pack2(q1.x, q1.y); u2.w = pack2(q1.z, q1.w);
    ((uint4*)(x1 + (size_t)r * 128))[c] = u1;
    ((uint4*)(x2 + (size_t)r * 128))[c] = u2;
    uint4 z = make_uint4(0, 0, 0, 0);
    ((uint4*)(x1s + (size_t)r * 128))[c] = z;
    ((uint4*)(x2s + (size_t)r * 128))[c] = z;
  }
}

__global__ void hist_kernel(const int* __restrict__ s0, const int* __restrict__ s1,
                            int* __restrict__ cnt0, int* __restrict__ cnt1, int E_)
{
  int e = blockIdx.x * blockDim.x + threadIdx.x;
  if (e >= E_) return;
  atomicAdd(&cnt0[s0[e]], 1);
  atomicAdd(&cnt1[s1[e]], 1);
}

// coarsened single-block scan; grid.x = 2 directions; writes rowstart AND cursor copy
struct ScanArgs { const int* cnt[2]; int* row[2]; int* cur[2]; int n; };
__global__ __launch_bounds__(1024) void scan_kernel(ScanArgs sa)
{
  int d = blockIdx.x;
  const int* __restrict__ cnt = sa.cnt[d];
  int* __restrict__ row = sa.row[d];
  int* __restrict__ cur = sa.cur[d];
  const int n = sa.n;
  __shared__ int part[1024];
  int tid = threadIdx.x;
  const int CH = (n + 1023) / 1024;
  int b0 = min(tid * CH, n), b1 = min(b0 + CH, n);
  int s = 0;
  for (int i = b0; i < b1; ++i) s += cnt[i];
  part[tid] = s;
  __syncthreads();
  for (int off = 1; off < 1024; off <<= 1) {
    int t = (tid >= off) ? part[tid - off] : 0;
    __syncthreads();
    part[tid] += t;
    __syncthreads();
  }
  int pre = part[tid] - s;
  for (int i = b0; i < b1; ++i) {
    row[i] = pre; cur[i] = pre; pre += cnt[i];
  }
  if (tid == 1023) row[n] = part[1023];
}

// packed 8B CSR fill
__global__ void fill_kernel(const int* __restrict__ s0, const int* __restrict__ s1,
                            const float* __restrict__ ew,
                            int* __restrict__ cur0, int* __restrict__ cur1,
                            unsigned long long* __restrict__ comb0,
                            unsigned long long* __restrict__ comb1, int E_)
{
  int e = blockIdx.x * blockDim.x + threadIdx.x;
  if (e >= E_) return;
  int d0 = s0[e], d1 = s1[e];
  unsigned long long wb = (unsigned long long)__float_as_uint(ew[e]) << 32;
  int p0 = atomicAdd(&cur0[d0], 1);
  comb0[p0] = wb | (unsigned int)d1;
  int p1 = atomicAdd(&cur1[d1], 1);
  comb1[p1] = wb | (unsigned int)d0;
}

// merged dual-direction gather; wave per node
struct GArgs {
  const int* rowstart[2];
  const unsigned long long* comb[2];
  const unsigned short* h[2];
  unsigned short* xout[2];
  unsigned short* xsum[2];
  int n;
};
__global__ void gather_kernel(GArgs ga)
{
  int gw = blockIdx.x * (blockDim.x >> 6) + (threadIdx.x >> 6);
  int lane = threadIdx.x & 63;
  if (gw >= 2 * ga.n) return;
  int dir = (gw >= ga.n) ? 1 : 0;
  int node = gw - dir * ga.n;
  const int* rowstart = ga.rowstart[dir];
  const unsigned long long* comb = ga.comb[dir];
  const unsigned short* h = ga.h[dir];
  int beg = rowstart[node], end = rowstart[node + 1];
  float a0 = 0.f, a1 = 0.f;
  for (int p = beg; p < end; ++p) {
    unsigned long long c = comb[p];
    int s = (int)(unsigned int)c;
    float wv = __uint_as_float((unsigned int)(c >> 32));
    unsigned int u = ((const unsigned int*)(h + (size_t)s * 128))[lane];
    a0 += wv * b2f((unsigned short)u);
    a1 += wv * b2f((unsigned short)(u >> 16));
  }
  float v0 = LRELU(a0), v1 = LRELU(a1);
  unsigned int* xo = (unsigned int*)(ga.xout[dir] + (size_t)node * 128);
  unsigned int* xs = (unsigned int*)(ga.xsum[dir] + (size_t)node * 128);
  xo[lane] = pack2(v0, v1);
  unsigned int sv = xs[lane];
  xs[lane] = pack2(b2f((unsigned short)sv) + v0, b2f((unsigned short)(sv >> 16)) + v1);
}

__global__ void segsum_kernel(const unsigned short* __restrict__ xc,
                              const int* __restrict__ batch,
                              const float* __restrict__ states,
                              float* __restrict__ gsel, float* __restrict__ gsum, int n)
{
  int f = threadIdx.x;
  int r0 = blockIdx.x * 256;
  int r1 = min(r0 + 256, n);
  float asel = 0.f, asum = 0.f;
  int cur = batch[r0];
  for (int r = r0; r < r1; ++r) {
    int b = batch[r];
    if (b != cur) {
      atomicAdd(&gsel[cur * 128 + f], asel);
      atomicAdd(&gsum[cur * 128 + f], asum);
      asel = asum = 0.f;
      cur = b;
    }
    float v = b2f(xc[(size_t)r * 128 + f]);
    asum += v;
    if (states[r] == 1.0f) asel += v;
  }
  atomicAdd(&gsel[cur * 128 + f], asel);
  atomicAdd(&gsum[cur * 128 + f], asum);
}

__global__ void small16_kernel(const float* __restrict__ gsel, const float* __restrict__ gsum,
                               const float* __restrict__ g1W, const float* __restrict__ g2W,
                               unsigned short* __restrict__ A16, unsigned short* __restrict__ B16)
{
  int r = blockIdx.x, t = threadIdx.x, o = t & 127;
  const float* src = (t < 128) ? gsel : gsum;
  const float* Wm  = (t < 128) ? g1W : g2W;
  float acc = 0.f;
  for (int k = 0; k < 128; ++k) acc += src[r * 128 + k] * Wm[o * 128 + k];
  unsigned short* dst = (t < 128) ? A16 : B16;
  dst[r * 128 + o] = f2b(acc);
}

extern "C" void kernel_launch(void* const* d_in, const int* in_sizes, int n_in,
                              void* d_out, int out_size, void* d_ws, size_t ws_size,
                              hipStream_t stream)
{
  const int N = 50000, F = 128, E = 800000, G = 16, T = 3;
  const float* x      = (const float*)d_in[0];
  const int*   ei     = (const int*)d_in[1];
  const int*   s0     = ei;
  const int*   s1     = ei + E;
  const float* ew     = (const float*)d_in[2];
  const int*   batch  = (const int*)d_in[3];
  const float* states = (const float*)d_in[4];
  const float* p_a0[2]   = {(const float*)d_in[5],  (const float*)d_in[10]};
  const float* p_a1W[2]  = {(const float*)d_in[6],  (const float*)d_in[11]};
  const float* p_a1b[2]  = {(const float*)d_in[7],  (const float*)d_in[12]};
  const float* p_linW[2] = {(const float*)d_in[8],  (const float*)d_in[13]};
  const float* p_linb[2] = {(const float*)d_in[9],  (const float*)d_in[14]};
  const float* beta0W = (const float*)d_in[15];
  const float* beta1W = (const float*)d_in[16];
  const float* beta2W = (const float*)d_in[17];
  const float* beta2b = (const float*)d_in[18];
  const float* g0W = (const float*)d_in[19];
  const float* g1W = (const float*)d_in[20];
  const float* g2W = (const float*)d_in[21];
  const float* g3W = (const float*)d_in[22];
  const float* g4W = (const float*)d_in[23];
  const float* g4b = (const float*)d_in[24];
  float* out = (float*)d_out;

  char* p = (char*)d_ws;
  auto alloc = [&](size_t bytes) {
    char* r = p;
    p += (bytes + 255) & ~(size_t)255;
    return r;
  };
  const size_t NFb2 = (size_t)N * F * sizeof(unsigned short);  // 12.8 MB
  unsigned short* B0 = (unsigned short*)alloc(NFb2);  // x1 -> xc
  unsigned short* B1 = (unsigned short*)alloc(NFb2);  // x2 -> wbuf
  unsigned short* B2 = (unsigned short*)alloc(NFb2);  // x1s
  unsigned short* B3 = (unsigned short*)alloc(NFb2);  // x2s
  unsigned short* B4 = (unsigned short*)alloc(NFb2);  // tmp p1 / u
  unsigned short* B5 = (unsigned short*)alloc(NFb2);  // h p1
  unsigned short* B6 = (unsigned short*)alloc(NFb2);  // tmp p2 / v
  unsigned short* B7 = (unsigned short*)alloc(NFb2);  // h p2
  int*   row0 = (int*)alloc((size_t)(N + 1) * 4);
  int*   row1 = (int*)alloc((size_t)(N + 1) * 4);
  int*   cur0 = (int*)alloc((size_t)N * 4);
  int*   cur1 = (int*)alloc((size_t)N * 4);
  int*   cnt0 = (int*)alloc((size_t)N * 4);
  int*   cnt1 = (int*)alloc((size_t)N * 4);
  unsigned long long* comb0 = (unsigned long long*)alloc((size_t)E * 8);
  unsigned long long* comb1 = (unsigned long long*)alloc((size_t)E * 8);
  float* gsel = (float*)alloc((size_t)G * F * 4);
  float* gsum = (float*)alloc((size_t)G * F * 4);
  unsigned short* A16b = (unsigned short*)alloc((size_t)G * F * 2);
  unsigned short* B16b = (unsigned short*)alloc((size_t)G * F * 2);
  unsigned short* wreg = (unsigned short*)alloc((size_t)352256 * 2);
  float* rs = (float*)alloc((size_t)6 * 128 * 4);

  unsigned short* a1Wb[2]  = {wreg + 0,      wreg + 49152};
  unsigned short* linWb[2] = {wreg + 98304,  wreg + 147456};
  unsigned short* b0b = wreg + 196608;
  unsigned short* b1b = wreg + 212992;
  unsigned short* b2b = wreg + 229376;
  unsigned short* g0b = wreg + 262144;
  unsigned short* g3b = wreg + 278528;

  const dim3 blk256(256);
  const dim3 edge_grid((E + 255) / 256);
  const int GX = (N + 127) / 128;
  const int KBIG = 1 << 30;

  // ---- CSR build ----
  hipMemsetAsync(cnt0, 0, (size_t)N * 4, stream);
  hipMemsetAsync(cnt1, 0, (size_t)N * 4, stream);
  hist_kernel<<<edge_grid, blk256, 0, stream>>>(s0, s1, cnt0, cnt1, E);
  ScanArgs sa;
  sa.cnt[0] = cnt0; sa.cnt[1] = cnt1;
  sa.row[0] = row0; sa.row[1] = row1;
  sa.cur[0] = cur0; sa.cur[1] = cur1;
  sa.n = N;
  scan_kernel<<<2, 1024, 0, stream>>>(sa);
  fill_kernel<<<edge_grid, blk256, 0, stream>>>(s0, s1, ew, cur0, cur1, comb0, comb1, E);

  // ---- weight conversion + rowsums + init ----
  CJobs jb;
  jb.s[0] = p_a1W[0];  jb.d[0] = a1Wb[0];  jb.n[0] = 49152;
  jb.s[1] = p_a1W[1];  jb.d[1] = a1Wb[1];  jb.n[1] = 49152;
  jb.s[2] = p_linW[0]; jb.d[2] = linWb[0]; jb.n[2] = 49152;
  jb.s[3] = p_linW[1]; jb.d[3] = linWb[1]; jb.n[3] = 49152;
  jb.s[4] = beta0W;    jb.d[4] = b0b;      jb.n[4] = 16384;
  jb.s[5] = beta1W;    jb.d[5] = b1b;      jb.n[5] = 16384;
  jb.s[6] = beta2W;    jb.d[6] = b2b;      jb.n[6] = 32768;
  jb.s[7] = g0W;       jb.d[7] = g0b;      jb.n[7] = 16384;
  jb.s[8] = g3W;       jb.d[8] = g3b;      jb.n[8] = 73728;
  convert_kernel<<<dim3(36, 9), blk256, 0, stream>>>(jb);
  rowsum_kernel<<<6, 128, 0, stream>>>(p_a1W[0], p_a1W[1], rs);
  init_kernel<<<3125, blk256, 0, stream>>>(x, B0, B1, B2, B3, N);

  GArgs ga;
  ga.rowstart[0] = row0; ga.rowstart[1] = row1;
  ga.comb[0] = comb0;    ga.comb[1] = comb1;
  ga.h[0] = B5;          ga.h[1] = B7;
  ga.xout[0] = B0;       ga.xout[1] = B1;
  ga.xsum[0] = B2;       ga.xsum[1] = B3;
  ga.n = N;

  // ---- T-loop ----
  for (int t = 0; t < T; ++t) {
    BArgs g1;
    g1.A1[0] = B0; g1.A2[0] = B0; g1.A1[1] = B1; g1.A2[1] = B1;
    g1.ldA1 = 128; g1.ldA2 = 128; g1.K1 = KBIG;
    g1.W[0] = a1Wb[0] + t * 16384; g1.W[1] = a1Wb[1] + t * 16384;
    g1.bias[0] = p_a1b[0] + t * F; g1.bias[1] = p_a1b[1] + t * F;
    g1.a0p[0] = p_a0[0] + t;       g1.a0p[1] = p_a0[1] + t;
    g1.rowsum[0] = rs + t * 128;   g1.rowsum[1] = rs + (3 + t) * 128;
    g1.C[0] = B4; g1.C[1] = B6;
    g1.states = states; g1.N = N; g1.K = 128;
    bgemm<128, 1, true, true><<<dim3(GX, 2), blk256, 0, stream>>>(g1);

    BArgs g2;
    g2.A1[0] = B4; g2.A2[0] = B4; g2.A1[1] = B6; g2.A2[1] = B6;
    g2.ldA1 = 128; g2.ldA2 = 128; g2.K1 = KBIG;
    g2.W[0] = linWb[0] + t * 16384; g2.W[1] = linWb[1] + t * 16384;
    g2.bias[0] = p_linb[0] + t * F; g2.bias[1] = p_linb[1] + t * F;
    g2.a0p[0] = nullptr; g2.a0p[1] = nullptr;
    g2.rowsum[0] = nullptr; g2.rowsum[1] = nullptr;
    g2.C[0] = B5; g2.C[1] = B7;
    g2.states = nullptr; g2.N = N; g2.K = 128;
    bgemm<128, 0, true, false><<<dim3(GX, 2), blk256, 0, stream>>>(g2);

    gather_kernel<<<(2 * N + 3) / 4, blk256, 0, stream>>>(ga);
  }

  // ---- beta stage: u = x1s@b0^T, v = x2s@b1^T (pair), then xc ----
  BArgs bu;
  bu.A1[0] = B2; bu.A2[0] = B2; bu.A1[1] = B3; bu.A2[1] = B3;
  bu.ldA1 = 128; bu.ldA2 = 128; bu.K1 = KBIG;
  bu.W[0] = b0b; bu.W[1] = b1b;
  bu.bias[0] = nullptr; bu.bias[1] = nullptr;
  bu.a0p[0] = nullptr; bu.a0p[1] = nullptr;
  bu.rowsum[0] = nullptr; bu.rowsum[1] = nullptr;
  bu.C[0] = B4; bu.C[1] = B6;
  bu.states = nullptr; bu.N = N; bu.K = 128;
  bgemm<128, 0, false, false><<<dim3(GX, 2), blk256, 0, stream>>>(bu);

  BArgs b2a;
  b2a.A1[0] = B4; b2a.A2[0] = B6; b2a.A1[1] = nullptr; b2a.A2[1] = nullptr;
  b2a.ldA1 = 128; b2a.ldA2 = 128; b2a.K1 = 128;
  b2a.W[0] = b2b; b2a.W[1] = nullptr;
  b2a.bias[0] = beta2b; b2a.bias[1] = nullptr;
  b2a.a0p[0] = nullptr; b2a.a0p[1] = nullptr;
  b2a.rowsum[0] = nullptr; b2a.rowsum[1] = nullptr;
  b2a.C[0] = B0; b2a.C[1] = nullptr;
  b2a.states = nullptr; b2a.N = N; b2a.K = 256;
  bgemm<128, 1, true, false><<<dim3(GX, 1), blk256, 0, stream>>>(b2a);

  // ---- per-graph sums + 16-row GEMMs ----
  hipMemsetAsync(gsel, 0, (size_t)G * F * 4, stream);
  hipMemsetAsync(gsum, 0, (size_t)G * F * 4, stream);
  segsum_kernel<<<(N + 255) / 256, dim3(128), 0, stream>>>(B0, batch, states, gsel, gsum, N);
  small16_kernel<<<G, blk256, 0, stream>>>(gsel, gsum, g1W, g2W, A16b, B16b);

  // ---- gamma stage ----
  BArgs g0a;
  g0a.A1[0] = B0; g0a.A2[0] = B0; g0a.A1[1] = nullptr; g0a.A2[1] = nullptr;
  g0a.ldA1 = 128; g0a.ldA2 = 128; g0a.K1 = KBIG;
  g0a.W[0] = g0b; g0a.W[1] = nullptr;
  g0a.bias[0] = nullptr; g0a.bias[1] = nullptr;
  g0a.a0p[0] = nullptr; g0a.a0p[1] = nullptr;
  g0a.rowsum[0] = nullptr; g0a.rowsum[1] = nullptr;
  g0a.C[0] = B1; g0a.C[1] = nullptr;
  g0a.states = nullptr; g0a.N = N; g0a.K = 128;
  bgemm<128, 0, false, false><<<dim3(GX, 1), blk256, 0, stream>>>(g0a);

  g3_kernel<<<GX, blk256, 0, stream>>>(B1, A16b, B16b, batch, g3b, g4W, g4b, out, N);
}

// Round 4
// 854.065 us; speedup vs baseline: 2.1742x; 1.2581x over previous
//
#include <hip/hip_runtime.h>

typedef short s8v __attribute__((ext_vector_type(8)));
typedef float f32x4 __attribute__((ext_vector_type(4)));

#define LRELU(v) ((v) > 0.f ? (v) : 0.2f * (v))

__device__ __forceinline__ float b2f(unsigned short b) {
  return __uint_as_float(((unsigned int)b) << 16);
}
__device__ __forceinline__ unsigned short f2b(float f) {
  unsigned int x = __float_as_uint(f);
  x += 0x7fffu + ((x >> 16) & 1u);
  return (unsigned short)(x >> 16);
}
__device__ __forceinline__ unsigned int pack2(float lo, float hi) {
  return ((unsigned int)f2b(hi) << 16) | (unsigned int)f2b(lo);
}

// ---------------- batched bf16 MFMA GEMM ----------------
struct BArgs {
  const unsigned short* A1[2];
  const unsigned short* A2[2];
  int ldA1, ldA2, K1;
  const unsigned short* W[2];
  const float* bias[2];
  const float* a0p[2];
  const float* rowsum[2];
  unsigned short* C[2];
  const float* states;
  int N, K;
};

template<int FOUT, int ACT, bool HAS_BIAS, bool HAS_STATES>
__global__ __launch_bounds__(256) void bgemm(BArgs ba)
{
  constexpr int NF = FOUT / 16;
  __shared__ __align__(16) unsigned short Ws[FOUT * 128];
  const int d = blockIdx.y;
  const unsigned short* __restrict__ A1 = ba.A1[d];
  const unsigned short* __restrict__ A2 = ba.A2[d];
  const unsigned short* __restrict__ W  = ba.W[d];
  unsigned short* __restrict__ C = ba.C[d];
  const int N = ba.N, K = ba.K, K1 = ba.K1, ldA1 = ba.ldA1, ldA2 = ba.ldA2;

  const int tid = threadIdx.x;
  const int lane = tid & 63;
  const int w = tid >> 6;
  const int l15 = lane & 15;
  const int g = lane >> 4;
  const int m0 = blockIdx.x * 128;

  f32x4 zero4 = {0.f, 0.f, 0.f, 0.f};
  f32x4 acc[2][NF];
#pragma unroll
  for (int mf = 0; mf < 2; ++mf)
#pragma unroll
    for (int nf = 0; nf < NF; ++nf) acc[mf][nf] = zero4;

  for (int kk = 0; kk < K; kk += 128) {
#pragma unroll
    for (int j = 0; j < NF; ++j) {
      int idx = tid + j * 256;
      int o = idx >> 4, c = idx & 15;
      uint4 v = *(const uint4*)(W + (size_t)o * K + kk + c * 8);
      *(uint4*)&Ws[o * 128 + (c ^ (o & 15)) * 8] = v;
    }
    const unsigned short* Ap; int ldA, koff;
    if (kk < K1) { Ap = A1; ldA = ldA1; koff = kk; }
    else         { Ap = A2; ldA = ldA2; koff = kk - K1; }
    s8v a[2][4];
#pragma unroll
    for (int mf = 0; mf < 2; ++mf) {
      int row = m0 + w * 32 + mf * 16 + l15;
      const unsigned short* ar = Ap + (size_t)row * ldA + koff + g * 8;
#pragma unroll
      for (int ks = 0; ks < 4; ++ks) {
        s8v t = {};
        if (row < N) t = *(const s8v*)(ar + ks * 32);
        a[mf][ks] = t;
      }
    }
    __syncthreads();
#pragma unroll
    for (int ks = 0; ks < 4; ++ks) {
#pragma unroll
      for (int nf = 0; nf < NF; ++nf) {
        int c = ks * 4 + g;
        s8v b = *(const s8v*)&Ws[(nf * 16 + l15) * 128 + (c ^ l15) * 8];
        acc[0][nf] = __builtin_amdgcn_mfma_f32_16x16x32_bf16(a[0][ks], b, acc[0][nf], 0, 0, 0);
        acc[1][nf] = __builtin_amdgcn_mfma_f32_16x16x32_bf16(a[1][ks], b, acc[1][nf], 0, 0, 0);
      }
    }
    if (kk + 128 < K) __syncthreads();
  }

  const float a0 = HAS_STATES ? ba.a0p[d][0] : 0.f;
#pragma unroll
  for (int mf = 0; mf < 2; ++mf) {
#pragma unroll
    for (int r = 0; r < 4; ++r) {
      int row = m0 + w * 32 + mf * 16 + g * 4 + r;
      if (row >= N) continue;
      float sa = HAS_STATES ? ba.states[row] * a0 : 0.f;
      unsigned short* crow = C + (size_t)row * FOUT;
#pragma unroll
      for (int nf = 0; nf < NF; ++nf) {
        int col = nf * 16 + l15;
        float v = acc[mf][nf][r];
        if (HAS_BIAS) v += ba.bias[d][col];
        if (HAS_STATES) v += sa * ba.rowsum[d][col];
        if (ACT) v = LRELU(v);
        crow[col] = f2b(v);
      }
    }
  }
}

// ---------------- g3 GEMM: A = [wbuf | A16[batch] | B16[batch]], fused final dot ----------------
__global__ __launch_bounds__(256) void g3_kernel(
    const unsigned short* __restrict__ wbuf,
    const unsigned short* __restrict__ A16,
    const unsigned short* __restrict__ B16,
    const int* __restrict__ batch,
    const unsigned short* __restrict__ W,   // g3W bf16 [192][384]
    const float* __restrict__ g4W,          // [192]
    const float* __restrict__ g4b,
    float* __restrict__ out, int N)
{
  constexpr int NF = 12;
  __shared__ __align__(16) unsigned short Ws[192 * 128];
  const int tid = threadIdx.x;
  const int lane = tid & 63;
  const int w = tid >> 6;
  const int l15 = lane & 15;
  const int g = lane >> 4;
  const int m0 = blockIdx.x * 128;

  f32x4 zero4 = {0.f, 0.f, 0.f, 0.f};
  f32x4 acc[2][NF];
#pragma unroll
  for (int mf = 0; mf < 2; ++mf)
#pragma unroll
    for (int nf = 0; nf < NF; ++nf) acc[mf][nf] = zero4;

  int brow[2];
#pragma unroll
  for (int mf = 0; mf < 2; ++mf) {
    int row = m0 + w * 32 + mf * 16 + l15;
    brow[mf] = (row < N) ? batch[row] : 0;
  }

  for (int kk = 0; kk < 384; kk += 128) {
#pragma unroll
    for (int j = 0; j < NF; ++j) {
      int idx = tid + j * 256;
      int o = idx >> 4, c = idx & 15;
      uint4 v = *(const uint4*)(W + (size_t)o * 384 + kk + c * 8);
      *(uint4*)&Ws[o * 128 + (c ^ (o & 15)) * 8] = v;
    }
    s8v a[2][4];
#pragma unroll
    for (int mf = 0; mf < 2; ++mf) {
      int row = m0 + w * 32 + mf * 16 + l15;
      const unsigned short* ar;
      if (kk == 0)        ar = wbuf + (size_t)row * 128 + g * 8;
      else if (kk == 128) ar = A16 + (size_t)brow[mf] * 128 + g * 8;
      else                ar = B16 + (size_t)brow[mf] * 128 + g * 8;
#pragma unroll
      for (int ks = 0; ks < 4; ++ks) {
        s8v t = {};
        if (row < N) t = *(const s8v*)(ar + ks * 32);
        a[mf][ks] = t;
      }
    }
    __syncthreads();
#pragma unroll
    for (int ks = 0; ks < 4; ++ks) {
#pragma unroll
      for (int nf = 0; nf < NF; ++nf) {
        int c = ks * 4 + g;
        s8v b = *(const s8v*)&Ws[(nf * 16 + l15) * 128 + (c ^ l15) * 8];
        acc[0][nf] = __builtin_amdgcn_mfma_f32_16x16x32_bf16(a[0][ks], b, acc[0][nf], 0, 0, 0);
        acc[1][nf] = __builtin_amdgcn_mfma_f32_16x16x32_bf16(a[1][ks], b, acc[1][nf], 0, 0, 0);
      }
    }
    if (kk < 256) __syncthreads();
  }

  float w4[NF];
#pragma unroll
  for (int nf = 0; nf < NF; ++nf) w4[nf] = g4W[nf * 16 + l15];
  const float gb = g4b[0];

#pragma unroll
  for (int mf = 0; mf < 2; ++mf) {
#pragma unroll
    for (int r = 0; r < 4; ++r) {
      int row = m0 + w * 32 + mf * 16 + g * 4 + r;
      float dot = 0.f;
#pragma unroll
      for (int nf = 0; nf < NF; ++nf) {
        float v = acc[mf][nf][r];
        v = LRELU(v);
        dot += v * w4[nf];
      }
#pragma unroll
      for (int m = 1; m < 16; m <<= 1) dot += __shfl_xor(dot, m, 16);
      if (l15 == 0 && row < N) out[row] = dot + gb;
    }
  }
}

// ---------------- weight fp32 -> bf16 conversion ----------------
struct CJobs { const float* s[9]; unsigned short* d[9]; int n[9]; };
__global__ void convert_kernel(CJobs jb) {
  int j = blockIdx.y;
  int idx = (blockIdx.x * 256 + threadIdx.x) * 8;
  if (idx >= jb.n[j]) return;
  const float* s = jb.s[j] + idx;
  float4 p0 = *(const float4*)s;
  float4 p1 = *(const float4*)(s + 4);
  uint4 u;
  u.x = pack2(p0.x, p0.y); u.y = pack2(p0.z, p0.w);
  u.z = pack2(p1.x, p1.y); u.w = pack2(p1.z, p1.w);
  *(uint4*)(jb.d[j] + idx) = u;
}

__global__ void rowsum_kernel(const float* __restrict__ a1,
                              const float* __restrict__ a2, float* __restrict__ rs) {
  int j = blockIdx.x;
  const float* src = (j < 3) ? (a1 + (size_t)j * 16384) : (a2 + (size_t)(j - 3) * 16384);
  int o = threadIdx.x;
  float s = 0.f;
  for (int k = 0; k < 128; ++k) s += src[o * 128 + k];
  rs[j * 128 + o] = s;
}

// split x into x1/x2 (bf16)
__global__ void init_kernel(const float* __restrict__ x,
                            unsigned short* __restrict__ x1, unsigned short* __restrict__ x2,
                            int n)
{
  int idx = blockIdx.x * blockDim.x + threadIdx.x;
  int total = n * 16;
  for (; idx < total; idx += gridDim.x * blockDim.x) {
    int r = idx >> 4, c = idx & 15;
    const float* xr = x + (size_t)r * 256 + c * 8;
    float4 p0 = *(const float4*)xr;
    float4 p1 = *(const float4*)(xr + 4);
    uint4 u1;
    u1.x = pack2(p0.x, p0.y); u1.y = pack2(p0.z, p0.w);
    u1.z = pack2(p1.x, p1.y); u1.w = pack2(p1.z, p1.w);
    float4 q0 = *(const float4*)(xr + 128);
    float4 q1 = *(const float4*)(xr + 132);
    uint4 u2;
    u2.x = pack2(q0.x, q0.y); u2.y = pack2(q0.z, q0.w);
    u2.z = pack2(q1.x, q1.y); u2.w = pack2(q1.z, q1.w);
    ((uint4*)(x1 + (size_t)r * 128))[c] = u1;
    ((uint4*)(x2 + (size_t)r * 128))[c] = u2;
  }
}

// sum of three bf16 buffers (fp32 math), both directions via blockIdx.y
struct S3Args { const unsigned int* a[2]; const unsigned int* b[2]; const unsigned int* c[2];
                unsigned int* o[2]; int n; };
__global__ void sum3_kernel(S3Args s)
{
  int d = blockIdx.y;
  const unsigned int* __restrict__ pa = s.a[d];
  const unsigned int* __restrict__ pb = s.b[d];
  const unsigned int* __restrict__ pc = s.c[d];
  unsigned int* __restrict__ po = s.o[d];
  for (int i = blockIdx.x * 256 + threadIdx.x; i < s.n; i += gridDim.x * 256) {
    unsigned int ua = pa[i], ub = pb[i], uc = pc[i];
    float lo = b2f((unsigned short)ua) + b2f((unsigned short)ub) + b2f((unsigned short)uc);
    float hi = b2f((unsigned short)(ua >> 16)) + b2f((unsigned short)(ub >> 16))
             + b2f((unsigned short)(uc >> 16));
    po[i] = pack2(lo, hi);
  }
}

__global__ void hist_kernel(const int* __restrict__ s0, const int* __restrict__ s1,
                            int* __restrict__ cnt0, int* __restrict__ cnt1, int E_)
{
  int e = blockIdx.x * blockDim.x + threadIdx.x;
  if (e >= E_) return;
  atomicAdd(&cnt0[s0[e]], 1);
  atomicAdd(&cnt1[s1[e]], 1);
}

// coarsened single-block scan; grid.x = 2 directions; writes rowstart AND cursor copy
struct ScanArgs { const int* cnt[2]; int* row[2]; int* cur[2]; int n; };
__global__ __launch_bounds__(1024) void scan_kernel(ScanArgs sa)
{
  int d = blockIdx.x;
  const int* __restrict__ cnt = sa.cnt[d];
  int* __restrict__ row = sa.row[d];
  int* __restrict__ cur = sa.cur[d];
  const int n = sa.n;
  __shared__ int part[1024];
  int tid = threadIdx.x;
  const int CH = (n + 1023) / 1024;
  int b0 = min(tid * CH, n), b1 = min(b0 + CH, n);
  int s = 0;
  for (int i = b0; i < b1; ++i) s += cnt[i];
  part[tid] = s;
  __syncthreads();
  for (int off = 1; off < 1024; off <<= 1) {
    int t = (tid >= off) ? part[tid - off] : 0;
    __syncthreads();
    part[tid] += t;
    __syncthreads();
  }
  int pre = part[tid] - s;
  for (int i = b0; i < b1; ++i) {
    row[i] = pre; cur[i] = pre; pre += cnt[i];
  }
  if (tid == 1023) row[n] = part[1023];
}

// packed 8B CSR fill
__global__ void fill_kernel(const int* __restrict__ s0, const int* __restrict__ s1,
                            const float* __restrict__ ew,
                            int* __restrict__ cur0, int* __restrict__ cur1,
                            unsigned long long* __restrict__ comb0,
                            unsigned long long* __restrict__ comb1, int E_)
{
  int e = blockIdx.x * blockDim.x + threadIdx.x;
  if (e >= E_) return;
  int d0 = s0[e], d1 = s1[e];
  unsigned long long wb = (unsigned long long)__float_as_uint(ew[e]) << 32;
  int p0 = atomicAdd(&cur0[d0], 1);
  comb0[p0] = wb | (unsigned int)d1;
  int p1 = atomicAdd(&cur1[d1], 1);
  comb1[p1] = wb | (unsigned int)d0;
}

// merged dual-direction gather; wave per node; 8-deep MLP unroll
struct GArgs {
  const int* rowstart[2];
  const unsigned long long* comb[2];
  const unsigned short* h[2];
  unsigned short* xout[2];
  int n;
};
__global__ void gather_kernel(GArgs ga)
{
  int gw = blockIdx.x * (blockDim.x >> 6) + (threadIdx.x >> 6);
  int lane = threadIdx.x & 63;
  if (gw >= 2 * ga.n) return;
  int dir = (gw >= ga.n) ? 1 : 0;
  int node = gw - dir * ga.n;
  const int* __restrict__ rowstart = ga.rowstart[dir];
  const unsigned long long* __restrict__ comb = ga.comb[dir];
  const unsigned int* __restrict__ h = (const unsigned int*)ga.h[dir];
  int beg = rowstart[node], end = rowstart[node + 1];
  float a0 = 0.f, a1 = 0.f;
  if (beg < end) {
    for (int p = beg; p < end; p += 8) {
      unsigned long long cc[8];
      unsigned int uu[8];
#pragma unroll
      for (int i = 0; i < 8; ++i) {
        int pi = p + i;
        cc[i] = comb[pi < end ? pi : end - 1];
      }
#pragma unroll
      for (int i = 0; i < 8; ++i)
        uu[i] = h[(size_t)(unsigned int)cc[i] * 64 + lane];
#pragma unroll
      for (int i = 0; i < 8; ++i) {
        float wv = (p + i < end) ? __uint_as_float((unsigned int)(cc[i] >> 32)) : 0.f;
        a0 += wv * b2f((unsigned short)uu[i]);
        a1 += wv * b2f((unsigned short)(uu[i] >> 16));
      }
    }
  }
  float v0 = LRELU(a0), v1 = LRELU(a1);
  unsigned int* xo = (unsigned int*)(ga.xout[dir] + (size_t)node * 128);
  xo[lane] = pack2(v0, v1);
}

__global__ void segsum_kernel(const unsigned short* __restrict__ xc,
                              const int* __restrict__ batch,
                              const float* __restrict__ states,
                              float* __restrict__ gsel, float* __restrict__ gsum, int n)
{
  int f = threadIdx.x;
  int r0 = blockIdx.x * 256;
  int r1 = min(r0 + 256, n);
  float asel = 0.f, asum = 0.f;
  int cur = batch[r0];
  for (int r = r0; r < r1; ++r) {
    int b = batch[r];
    if (b != cur) {
      atomicAdd(&gsel[cur * 128 + f], asel);
      atomicAdd(&gsum[cur * 128 + f], asum);
      asel = asum = 0.f;
      cur = b;
    }
    float v = b2f(xc[(size_t)r * 128 + f]);
    asum += v;
    if (states[r] == 1.0f) asel += v;
  }
  atomicAdd(&gsel[cur * 128 + f], asel);
  atomicAdd(&gsum[cur * 128 + f], asum);
}

__global__ void small16_kernel(const float* __restrict__ gsel, const float* __restrict__ gsum,
                               const float* __restrict__ g1W, const float* __restrict__ g2W,
                               unsigned short* __restrict__ A16, unsigned short* __restrict__ B16)
{
  int r = blockIdx.x, t = threadIdx.x, o = t & 127;
  const float* src = (t < 128) ? gsel : gsum;
  const float* Wm  = (t < 128) ? g1W : g2W;
  float acc = 0.f;
  for (int k = 0; k < 128; ++k) acc += src[r * 128 + k] * Wm[o * 128 + k];
  unsigned short* dst = (t < 128) ? A16 : B16;
  dst[r * 128 + o] = f2b(acc);
}

extern "C" void kernel_launch(void* const* d_in, const int* in_sizes, int n_in,
                              void* d_out, int out_size, void* d_ws, size_t ws_size,
                              hipStream_t stream)
{
  const int N = 50000, F = 128, E = 800000, G = 16, T = 3;
  const float* x      = (const float*)d_in[0];
  const int*   ei     = (const int*)d_in[1];
  const int*   s0     = ei;
  const int*   s1     = ei + E;
  const float* ew     = (const float*)d_in[2];
  const int*   batch  = (const int*)d_in[3];
  const float* states = (const float*)d_in[4];
  const float* p_a0[2]   = {(const float*)d_in[5],  (const float*)d_in[10]};
  const float* p_a1W[2]  = {(const float*)d_in[6],  (const float*)d_in[11]};
  const float* p_a1b[2]  = {(const float*)d_in[7],  (const float*)d_in[12]};
  const float* p_linW[2] = {(const float*)d_in[8],  (const float*)d_in[13]};
  const float* p_linb[2] = {(const float*)d_in[9],  (const float*)d_in[14]};
  const float* beta0W = (const float*)d_in[15];
  const float* beta1W = (const float*)d_in[16];
  const float* beta2W = (const float*)d_in[17];
  const float* beta2b = (const float*)d_in[18];
  const float* g0W = (const float*)d_in[19];
  const float* g1W = (const float*)d_in[20];
  const float* g2W = (const float*)d_in[21];
  const float* g3W = (const float*)d_in[22];
  const float* g4W = (const float*)d_in[23];
  const float* g4b = (const float*)d_in[24];
  float* out = (float*)d_out;

  char* p = (char*)d_ws;
  auto alloc = [&](size_t bytes) {
    char* r = p;
    p += (bytes + 255) & ~(size_t)255;
    return r;
  };
  const size_t NFb2 = (size_t)N * F * sizeof(unsigned short);  // 12.8 MB
  // x-version rotation buffers (3 per direction)
  unsigned short* X1[3] = {(unsigned short*)alloc(NFb2), (unsigned short*)alloc(NFb2),
                           (unsigned short*)alloc(NFb2)};
  unsigned short* X2[3] = {(unsigned short*)alloc(NFb2), (unsigned short*)alloc(NFb2),
                           (unsigned short*)alloc(NFb2)};
  unsigned short* TMP0 = (unsigned short*)alloc(NFb2);
  unsigned short* TMP1 = (unsigned short*)alloc(NFb2);
  unsigned short* HH0  = (unsigned short*)alloc(NFb2);
  unsigned short* HH1  = (unsigned short*)alloc(NFb2);
  int*   row0 = (int*)alloc((size_t)(N + 1) * 4);
  int*   row1 = (int*)alloc((size_t)(N + 1) * 4);
  int*   cur0 = (int*)alloc((size_t)N * 4);
  int*   cur1 = (int*)alloc((size_t)N * 4);
  int*   cnt0 = (int*)alloc((size_t)N * 4);
  int*   cnt1 = (int*)alloc((size_t)N * 4);
  unsigned long long* comb0 = (unsigned long long*)alloc((size_t)E * 8);
  unsigned long long* comb1 = (unsigned long long*)alloc((size_t)E * 8);
  float* gsel = (float*)alloc((size_t)G * F * 4);
  float* gsum = (float*)alloc((size_t)G * F * 4);
  unsigned short* A16b = (unsigned short*)alloc((size_t)G * F * 2);
  unsigned short* B16b = (unsigned short*)alloc((size_t)G * F * 2);
  unsigned short* wreg = (unsigned short*)alloc((size_t)352256 * 2);
  float* rs = (float*)alloc((size_t)6 * 128 * 4);

  unsigned short* a1Wb[2]  = {wreg + 0,      wreg + 49152};
  unsigned short* linWb[2] = {wreg + 98304,  wreg + 147456};
  unsigned short* b0b = wreg + 196608;
  unsigned short* b1b = wreg + 212992;
  unsigned short* b2b = wreg + 229376;
  unsigned short* g0b = wreg + 262144;
  unsigned short* g3b = wreg + 278528;

  const dim3 blk256(256);
  const dim3 edge_grid((E + 255) / 256);
  const int GX = (N + 127) / 128;
  const int KBIG = 1 << 30;

  // ---- CSR build ----
  hipMemsetAsync(cnt0, 0, (size_t)N * 4, stream);
  hipMemsetAsync(cnt1, 0, (size_t)N * 4, stream);
  hist_kernel<<<edge_grid, blk256, 0, stream>>>(s0, s1, cnt0, cnt1, E);
  ScanArgs sa;
  sa.cnt[0] = cnt0; sa.cnt[1] = cnt1;
  sa.row[0] = row0; sa.row[1] = row1;
  sa.cur[0] = cur0; sa.cur[1] = cur1;
  sa.n = N;
  scan_kernel<<<2, 1024, 0, stream>>>(sa);
  fill_kernel<<<edge_grid, blk256, 0, stream>>>(s0, s1, ew, cur0, cur1, comb0, comb1, E);

  // ---- weight conversion + rowsums + init ----
  CJobs jb;
  jb.s[0] = p_a1W[0];  jb.d[0] = a1Wb[0];  jb.n[0] = 49152;
  jb.s[1] = p_a1W[1];  jb.d[1] = a1Wb[1];  jb.n[1] = 49152;
  jb.s[2] = p_linW[0]; jb.d[2] = linWb[0]; jb.n[2] = 49152;
  jb.s[3] = p_linW[1]; jb.d[3] = linWb[1]; jb.n[3] = 49152;
  jb.s[4] = beta0W;    jb.d[4] = b0b;      jb.n[4] = 16384;
  jb.s[5] = beta1W;    jb.d[5] = b1b;      jb.n[5] = 16384;
  jb.s[6] = beta2W;    jb.d[6] = b2b;      jb.n[6] = 32768;
  jb.s[7] = g0W;       jb.d[7] = g0b;      jb.n[7] = 16384;
  jb.s[8] = g3W;       jb.d[8] = g3b;      jb.n[8] = 73728;
  convert_kernel<<<dim3(36, 9), blk256, 0, stream>>>(jb);
  rowsum_kernel<<<6, 128, 0, stream>>>(p_a1W[0], p_a1W[1], rs);
  init_kernel<<<3125, blk256, 0, stream>>>(x, X1[0], X2[0], N);

  // ---- T-loop (x-version rotation: read t%3, write (t+1)%3) ----
  for (int t = 0; t < T; ++t) {
    int rv = t % 3, wv = (t + 1) % 3;

    BArgs g1;
    g1.A1[0] = X1[rv]; g1.A2[0] = X1[rv]; g1.A1[1] = X2[rv]; g1.A2[1] = X2[rv];
    g1.ldA1 = 128; g1.ldA2 = 128; g1.K1 = KBIG;
    g1.W[0] = a1Wb[0] + t * 16384; g1.W[1] = a1Wb[1] + t * 16384;
    g1.bias[0] = p_a1b[0] + t * F; g1.bias[1] = p_a1b[1] + t * F;
    g1.a0p[0] = p_a0[0] + t;       g1.a0p[1] = p_a0[1] + t;
    g1.rowsum[0] = rs + t * 128;   g1.rowsum[1] = rs + (3 + t) * 128;
    g1.C[0] = TMP0; g1.C[1] = TMP1;
    g1.states = states; g1.N = N; g1.K = 128;
    bgemm<128, 1, true, true><<<dim3(GX, 2), blk256, 0, stream>>>(g1);

    BArgs g2;
    g2.A1[0] = TMP0; g2.A2[0] = TMP0; g2.A1[1] = TMP1; g2.A2[1] = TMP1;
    g2.ldA1 = 128; g2.ldA2 = 128; g2.K1 = KBIG;
    g2.W[0] = linWb[0] + t * 16384; g2.W[1] = linWb[1] + t * 16384;
    g2.bias[0] = p_linb[0] + t * F; g2.bias[1] = p_linb[1] + t * F;
    g2.a0p[0] = nullptr; g2.a0p[1] = nullptr;
    g2.rowsum[0] = nullptr; g2.rowsum[1] = nullptr;
    g2.C[0] = HH0; g2.C[1] = HH1;
    g2.states = nullptr; g2.N = N; g2.K = 128;
    bgemm<128, 0, true, false><<<dim3(GX, 2), blk256, 0, stream>>>(g2);

    GArgs ga;
    ga.rowstart[0] = row0; ga.rowstart[1] = row1;
    ga.comb[0] = comb0;    ga.comb[1] = comb1;
    ga.h[0] = HH0;         ga.h[1] = HH1;
    ga.xout[0] = X1[wv];   ga.xout[1] = X2[wv];
    ga.n = N;
    gather_kernel<<<(2 * N + 3) / 4, blk256, 0, stream>>>(ga);
  }

  // ---- x1s/x2s = sum of the 3 versions ----
  S3Args s3;
  s3.a[0] = (const unsigned int*)X1[0]; s3.b[0] = (const unsigned int*)X1[1];
  s3.c[0] = (const unsigned int*)X1[2]; s3.o[0] = (unsigned int*)TMP0;
  s3.a[1] = (const unsigned int*)X2[0]; s3.b[1] = (const unsigned int*)X2[1];
  s3.c[1] = (const unsigned int*)X2[2]; s3.o[1] = (unsigned int*)TMP1;
  s3.n = N * 64;
  sum3_kernel<<<dim3(2048, 2), blk256, 0, stream>>>(s3);

  // ---- beta stage: u = x1s@b0^T, v = x2s@b1^T (pair), then xc ----
  BArgs bu;
  bu.A1[0] = TMP0; bu.A2[0] = TMP0; bu.A1[1] = TMP1; bu.A2[1] = TMP1;
  bu.ldA1 = 128; bu.ldA2 = 128; bu.K1 = KBIG;
  bu.W[0] = b0b; bu.W[1] = b1b;
  bu.bias[0] = nullptr; bu.bias[1] = nullptr;
  bu.a0p[0] = nullptr; bu.a0p[1] = nullptr;
  bu.rowsum[0] = nullptr; bu.rowsum[1] = nullptr;
  bu.C[0] = HH0; bu.C[1] = HH1;
  bu.states = nullptr; bu.N = N; bu.K = 128;
  bgemm<128, 0, false, false><<<dim3(GX, 2), blk256, 0, stream>>>(bu);

  BArgs b2a;
  b2a.A1[0] = HH0; b2a.A2[0] = HH1; b2a.A1[1] = nullptr; b2a.A2[1] = nullptr;
  b2a.ldA1 = 128; b2a.ldA2 = 128; b2a.K1 = 128;
  b2a.W[0] = b2b; b2a.W[1] = nullptr;
  b2a.bias[0] = beta2b; b2a.bias[1] = nullptr;
  b2a.a0p[0] = nullptr; b2a.a0p[1] = nullptr;
  b2a.rowsum[0] = nullptr; b2a.rowsum[1] = nullptr;
  b2a.C[0] = TMP0; b2a.C[1] = nullptr;
  b2a.states = nullptr; b2a.N = N; b2a.K = 256;
  bgemm<128, 1, true, false><<<dim3(GX, 1), blk256, 0, stream>>>(b2a);

  // ---- per-graph sums + 16-row GEMMs ----
  hipMemsetAsync(gsel, 0, (size_t)G * F * 4, stream);
  hipMemsetAsync(gsum, 0, (size_t)G * F * 4, stream);
  segsum_kernel<<<(N + 255) / 256, dim3(128), 0, stream>>>(TMP0, batch, states, gsel, gsum, N);
  small16_kernel<<<G, blk256, 0, stream>>>(gsel, gsum, g1W, g2W, A16b, B16b);

  // ---- gamma stage ----
  BArgs g0a;
  g0a.A1[0] = TMP0; g0a.A2[0] = TMP0; g0a.A1[1] = nullptr; g0a.A2[1] = nullptr;
  g0a.ldA1 = 128; g0a.ldA2 = 128; g0a.K1 = KBIG;
  g0a.W[0] = g0b; g0a.W[1] = nullptr;
  g0a.bias[0] = nullptr; g0a.bias[1] = nullptr;
  g0a.a0p[0] = nullptr; g0a.a0p[1] = nullptr;
  g0a.rowsum[0] = nullptr; g0a.rowsum[1] = nullptr;
  g0a.C[0] = TMP1; g0a.C[1] = nullptr;
  g0a.states = nullptr; g0a.N = N; g0a.K = 128;
  bgemm<128, 0, false, false><<<dim3(GX, 1), blk256, 0, stream>>>(g0a);

  g3_kernel<<<GX, blk256, 0, stream>>>(TMP1, A16b, B16b, batch, g3b, g4W, g4b, out, N);
}

// Round 5
// 666.821 us; speedup vs baseline: 2.7847x; 1.2808x over previous
//
#include <hip/hip_runtime.h>

typedef short s8v __attribute__((ext_vector_type(8)));
typedef float f32x4 __attribute__((ext_vector_type(4)));

#define LRELU(v) ((v) > 0.f ? (v) : 0.2f * (v))

constexpr int NBK = 391;   // (50000+127)/128 node buckets
constexpr int TILE = 8192; // edges per bin-pass block

__device__ __forceinline__ float b2f(unsigned short b) {
  return __uint_as_float(((unsigned int)b) << 16);
}
__device__ __forceinline__ unsigned short f2b(float f) {
  unsigned int x = __float_as_uint(f);
  x += 0x7fffu + ((x >> 16) & 1u);
  return (unsigned short)(x >> 16);
}
__device__ __forceinline__ unsigned int pack2(float lo, float hi) {
  return ((unsigned int)f2b(hi) << 16) | (unsigned int)f2b(lo);
}

// ---------------- batched bf16 MFMA GEMM ----------------
struct BArgs {
  const unsigned short* A1[2];
  const unsigned short* A2[2];
  int ldA1, ldA2, K1;
  const unsigned short* W[2];
  const float* bias[2];
  const float* a0p[2];
  const float* rowsum[2];
  unsigned short* C[2];
  const float* states;
  int N, K;
};

template<int FOUT, int ACT, bool HAS_BIAS, bool HAS_STATES>
__global__ __launch_bounds__(256) void bgemm(BArgs ba)
{
  constexpr int NF = FOUT / 16;
  __shared__ __align__(16) unsigned short Ws[FOUT * 128];
  const int d = blockIdx.y;
  const unsigned short* __restrict__ A1 = ba.A1[d];
  const unsigned short* __restrict__ A2 = ba.A2[d];
  const unsigned short* __restrict__ W  = ba.W[d];
  unsigned short* __restrict__ C = ba.C[d];
  const int N = ba.N, K = ba.K, K1 = ba.K1, ldA1 = ba.ldA1, ldA2 = ba.ldA2;

  const int tid = threadIdx.x;
  const int lane = tid & 63;
  const int w = tid >> 6;
  const int l15 = lane & 15;
  const int g = lane >> 4;
  const int m0 = blockIdx.x * 128;

  f32x4 zero4 = {0.f, 0.f, 0.f, 0.f};
  f32x4 acc[2][NF];
#pragma unroll
  for (int mf = 0; mf < 2; ++mf)
#pragma unroll
    for (int nf = 0; nf < NF; ++nf) acc[mf][nf] = zero4;

  for (int kk = 0; kk < K; kk += 128) {
#pragma unroll
    for (int j = 0; j < NF; ++j) {
      int idx = tid + j * 256;
      int o = idx >> 4, c = idx & 15;
      uint4 v = *(const uint4*)(W + (size_t)o * K + kk + c * 8);
      *(uint4*)&Ws[o * 128 + (c ^ (o & 15)) * 8] = v;
    }
    const unsigned short* Ap; int ldA, koff;
    if (kk < K1) { Ap = A1; ldA = ldA1; koff = kk; }
    else         { Ap = A2; ldA = ldA2; koff = kk - K1; }
    s8v a[2][4];
#pragma unroll
    for (int mf = 0; mf < 2; ++mf) {
      int row = m0 + w * 32 + mf * 16 + l15;
      const unsigned short* ar = Ap + (size_t)row * ldA + koff + g * 8;
#pragma unroll
      for (int ks = 0; ks < 4; ++ks) {
        s8v t = {};
        if (row < N) t = *(const s8v*)(ar + ks * 32);
        a[mf][ks] = t;
      }
    }
    __syncthreads();
#pragma unroll
    for (int ks = 0; ks < 4; ++ks) {
#pragma unroll
      for (int nf = 0; nf < NF; ++nf) {
        int c = ks * 4 + g;
        s8v b = *(const s8v*)&Ws[(nf * 16 + l15) * 128 + (c ^ l15) * 8];
        acc[0][nf] = __builtin_amdgcn_mfma_f32_16x16x32_bf16(a[0][ks], b, acc[0][nf], 0, 0, 0);
        acc[1][nf] = __builtin_amdgcn_mfma_f32_16x16x32_bf16(a[1][ks], b, acc[1][nf], 0, 0, 0);
      }
    }
    if (kk + 128 < K) __syncthreads();
  }

  const float a0 = HAS_STATES ? ba.a0p[d][0] : 0.f;
#pragma unroll
  for (int mf = 0; mf < 2; ++mf) {
#pragma unroll
    for (int r = 0; r < 4; ++r) {
      int row = m0 + w * 32 + mf * 16 + g * 4 + r;
      if (row >= N) continue;
      float sa = HAS_STATES ? ba.states[row] * a0 : 0.f;
      unsigned short* crow = C + (size_t)row * FOUT;
#pragma unroll
      for (int nf = 0; nf < NF; ++nf) {
        int col = nf * 16 + l15;
        float v = acc[mf][nf][r];
        if (HAS_BIAS) v += ba.bias[d][col];
        if (HAS_STATES) v += sa * ba.rowsum[d][col];
        if (ACT) v = LRELU(v);
        crow[col] = f2b(v);
      }
    }
  }
}

// ---------------- g3 GEMM: A = [wbuf | A16[batch] | B16[batch]], fused final dot ----------------
__global__ __launch_bounds__(256) void g3_kernel(
    const unsigned short* __restrict__ wbuf,
    const unsigned short* __restrict__ A16,
    const unsigned short* __restrict__ B16,
    const int* __restrict__ batch,
    const unsigned short* __restrict__ W,   // g3W bf16 [192][384]
    const float* __restrict__ g4W,          // [192]
    const float* __restrict__ g4b,
    float* __restrict__ out, int N)
{
  constexpr int NF = 12;
  __shared__ __align__(16) unsigned short Ws[192 * 128];
  const int tid = threadIdx.x;
  const int lane = tid & 63;
  const int w = tid >> 6;
  const int l15 = lane & 15;
  const int g = lane >> 4;
  const int m0 = blockIdx.x * 128;

  f32x4 zero4 = {0.f, 0.f, 0.f, 0.f};
  f32x4 acc[2][NF];
#pragma unroll
  for (int mf = 0; mf < 2; ++mf)
#pragma unroll
    for (int nf = 0; nf < NF; ++nf) acc[mf][nf] = zero4;

  int brow[2];
#pragma unroll
  for (int mf = 0; mf < 2; ++mf) {
    int row = m0 + w * 32 + mf * 16 + l15;
    brow[mf] = (row < N) ? batch[row] : 0;
  }

  for (int kk = 0; kk < 384; kk += 128) {
#pragma unroll
    for (int j = 0; j < NF; ++j) {
      int idx = tid + j * 256;
      int o = idx >> 4, c = idx & 15;
      uint4 v = *(const uint4*)(W + (size_t)o * 384 + kk + c * 8);
      *(uint4*)&Ws[o * 128 + (c ^ (o & 15)) * 8] = v;
    }
    s8v a[2][4];
#pragma unroll
    for (int mf = 0; mf < 2; ++mf) {
      int row = m0 + w * 32 + mf * 16 + l15;
      const unsigned short* ar;
      if (kk == 0)        ar = wbuf + (size_t)row * 128 + g * 8;
      else if (kk == 128) ar = A16 + (size_t)brow[mf] * 128 + g * 8;
      else                ar = B16 + (size_t)brow[mf] * 128 + g * 8;
#pragma unroll
      for (int ks = 0; ks < 4; ++ks) {
        s8v t = {};
        if (row < N) t = *(const s8v*)(ar + ks * 32);
        a[mf][ks] = t;
      }
    }
    __syncthreads();
#pragma unroll
    for (int ks = 0; ks < 4; ++ks) {
#pragma unroll
      for (int nf = 0; nf < NF; ++nf) {
        int c = ks * 4 + g;
        s8v b = *(const s8v*)&Ws[(nf * 16 + l15) * 128 + (c ^ l15) * 8];
        acc[0][nf] = __builtin_amdgcn_mfma_f32_16x16x32_bf16(a[0][ks], b, acc[0][nf], 0, 0, 0);
        acc[1][nf] = __builtin_amdgcn_mfma_f32_16x16x32_bf16(a[1][ks], b, acc[1][nf], 0, 0, 0);
      }
    }
    if (kk < 256) __syncthreads();
  }

  float w4[NF];
#pragma unroll
  for (int nf = 0; nf < NF; ++nf) w4[nf] = g4W[nf * 16 + l15];
  const float gb = g4b[0];

#pragma unroll
  for (int mf = 0; mf < 2; ++mf) {
#pragma unroll
    for (int r = 0; r < 4; ++r) {
      int row = m0 + w * 32 + mf * 16 + g * 4 + r;
      float dot = 0.f;
#pragma unroll
      for (int nf = 0; nf < NF; ++nf) {
        float v = acc[mf][nf][r];
        v = LRELU(v);
        dot += v * w4[nf];
      }
#pragma unroll
      for (int m = 1; m < 16; m <<= 1) dot += __shfl_xor(dot, m, 16);
      if (l15 == 0 && row < N) out[row] = dot + gb;
    }
  }
}

// ---------------- weight fp32 -> bf16 conversion ----------------
struct CJobs { const float* s[9]; unsigned short* d[9]; int n[9]; };
__global__ void convert_kernel(CJobs jb) {
  int j = blockIdx.y;
  int idx = (blockIdx.x * 256 + threadIdx.x) * 8;
  if (idx >= jb.n[j]) return;
  const float* s = jb.s[j] + idx;
  float4 p0 = *(const float4*)s;
  float4 p1 = *(const float4*)(s + 4);
  uint4 u;
  u.x = pack2(p0.x, p0.y); u.y = pack2(p0.z, p0.w);
  u.z = pack2(p1.x, p1.y); u.w = pack2(p1.z, p1.w);
  *(uint4*)(jb.d[j] + idx) = u;
}

__global__ void rowsum_kernel(const float* __restrict__ a1,
                              const float* __restrict__ a2, float* __restrict__ rs) {
  int j = blockIdx.x;
  const float* src = (j < 3) ? (a1 + (size_t)j * 16384) : (a2 + (size_t)(j - 3) * 16384);
  int o = threadIdx.x;
  float s = 0.f;
  for (int k = 0; k < 128; ++k) s += src[o * 128 + k];
  rs[j * 128 + o] = s;
}

// split x into x1/x2 (bf16)
__global__ void init_kernel(const float* __restrict__ x,
                            unsigned short* __restrict__ x1, unsigned short* __restrict__ x2,
                            int n)
{
  int idx = blockIdx.x * blockDim.x + threadIdx.x;
  int total = n * 16;
  for (; idx < total; idx += gridDim.x * blockDim.x) {
    int r = idx >> 4, c = idx & 15;
    const float* xr = x + (size_t)r * 256 + c * 8;
    float4 p0 = *(const float4*)xr;
    float4 p1 = *(const float4*)(xr + 4);
    uint4 u1;
    u1.x = pack2(p0.x, p0.y); u1.y = pack2(p0.z, p0.w);
    u1.z = pack2(p1.x, p1.y); u1.w = pack2(p1.z, p1.w);
    float4 q0 = *(const float4*)(xr + 128);
    float4 q1 = *(const float4*)(xr + 132);
    uint4 u2;
    u2.x = pack2(q0.x, q0.y); u2.y = pack2(q0.z, q0.w);
    u2.z = pack2(q1.x, q1.y); u2.w = pack2(q1.z, q1.w);
    ((uint4*)(x1 + (size_t)r * 128))[c] = u1;
    ((uint4*)(x2 + (size_t)r * 128))[c] = u2;
  }
}

// sum of three bf16 buffers (fp32 math), both directions via blockIdx.y
struct S3Args { const unsigned int* a[2]; const unsigned int* b[2]; const unsigned int* c[2];
                unsigned int* o[2]; int n; };
__global__ void sum3_kernel(S3Args s)
{
  int d = blockIdx.y;
  const unsigned int* __restrict__ pa = s.a[d];
  const unsigned int* __restrict__ pb = s.b[d];
  const unsigned int* __restrict__ pc = s.c[d];
  unsigned int* __restrict__ po = s.o[d];
  for (int i = blockIdx.x * 256 + threadIdx.x; i < s.n; i += gridDim.x * 256) {
    unsigned int ua = pa[i], ub = pb[i], uc = pc[i];
    float lo = b2f((unsigned short)ua) + b2f((unsigned short)ub) + b2f((unsigned short)uc);
    float hi = b2f((unsigned short)(ua >> 16)) + b2f((unsigned short)(ub >> 16))
             + b2f((unsigned short)(uc >> 16));
    po[i] = pack2(lo, hi);
  }
}

__global__ void hist_kernel(const int* __restrict__ s0, const int* __restrict__ s1,
                            int* __restrict__ cnt0, int* __restrict__ cnt1, int E_)
{
  int e = blockIdx.x * blockDim.x + threadIdx.x;
  if (e >= E_) return;
  atomicAdd(&cnt0[s0[e]], 1);
  atomicAdd(&cnt1[s1[e]], 1);
}

// coarsened single-block scan; grid.x = 2 directions; writes rowstart + per-bucket base cursors
struct ScanArgs { const int* cnt[2]; int* row[2]; int* bcur[2]; int n; };
__global__ __launch_bounds__(1024) void scan_kernel(ScanArgs sa)
{
  int d = blockIdx.x;
  const int* __restrict__ cnt = sa.cnt[d];
  int* __restrict__ row = sa.row[d];
  int* __restrict__ bcur = sa.bcur[d];
  const int n = sa.n;
  __shared__ int part[1024];
  int tid = threadIdx.x;
  const int CH = (n + 1023) / 1024;
  int b0 = min(tid * CH, n), b1 = min(b0 + CH, n);
  int s = 0;
  for (int i = b0; i < b1; ++i) s += cnt[i];
  part[tid] = s;
  __syncthreads();
  for (int off = 1; off < 1024; off <<= 1) {
    int t = (tid >= off) ? part[tid - off] : 0;
    __syncthreads();
    part[tid] += t;
    __syncthreads();
  }
  int pre = part[tid] - s;
  for (int i = b0; i < b1; ++i) {
    row[i] = pre;
    if ((i & 127) == 0) bcur[i >> 7] = pre;
    pre += cnt[i];
  }
  if (tid == 1023) row[n] = part[1023];
}

// ---------------- multi-split bin pass ----------------
// Per-block: LDS bucket hist -> reserve dense global chunks -> write 8B bin records
// record: [w fp32 | d_low7<<16 | other16]
struct BinArgs {
  const int* s0; const int* s1; const float* ew;
  int* bcur0; int* bcur1;
  unsigned long long* bin0; unsigned long long* bin1;
  int E;
};
__global__ __launch_bounds__(256) void bin_kernel(BinArgs ba)
{
  __shared__ int hist0[NBK], hist1[NBK];
  __shared__ int base0[NBK], base1[NBK];
  const int t = threadIdx.x;
  const int e0 = blockIdx.x * TILE;
  const int e1 = min(e0 + TILE, ba.E);
  for (int i = t; i < NBK; i += 256) { hist0[i] = 0; hist1[i] = 0; }
  __syncthreads();
  for (int e = e0 + t; e < e1; e += 256) {
    atomicAdd(&hist0[ba.s0[e] >> 7], 1);
    atomicAdd(&hist1[ba.s1[e] >> 7], 1);
  }
  __syncthreads();
  for (int i = t; i < NBK; i += 256) {
    int c0 = hist0[i];
    base0[i] = c0 ? atomicAdd(&ba.bcur0[i], c0) : 0;
    int c1 = hist1[i];
    base1[i] = c1 ? atomicAdd(&ba.bcur1[i], c1) : 0;
  }
  __syncthreads();
  for (int i = t; i < NBK; i += 256) { hist0[i] = 0; hist1[i] = 0; }
  __syncthreads();
  for (int e = e0 + t; e < e1; e += 256) {
    int d0 = ba.s0[e], d1 = ba.s1[e];
    unsigned long long wb = (unsigned long long)__float_as_uint(ba.ew[e]) << 32;
    int r0 = atomicAdd(&hist0[d0 >> 7], 1);
    ba.bin0[base0[d0 >> 7] + r0] = wb | (unsigned int)((d0 & 127) << 16) | (unsigned int)d1;
    int r1 = atomicAdd(&hist1[d1 >> 7], 1);
    ba.bin1[base1[d1 >> 7] + r1] = wb | (unsigned int)((d1 & 127) << 16) | (unsigned int)d0;
  }
}

// ---------------- reorder pass: bucket span -> per-node CSR slots, 4B records ----------------
struct RArgs {
  const int* row[2];
  const unsigned long long* bin[2];
  unsigned int* comb[2];
  int n;
};
__global__ __launch_bounds__(256) void reorder_kernel(RArgs ra)
{
  const int d = blockIdx.y;
  const int b = blockIdx.x;
  const int* __restrict__ row = ra.row[d];
  const unsigned long long* __restrict__ bin = ra.bin[d];
  unsigned int* __restrict__ comb = ra.comb[d];
  const int nb = b * 128;
  const int ne = min(nb + 128, ra.n);
  __shared__ int lcur[128];
  const int t = threadIdx.x;
  const int span_beg = row[nb];
  const int span_end = row[ne];
  if (t < ne - nb) lcur[t] = row[nb + t] - span_beg;
  __syncthreads();
  for (int i = span_beg + t; i < span_end; i += 256) {
    unsigned long long r = bin[i];
    unsigned int lo = (unsigned int)r;
    float w = __uint_as_float((unsigned int)(r >> 32));
    int nl = (lo >> 16) & 127;
    unsigned int other = lo & 0xffffu;
    int slot = atomicAdd(&lcur[nl], 1);
    comb[span_beg + slot] = other | ((unsigned int)f2b(w) << 16);
  }
}

// merged dual-direction gather; wave per node; 16-deep MLP unroll; 4B records
struct GArgs {
  const int* rowstart[2];
  const unsigned int* comb[2];
  const unsigned short* h[2];
  unsigned short* xout[2];
  int n;
};
__global__ void gather_kernel(GArgs ga)
{
  int gw = blockIdx.x * (blockDim.x >> 6) + (threadIdx.x >> 6);
  int lane = threadIdx.x & 63;
  if (gw >= 2 * ga.n) return;
  int dir = (gw >= ga.n) ? 1 : 0;
  int node = gw - dir * ga.n;
  const int* __restrict__ rowstart = ga.rowstart[dir];
  const unsigned int* __restrict__ comb = ga.comb[dir];
  const unsigned int* __restrict__ h = (const unsigned int*)ga.h[dir];
  int beg = rowstart[node], end = rowstart[node + 1];
  float a0 = 0.f, a1 = 0.f;
  for (int p = beg; p < end; p += 16) {
    unsigned int cc[16];
    unsigned int uu[16];
#pragma unroll
    for (int i = 0; i < 16; ++i) {
      int pi = p + i;
      cc[i] = (pi < end) ? comb[pi] : 0u;   // rec 0 -> node 0, weight +0.0f
    }
#pragma unroll
    for (int i = 0; i < 16; ++i)
      uu[i] = h[(size_t)(cc[i] & 0xffffu) * 64 + lane];
#pragma unroll
    for (int i = 0; i < 16; ++i) {
      float wv = b2f((unsigned short)(cc[i] >> 16));
      a0 += wv * b2f((unsigned short)uu[i]);
      a1 += wv * b2f((unsigned short)(uu[i] >> 16));
    }
  }
  float v0 = LRELU(a0), v1 = LRELU(a1);
  unsigned int* xo = (unsigned int*)(ga.xout[dir] + (size_t)node * 128);
  xo[lane] = pack2(v0, v1);
}

__global__ void segsum_kernel(const unsigned short* __restrict__ xc,
                              const int* __restrict__ batch,
                              const float* __restrict__ states,
                              float* __restrict__ gsel, float* __restrict__ gsum, int n)
{
  int f = threadIdx.x;
  int r0 = blockIdx.x * 256;
  int r1 = min(r0 + 256, n);
  float asel = 0.f, asum = 0.f;
  int cur = batch[r0];
  for (int r = r0; r < r1; ++r) {
    int b = batch[r];
    if (b != cur) {
      atomicAdd(&gsel[cur * 128 + f], asel);
      atomicAdd(&gsum[cur * 128 + f], asum);
      asel = asum = 0.f;
      cur = b;
    }
    float v = b2f(xc[(size_t)r * 128 + f]);
    asum += v;
    if (states[r] == 1.0f) asel += v;
  }
  atomicAdd(&gsel[cur * 128 + f], asel);
  atomicAdd(&gsum[cur * 128 + f], asum);
}

__global__ void small16_kernel(const float* __restrict__ gsel, const float* __restrict__ gsum,
                               const float* __restrict__ g1W, const float* __restrict__ g2W,
                               unsigned short* __restrict__ A16, unsigned short* __restrict__ B16)
{
  int r = blockIdx.x, t = threadIdx.x, o = t & 127;
  const float* src = (t < 128) ? gsel : gsum;
  const float* Wm  = (t < 128) ? g1W : g2W;
  float acc = 0.f;
  for (int k = 0; k < 128; ++k) acc += src[r * 128 + k] * Wm[o * 128 + k];
  unsigned short* dst = (t < 128) ? A16 : B16;
  dst[r * 128 + o] = f2b(acc);
}

extern "C" void kernel_launch(void* const* d_in, const int* in_sizes, int n_in,
                              void* d_out, int out_size, void* d_ws, size_t ws_size,
                              hipStream_t stream)
{
  const int N = 50000, F = 128, E = 800000, G = 16, T = 3;
  const float* x      = (const float*)d_in[0];
  const int*   ei     = (const int*)d_in[1];
  const int*   s0     = ei;
  const int*   s1     = ei + E;
  const float* ew     = (const float*)d_in[2];
  const int*   batch  = (const int*)d_in[3];
  const float* states = (const float*)d_in[4];
  const float* p_a0[2]   = {(const float*)d_in[5],  (const float*)d_in[10]};
  const float* p_a1W[2]  = {(const float*)d_in[6],  (const float*)d_in[11]};
  const float* p_a1b[2]  = {(const float*)d_in[7],  (const float*)d_in[12]};
  const float* p_linW[2] = {(const float*)d_in[8],  (const float*)d_in[13]};
  const float* p_linb[2] = {(const float*)d_in[9],  (const float*)d_in[14]};
  const float* beta0W = (const float*)d_in[15];
  const float* beta1W = (const float*)d_in[16];
  const float* beta2W = (const float*)d_in[17];
  const float* beta2b = (const float*)d_in[18];
  const float* g0W = (const float*)d_in[19];
  const float* g1W = (const float*)d_in[20];
  const float* g2W = (const float*)d_in[21];
  const float* g3W = (const float*)d_in[22];
  const float* g4W = (const float*)d_in[23];
  const float* g4b = (const float*)d_in[24];
  float* out = (float*)d_out;

  char* p = (char*)d_ws;
  auto alloc = [&](size_t bytes) {
    char* r = p;
    p += (bytes + 255) & ~(size_t)255;
    return r;
  };
  const size_t NFb2 = (size_t)N * F * sizeof(unsigned short);  // 12.8 MB
  unsigned short* X1[3] = {(unsigned short*)alloc(NFb2), (unsigned short*)alloc(NFb2),
                           (unsigned short*)alloc(NFb2)};
  unsigned short* X2[3] = {(unsigned short*)alloc(NFb2), (unsigned short*)alloc(NFb2),
                           (unsigned short*)alloc(NFb2)};
  unsigned short* TMP0 = (unsigned short*)alloc(NFb2);
  unsigned short* TMP1 = (unsigned short*)alloc(NFb2);
  unsigned short* HH0  = (unsigned short*)alloc(NFb2);
  unsigned short* HH1  = (unsigned short*)alloc(NFb2);
  int*   row0 = (int*)alloc((size_t)(N + 1) * 4);
  int*   row1 = (int*)alloc((size_t)(N + 1) * 4);
  int*   cnt0 = (int*)alloc((size_t)N * 4);
  int*   cnt1 = (int*)alloc((size_t)N * 4);
  int*   bcur0 = (int*)alloc((size_t)NBK * 4);
  int*   bcur1 = (int*)alloc((size_t)NBK * 4);
  unsigned long long* bin0 = (unsigned long long*)alloc((size_t)E * 8);
  unsigned long long* bin1 = (unsigned long long*)alloc((size_t)E * 8);
  unsigned int* comb0 = (unsigned int*)alloc((size_t)E * 4);
  unsigned int* comb1 = (unsigned int*)alloc((size_t)E * 4);
  float* gsel = (float*)alloc((size_t)G * F * 4);
  float* gsum = (float*)alloc((size_t)G * F * 4);
  unsigned short* A16b = (unsigned short*)alloc((size_t)G * F * 2);
  unsigned short* B16b = (unsigned short*)alloc((size_t)G * F * 2);
  unsigned short* wreg = (unsigned short*)alloc((size_t)352256 * 2);
  float* rs = (float*)alloc((size_t)6 * 128 * 4);

  unsigned short* a1Wb[2]  = {wreg + 0,      wreg + 49152};
  unsigned short* linWb[2] = {wreg + 98304,  wreg + 147456};
  unsigned short* b0b = wreg + 196608;
  unsigned short* b1b = wreg + 212992;
  unsigned short* b2b = wreg + 229376;
  unsigned short* g0b = wreg + 262144;
  unsigned short* g3b = wreg + 278528;

  const dim3 blk256(256);
  const dim3 edge_grid((E + 255) / 256);
  const int GX = (N + 127) / 128;
  const int KBIG = 1 << 30;

  // ---- CSR build (hist -> scan -> bin -> reorder) ----
  hipMemsetAsync(cnt0, 0, (size_t)N * 4, stream);
  hipMemsetAsync(cnt1, 0, (size_t)N * 4, stream);
  hist_kernel<<<edge_grid, blk256, 0, stream>>>(s0, s1, cnt0, cnt1, E);
  ScanArgs sa;
  sa.cnt[0] = cnt0; sa.cnt[1] = cnt1;
  sa.row[0] = row0; sa.row[1] = row1;
  sa.bcur[0] = bcur0; sa.bcur[1] = bcur1;
  sa.n = N;
  scan_kernel<<<2, 1024, 0, stream>>>(sa);
  BinArgs bna;
  bna.s0 = s0; bna.s1 = s1; bna.ew = ew;
  bna.bcur0 = bcur0; bna.bcur1 = bcur1;
  bna.bin0 = bin0; bna.bin1 = bin1;
  bna.E = E;
  bin_kernel<<<(E + TILE - 1) / TILE, blk256, 0, stream>>>(bna);
  RArgs ra;
  ra.row[0] = row0; ra.row[1] = row1;
  ra.bin[0] = bin0; ra.bin[1] = bin1;
  ra.comb[0] = comb0; ra.comb[1] = comb1;
  ra.n = N;
  reorder_kernel<<<dim3(NBK, 2), blk256, 0, stream>>>(ra);

  // ---- weight conversion + rowsums + init ----
  CJobs jb;
  jb.s[0] = p_a1W[0];  jb.d[0] = a1Wb[0];  jb.n[0] = 49152;
  jb.s[1] = p_a1W[1];  jb.d[1] = a1Wb[1];  jb.n[1] = 49152;
  jb.s[2] = p_linW[0]; jb.d[2] = linWb[0]; jb.n[2] = 49152;
  jb.s[3] = p_linW[1]; jb.d[3] = linWb[1]; jb.n[3] = 49152;
  jb.s[4] = beta0W;    jb.d[4] = b0b;      jb.n[4] = 16384;
  jb.s[5] = beta1W;    jb.d[5] = b1b;      jb.n[5] = 16384;
  jb.s[6] = beta2W;    jb.d[6] = b2b;      jb.n[6] = 32768;
  jb.s[7] = g0W;       jb.d[7] = g0b;      jb.n[7] = 16384;
  jb.s[8] = g3W;       jb.d[8] = g3b;      jb.n[8] = 73728;
  convert_kernel<<<dim3(36, 9), blk256, 0, stream>>>(jb);
  rowsum_kernel<<<6, 128, 0, stream>>>(p_a1W[0], p_a1W[1], rs);
  init_kernel<<<3125, blk256, 0, stream>>>(x, X1[0], X2[0], N);

  // ---- T-loop (x-version rotation: read t%3, write (t+1)%3) ----
  for (int t = 0; t < T; ++t) {
    int rv = t % 3, wv = (t + 1) % 3;

    BArgs g1;
    g1.A1[0] = X1[rv]; g1.A2[0] = X1[rv]; g1.A1[1] = X2[rv]; g1.A2[1] = X2[rv];
    g1.ldA1 = 128; g1.ldA2 = 128; g1.K1 = KBIG;
    g1.W[0] = a1Wb[0] + t * 16384; g1.W[1] = a1Wb[1] + t * 16384;
    g1.bias[0] = p_a1b[0] + t * F; g1.bias[1] = p_a1b[1] + t * F;
    g1.a0p[0] = p_a0[0] + t;       g1.a0p[1] = p_a0[1] + t;
    g1.rowsum[0] = rs + t * 128;   g1.rowsum[1] = rs + (3 + t) * 128;
    g1.C[0] = TMP0; g1.C[1] = TMP1;
    g1.states = states; g1.N = N; g1.K = 128;
    bgemm<128, 1, true, true><<<dim3(GX, 2), blk256, 0, stream>>>(g1);

    BArgs g2;
    g2.A1[0] = TMP0; g2.A2[0] = TMP0; g2.A1[1] = TMP1; g2.A2[1] = TMP1;
    g2.ldA1 = 128; g2.ldA2 = 128; g2.K1 = KBIG;
    g2.W[0] = linWb[0] + t * 16384; g2.W[1] = linWb[1] + t * 16384;
    g2.bias[0] = p_linb[0] + t * F; g2.bias[1] = p_linb[1] + t * F;
    g2.a0p[0] = nullptr; g2.a0p[1] = nullptr;
    g2.rowsum[0] = nullptr; g2.rowsum[1] = nullptr;
    g2.C[0] = HH0; g2.C[1] = HH1;
    g2.states = nullptr; g2.N = N; g2.K = 128;
    bgemm<128, 0, true, false><<<dim3(GX, 2), blk256, 0, stream>>>(g2);

    GArgs ga;
    ga.rowstart[0] = row0; ga.rowstart[1] = row1;
    ga.comb[0] = comb0;    ga.comb[1] = comb1;
    ga.h[0] = HH0;         ga.h[1] = HH1;
    ga.xout[0] = X1[wv];   ga.xout[1] = X2[wv];
    ga.n = N;
    gather_kernel<<<(2 * N + 3) / 4, blk256, 0, stream>>>(ga);
  }

  // ---- x1s/x2s = sum of the 3 versions ----
  S3Args s3;
  s3.a[0] = (const unsigned int*)X1[0]; s3.b[0] = (const unsigned int*)X1[1];
  s3.c[0] = (const unsigned int*)X1[2]; s3.o[0] = (unsigned int*)TMP0;
  s3.a[1] = (const unsigned int*)X2[0]; s3.b[1] = (const unsigned int*)X2[1];
  s3.c[1] = (const unsigned int*)X2[2]; s3.o[1] = (unsigned int*)TMP1;
  s3.n = N * 64;
  sum3_kernel<<<dim3(2048, 2), blk256, 0, stream>>>(s3);

  // ---- beta stage: u = x1s@b0^T, v = x2s@b1^T (pair), then xc ----
  BArgs bu;
  bu.A1[0] = TMP0; bu.A2[0] = TMP0; bu.A1[1] = TMP1; bu.A2[1] = TMP1;
  bu.ldA1 = 128; bu.ldA2 = 128; bu.K1 = KBIG;
  bu.W[0] = b0b; bu.W[1] = b1b;
  bu.bias[0] = nullptr; bu.bias[1] = nullptr;
  bu.a0p[0] = nullptr; bu.a0p[1] = nullptr;
  bu.rowsum[0] = nullptr; bu.rowsum[1] = nullptr;
  bu.C[0] = HH0; bu.C[1] = HH1;
  bu.states = nullptr; bu.N = N; bu.K = 128;
  bgemm<128, 0, false, false><<<dim3(GX, 2), blk256, 0, stream>>>(bu);

  BArgs b2a;
  b2a.A1[0] = HH0; b2a.A2[0] = HH1; b2a.A1[1] = nullptr; b2a.A2[1] = nullptr;
  b2a.ldA1 = 128; b2a.ldA2 = 128; b2a.K1 = 128;
  b2a.W[0] = b2b; b2a.W[1] = nullptr;
  b2a.bias[0] = beta2b; b2a.bias[1] = nullptr;
  b2a.a0p[0] = nullptr; b2a.a0p[1] = nullptr;
  b2a.rowsum[0] = nullptr; b2a.rowsum[1] = nullptr;
  b2a.C[0] = TMP0; b2a.C[1] = nullptr;
  b2a.states = nullptr; b2a.N = N; b2a.K = 256;
  bgemm<128, 1, true, false><<<dim3(GX, 1), blk256, 0, stream>>>(b2a);

  // ---- per-graph sums + 16-row GEMMs ----
  hipMemsetAsync(gsel, 0, (size_t)G * F * 4, stream);
  hipMemsetAsync(gsum, 0, (size_t)G * F * 4, stream);
  segsum_kernel<<<(N + 255) / 256, dim3(128), 0, stream>>>(TMP0, batch, states, gsel, gsum, N);
  small16_kernel<<<G, blk256, 0, stream>>>(gsel, gsum, g1W, g2W, A16b, B16b);

  // ---- gamma stage ----
  BArgs g0a;
  g0a.A1[0] = TMP0; g0a.A2[0] = TMP0; g0a.A1[1] = nullptr; g0a.A2[1] = nullptr;
  g0a.ldA1 = 128; g0a.ldA2 = 128; g0a.K1 = KBIG;
  g0a.W[0] = g0b; g0a.W[1] = nullptr;
  g0a.bias[0] = nullptr; g0a.bias[1] = nullptr;
  g0a.a0p[0] = nullptr; g0a.a0p[1] = nullptr;
  g0a.rowsum[0] = nullptr; g0a.rowsum[1] = nullptr;
  g0a.C[0] = TMP1; g0a.C[1] = nullptr;
  g0a.states = nullptr; g0a.N = N; g0a.K = 128;
  bgemm<128, 0, false, false><<<dim3(GX, 1), blk256, 0, stream>>>(g0a);

  g3_kernel<<<GX, blk256, 0, stream>>>(TMP1, A16b, B16b, batch, g3b, g4W, g4b, out, N);
}

// Round 6
// 596.222 us; speedup vs baseline: 3.1145x; 1.1184x over previous
//
#include <hip/hip_runtime.h>

typedef short s8v __attribute__((ext_vector_type(8)));
typedef float f32x4 __attribute__((ext_vector_type(4)));

#define LRELU(v) ((v) > 0.f ? (v) : 0.2f * (v))

constexpr int NBK = 391;   // (50000+127)/128 node buckets
constexpr int TILE = 8192; // edges per bin-pass block
constexpr int SCB = 2048;  // elements per scan block
constexpr int NSB = (50000 + SCB - 1) / SCB;  // 25

__device__ __forceinline__ float b2f(unsigned short b) {
  return __uint_as_float(((unsigned int)b) << 16);
}
__device__ __forceinline__ unsigned short f2b(float f) {
  unsigned int x = __float_as_uint(f);
  x += 0x7fffu + ((x >> 16) & 1u);
  return (unsigned short)(x >> 16);
}
__device__ __forceinline__ unsigned int pack2(float lo, float hi) {
  return ((unsigned int)f2b(hi) << 16) | (unsigned int)f2b(lo);
}

// ---------------- batched bf16 MFMA GEMM ----------------
struct BArgs {
  const unsigned short* A1[2];
  const unsigned short* A2[2];
  int ldA1, ldA2, K1;
  const unsigned short* W[2];
  const float* bias[2];
  const float* a0p[2];
  const float* rowsum[2];
  unsigned short* C[2];
  const float* states;
  int N, K;
};

template<int FOUT, int ACT, bool HAS_BIAS, bool HAS_STATES>
__global__ __launch_bounds__(256) void bgemm(BArgs ba)
{
  constexpr int NF = FOUT / 16;
  __shared__ __align__(16) unsigned short Ws[FOUT * 128];
  const int d = blockIdx.y;
  const unsigned short* __restrict__ A1 = ba.A1[d];
  const unsigned short* __restrict__ A2 = ba.A2[d];
  const unsigned short* __restrict__ W  = ba.W[d];
  unsigned short* __restrict__ C = ba.C[d];
  const int N = ba.N, K = ba.K, K1 = ba.K1, ldA1 = ba.ldA1, ldA2 = ba.ldA2;

  const int tid = threadIdx.x;
  const int lane = tid & 63;
  const int w = tid >> 6;
  const int l15 = lane & 15;
  const int g = lane >> 4;
  const int m0 = blockIdx.x * 128;

  f32x4 zero4 = {0.f, 0.f, 0.f, 0.f};
  f32x4 acc[2][NF];
#pragma unroll
  for (int mf = 0; mf < 2; ++mf)
#pragma unroll
    for (int nf = 0; nf < NF; ++nf) acc[mf][nf] = zero4;

  for (int kk = 0; kk < K; kk += 128) {
#pragma unroll
    for (int j = 0; j < NF; ++j) {
      int idx = tid + j * 256;
      int o = idx >> 4, c = idx & 15;
      uint4 v = *(const uint4*)(W + (size_t)o * K + kk + c * 8);
      *(uint4*)&Ws[o * 128 + (c ^ (o & 15)) * 8] = v;
    }
    const unsigned short* Ap; int ldA, koff;
    if (kk < K1) { Ap = A1; ldA = ldA1; koff = kk; }
    else         { Ap = A2; ldA = ldA2; koff = kk - K1; }
    s8v a[2][4];
#pragma unroll
    for (int mf = 0; mf < 2; ++mf) {
      int row = m0 + w * 32 + mf * 16 + l15;
      const unsigned short* ar = Ap + (size_t)row * ldA + koff + g * 8;
#pragma unroll
      for (int ks = 0; ks < 4; ++ks) {
        s8v t = {};
        if (row < N) t = *(const s8v*)(ar + ks * 32);
        a[mf][ks] = t;
      }
    }
    __syncthreads();
#pragma unroll
    for (int ks = 0; ks < 4; ++ks) {
#pragma unroll
      for (int nf = 0; nf < NF; ++nf) {
        int c = ks * 4 + g;
        s8v b = *(const s8v*)&Ws[(nf * 16 + l15) * 128 + (c ^ l15) * 8];
        acc[0][nf] = __builtin_amdgcn_mfma_f32_16x16x32_bf16(a[0][ks], b, acc[0][nf], 0, 0, 0);
        acc[1][nf] = __builtin_amdgcn_mfma_f32_16x16x32_bf16(a[1][ks], b, acc[1][nf], 0, 0, 0);
      }
    }
    if (kk + 128 < K) __syncthreads();
  }

  const float a0 = HAS_STATES ? ba.a0p[d][0] : 0.f;
#pragma unroll
  for (int mf = 0; mf < 2; ++mf) {
#pragma unroll
    for (int r = 0; r < 4; ++r) {
      int row = m0 + w * 32 + mf * 16 + g * 4 + r;
      if (row >= N) continue;
      float sa = HAS_STATES ? ba.states[row] * a0 : 0.f;
      unsigned short* crow = C + (size_t)row * FOUT;
#pragma unroll
      for (int nf = 0; nf < NF; ++nf) {
        int col = nf * 16 + l15;
        float v = acc[mf][nf][r];
        if (HAS_BIAS) v += ba.bias[d][col];
        if (HAS_STATES) v += sa * ba.rowsum[d][col];
        if (ACT) v = LRELU(v);
        crow[col] = f2b(v);
      }
    }
  }
}

// ---------------- g3 GEMM: A = [wbuf | A16[batch] | B16[batch]], fused final dot ----------------
__global__ __launch_bounds__(256) void g3_kernel(
    const unsigned short* __restrict__ wbuf,
    const unsigned short* __restrict__ A16,
    const unsigned short* __restrict__ B16,
    const int* __restrict__ batch,
    const unsigned short* __restrict__ W,   // g3W bf16 [192][384]
    const float* __restrict__ g4W,          // [192]
    const float* __restrict__ g4b,
    float* __restrict__ out, int N)
{
  constexpr int NF = 12;
  __shared__ __align__(16) unsigned short Ws[192 * 128];
  const int tid = threadIdx.x;
  const int lane = tid & 63;
  const int w = tid >> 6;
  const int l15 = lane & 15;
  const int g = lane >> 4;
  const int m0 = blockIdx.x * 128;

  f32x4 zero4 = {0.f, 0.f, 0.f, 0.f};
  f32x4 acc[2][NF];
#pragma unroll
  for (int mf = 0; mf < 2; ++mf)
#pragma unroll
    for (int nf = 0; nf < NF; ++nf) acc[mf][nf] = zero4;

  int brow[2];
#pragma unroll
  for (int mf = 0; mf < 2; ++mf) {
    int row = m0 + w * 32 + mf * 16 + l15;
    brow[mf] = (row < N) ? batch[row] : 0;
  }

  for (int kk = 0; kk < 384; kk += 128) {
#pragma unroll
    for (int j = 0; j < NF; ++j) {
      int idx = tid + j * 256;
      int o = idx >> 4, c = idx & 15;
      uint4 v = *(const uint4*)(W + (size_t)o * 384 + kk + c * 8);
      *(uint4*)&Ws[o * 128 + (c ^ (o & 15)) * 8] = v;
    }
    s8v a[2][4];
#pragma unroll
    for (int mf = 0; mf < 2; ++mf) {
      int row = m0 + w * 32 + mf * 16 + l15;
      const unsigned short* ar;
      if (kk == 0)        ar = wbuf + (size_t)row * 128 + g * 8;
      else if (kk == 128) ar = A16 + (size_t)brow[mf] * 128 + g * 8;
      else                ar = B16 + (size_t)brow[mf] * 128 + g * 8;
#pragma unroll
      for (int ks = 0; ks < 4; ++ks) {
        s8v t = {};
        if (row < N) t = *(const s8v*)(ar + ks * 32);
        a[mf][ks] = t;
      }
    }
    __syncthreads();
#pragma unroll
    for (int ks = 0; ks < 4; ++ks) {
#pragma unroll
      for (int nf = 0; nf < NF; ++nf) {
        int c = ks * 4 + g;
        s8v b = *(const s8v*)&Ws[(nf * 16 + l15) * 128 + (c ^ l15) * 8];
        acc[0][nf] = __builtin_amdgcn_mfma_f32_16x16x32_bf16(a[0][ks], b, acc[0][nf], 0, 0, 0);
        acc[1][nf] = __builtin_amdgcn_mfma_f32_16x16x32_bf16(a[1][ks], b, acc[1][nf], 0, 0, 0);
      }
    }
    if (kk < 256) __syncthreads();
  }

  float w4[NF];
#pragma unroll
  for (int nf = 0; nf < NF; ++nf) w4[nf] = g4W[nf * 16 + l15];
  const float gb = g4b[0];

#pragma unroll
  for (int mf = 0; mf < 2; ++mf) {
#pragma unroll
    for (int r = 0; r < 4; ++r) {
      int row = m0 + w * 32 + mf * 16 + g * 4 + r;
      float dot = 0.f;
#pragma unroll
      for (int nf = 0; nf < NF; ++nf) {
        float v = acc[mf][nf][r];
        v = LRELU(v);
        dot += v * w4[nf];
      }
#pragma unroll
      for (int m = 1; m < 16; m <<= 1) dot += __shfl_xor(dot, m, 16);
      if (l15 == 0 && row < N) out[row] = dot + gb;
    }
  }
}

// ---------------- weight fp32 -> bf16 conversion ----------------
struct CJobs { const float* s[9]; unsigned short* d[9]; int n[9]; };
__global__ void convert_kernel(CJobs jb) {
  int j = blockIdx.y;
  int idx = (blockIdx.x * 256 + threadIdx.x) * 8;
  if (idx >= jb.n[j]) return;
  const float* s = jb.s[j] + idx;
  float4 p0 = *(const float4*)s;
  float4 p1 = *(const float4*)(s + 4);
  uint4 u;
  u.x = pack2(p0.x, p0.y); u.y = pack2(p0.z, p0.w);
  u.z = pack2(p1.x, p1.y); u.w = pack2(p1.z, p1.w);
  *(uint4*)(jb.d[j] + idx) = u;
}

__global__ void rowsum_kernel(const float* __restrict__ a1,
                              const float* __restrict__ a2, float* __restrict__ rs) {
  int j = blockIdx.x;
  const float* src = (j < 3) ? (a1 + (size_t)j * 16384) : (a2 + (size_t)(j - 3) * 16384);
  int o = threadIdx.x;
  float s = 0.f;
  for (int k = 0; k < 128; ++k) s += src[o * 128 + k];
  rs[j * 128 + o] = s;
}

// split x into x1/x2 (bf16)
__global__ void init_kernel(const float* __restrict__ x,
                            unsigned short* __restrict__ x1, unsigned short* __restrict__ x2,
                            int n)
{
  int idx = blockIdx.x * blockDim.x + threadIdx.x;
  int total = n * 16;
  for (; idx < total; idx += gridDim.x * blockDim.x) {
    int r = idx >> 4, c = idx & 15;
    const float* xr = x + (size_t)r * 256 + c * 8;
    float4 p0 = *(const float4*)xr;
    float4 p1 = *(const float4*)(xr + 4);
    uint4 u1;
    u1.x = pack2(p0.x, p0.y); u1.y = pack2(p0.z, p0.w);
    u1.z = pack2(p1.x, p1.y); u1.w = pack2(p1.z, p1.w);
    float4 q0 = *(const float4*)(xr + 128);
    float4 q1 = *(const float4*)(xr + 132);
    uint4 u2;
    u2.x = pack2(q0.x, q0.y); u2.y = pack2(q0.z, q0.w);
    u2.z = pack2(q1.x, q1.y); u2.w = pack2(q1.z, q1.w);
    ((uint4*)(x1 + (size_t)r * 128))[c] = u1;
    ((uint4*)(x2 + (size_t)r * 128))[c] = u2;
  }
}

// sum of three bf16 buffers (fp32 math), both directions via blockIdx.y
struct S3Args { const unsigned int* a[2]; const unsigned int* b[2]; const unsigned int* c[2];
                unsigned int* o[2]; int n; };
__global__ void sum3_kernel(S3Args s)
{
  int d = blockIdx.y;
  const unsigned int* __restrict__ pa = s.a[d];
  const unsigned int* __restrict__ pb = s.b[d];
  const unsigned int* __restrict__ pc = s.c[d];
  unsigned int* __restrict__ po = s.o[d];
  for (int i = blockIdx.x * 256 + threadIdx.x; i < s.n; i += gridDim.x * 256) {
    unsigned int ua = pa[i], ub = pb[i], uc = pc[i];
    float lo = b2f((unsigned short)ua) + b2f((unsigned short)ub) + b2f((unsigned short)uc);
    float hi = b2f((unsigned short)(ua >> 16)) + b2f((unsigned short)(ub >> 16))
             + b2f((unsigned short)(uc >> 16));
    po[i] = pack2(lo, hi);
  }
}

__global__ void hist_kernel(const int* __restrict__ s0, const int* __restrict__ s1,
                            int* __restrict__ cnt0, int* __restrict__ cnt1, int E_)
{
  int e = blockIdx.x * blockDim.x + threadIdx.x;
  if (e >= E_) return;
  atomicAdd(&cnt0[s0[e]], 1);
  atomicAdd(&cnt1[s1[e]], 1);
}

// ---------------- 3-phase parallel exclusive scan ----------------
struct Scan1Args { const int* cnt[2]; int* bsum; int n; };
__global__ __launch_bounds__(256) void scan1_kernel(Scan1Args a)
{
  int d = blockIdx.y, b = blockIdx.x, t = threadIdx.x;
  const int* __restrict__ cnt = a.cnt[d];
  int i0 = b * SCB + t * 8;
  int s = 0;
#pragma unroll
  for (int i = 0; i < 8; ++i) {
    int idx = i0 + i;
    if (idx < a.n) s += cnt[idx];
  }
  __shared__ int red[256];
  red[t] = s;
  __syncthreads();
  for (int off = 128; off; off >>= 1) {
    if (t < off) red[t] += red[t + off];
    __syncthreads();
  }
  if (t == 0) a.bsum[d * NSB + b] = red[0];
}

__global__ void scan2_kernel(int* __restrict__ bsum)
{
  int d = threadIdx.x;
  if (d < 2) {
    int acc = 0;
    for (int b = 0; b < NSB; ++b) {
      int v = bsum[d * NSB + b];
      bsum[d * NSB + b] = acc;
      acc += v;
    }
  }
}

struct Scan3Args { const int* cnt[2]; const int* bsum; int* row[2]; int* bcur[2]; int n; };
__global__ __launch_bounds__(256) void scan3_kernel(Scan3Args a)
{
  int d = blockIdx.y, b = blockIdx.x, t = threadIdx.x;
  const int* __restrict__ cnt = a.cnt[d];
  int* __restrict__ row = a.row[d];
  int* __restrict__ bcur = a.bcur[d];
  int i0 = b * SCB + t * 8;
  int v[8];
  int s = 0;
#pragma unroll
  for (int i = 0; i < 8; ++i) {
    int idx = i0 + i;
    v[i] = (idx < a.n) ? cnt[idx] : 0;
    s += v[i];
  }
  int lane = t & 63, wid = t >> 6;
  int sc = s;
#pragma unroll
  for (int off = 1; off < 64; off <<= 1) {
    int u = __shfl_up(sc, off, 64);
    if (lane >= off) sc += u;
  }
  __shared__ int wt[4];
  if (lane == 63) wt[wid] = sc;
  __syncthreads();
  int wof = 0;
  for (int wI = 0; wI < wid; ++wI) wof += wt[wI];
  int base = a.bsum[d * NSB + b] + wof + (sc - s);
#pragma unroll
  for (int i = 0; i < 8; ++i) {
    int idx = i0 + i;
    if (idx < a.n) {
      row[idx] = base;
      if ((idx & 127) == 0) bcur[idx >> 7] = base;
      base += v[i];
    }
  }
  if (i0 <= a.n - 1 && a.n - 1 < i0 + 8) row[a.n] = base;
}

// ---------------- multi-split bin pass ----------------
// Per-block: LDS bucket hist -> reserve dense global chunks -> write 8B bin records
// record: [w fp32 | d_low7<<16 | other16]
struct BinArgs {
  const int* s0; const int* s1; const float* ew;
  int* bcur0; int* bcur1;
  unsigned long long* bin0; unsigned long long* bin1;
  int E;
};
__global__ __launch_bounds__(256) void bin_kernel(BinArgs ba)
{
  __shared__ int hist0[NBK], hist1[NBK];
  __shared__ int base0[NBK], base1[NBK];
  const int t = threadIdx.x;
  const int e0 = blockIdx.x * TILE;
  const int e1 = min(e0 + TILE, ba.E);
  for (int i = t; i < NBK; i += 256) { hist0[i] = 0; hist1[i] = 0; }
  __syncthreads();
  for (int e = e0 + t; e < e1; e += 256) {
    atomicAdd(&hist0[ba.s0[e] >> 7], 1);
    atomicAdd(&hist1[ba.s1[e] >> 7], 1);
  }
  __syncthreads();
  for (int i = t; i < NBK; i += 256) {
    int c0 = hist0[i];
    base0[i] = c0 ? atomicAdd(&ba.bcur0[i], c0) : 0;
    int c1 = hist1[i];
    base1[i] = c1 ? atomicAdd(&ba.bcur1[i], c1) : 0;
  }
  __syncthreads();
  for (int i = t; i < NBK; i += 256) { hist0[i] = 0; hist1[i] = 0; }
  __syncthreads();
  for (int e = e0 + t; e < e1; e += 256) {
    int d0 = ba.s0[e], d1 = ba.s1[e];
    unsigned long long wb = (unsigned long long)__float_as_uint(ba.ew[e]) << 32;
    int r0 = atomicAdd(&hist0[d0 >> 7], 1);
    ba.bin0[base0[d0 >> 7] + r0] = wb | (unsigned int)((d0 & 127) << 16) | (unsigned int)d1;
    int r1 = atomicAdd(&hist1[d1 >> 7], 1);
    ba.bin1[base1[d1 >> 7] + r1] = wb | (unsigned int)((d1 & 127) << 16) | (unsigned int)d0;
  }
}

// ---------------- reorder pass: bucket span -> per-node CSR slots, 4B records ----------------
struct RArgs {
  const int* row[2];
  const unsigned long long* bin[2];
  unsigned int* comb[2];
  int n;
};
__global__ __launch_bounds__(256) void reorder_kernel(RArgs ra)
{
  const int d = blockIdx.y;
  const int b = blockIdx.x;
  const int* __restrict__ row = ra.row[d];
  const unsigned long long* __restrict__ bin = ra.bin[d];
  unsigned int* __restrict__ comb = ra.comb[d];
  const int nb = b * 128;
  const int ne = min(nb + 128, ra.n);
  __shared__ int lcur[128];
  const int t = threadIdx.x;
  const int span_beg = row[nb];
  const int span_end = row[ne];
  if (t < ne - nb) lcur[t] = row[nb + t] - span_beg;
  __syncthreads();
  for (int i = span_beg + t; i < span_end; i += 256) {
    unsigned long long r = bin[i];
    unsigned int lo = (unsigned int)r;
    float w = __uint_as_float((unsigned int)(r >> 32));
    int nl = (lo >> 16) & 127;
    unsigned int other = lo & 0xffffu;
    int slot = atomicAdd(&lcur[nl], 1);
    comb[span_beg + slot] = other | ((unsigned int)f2b(w) << 16);
  }
}

// merged dual-direction gather; wave per node; 16-deep MLP unroll; 4B records
struct GArgs {
  const int* rowstart[2];
  const unsigned int* comb[2];
  const unsigned short* h[2];
  unsigned short* xout[2];
  int n;
};
__global__ void gather_kernel(GArgs ga)
{
  int gw = blockIdx.x * (blockDim.x >> 6) + (threadIdx.x >> 6);
  int lane = threadIdx.x & 63;
  if (gw >= 2 * ga.n) return;
  int dir = (gw >= ga.n) ? 1 : 0;
  int node = gw - dir * ga.n;
  const int* __restrict__ rowstart = ga.rowstart[dir];
  const unsigned int* __restrict__ comb = ga.comb[dir];
  const unsigned int* __restrict__ h = (const unsigned int*)ga.h[dir];
  int beg = rowstart[node], end = rowstart[node + 1];
  float a0 = 0.f, a1 = 0.f;
  for (int p = beg; p < end; p += 16) {
    unsigned int cc[16];
    unsigned int uu[16];
#pragma unroll
    for (int i = 0; i < 16; ++i) {
      int pi = p + i;
      cc[i] = (pi < end) ? comb[pi] : 0u;   // rec 0 -> node 0, weight +0.0f
    }
#pragma unroll
    for (int i = 0; i < 16; ++i)
      uu[i] = h[(size_t)(cc[i] & 0xffffu) * 64 + lane];
#pragma unroll
    for (int i = 0; i < 16; ++i) {
      float wv = b2f((unsigned short)(cc[i] >> 16));
      a0 += wv * b2f((unsigned short)uu[i]);
      a1 += wv * b2f((unsigned short)(uu[i] >> 16));
    }
  }
  float v0 = LRELU(a0), v1 = LRELU(a1);
  unsigned int* xo = (unsigned int*)(ga.xout[dir] + (size_t)node * 128);
  xo[lane] = pack2(v0, v1);
}

__global__ void segsum_kernel(const unsigned short* __restrict__ xc,
                              const int* __restrict__ batch,
                              const float* __restrict__ states,
                              float* __restrict__ gsel, float* __restrict__ gsum, int n)
{
  int f = threadIdx.x;
  int r0 = blockIdx.x * 256;
  int r1 = min(r0 + 256, n);
  float asel = 0.f, asum = 0.f;
  int cur = batch[r0];
  for (int r = r0; r < r1; ++r) {
    int b = batch[r];
    if (b != cur) {
      atomicAdd(&gsel[cur * 128 + f], asel);
      atomicAdd(&gsum[cur * 128 + f], asum);
      asel = asum = 0.f;
      cur = b;
    }
    float v = b2f(xc[(size_t)r * 128 + f]);
    asum += v;
    if (states[r] == 1.0f) asel += v;
  }
  atomicAdd(&gsel[cur * 128 + f], asel);
  atomicAdd(&gsum[cur * 128 + f], asum);
}

__global__ void small16_kernel(const float* __restrict__ gsel, const float* __restrict__ gsum,
                               const float* __restrict__ g1W, const float* __restrict__ g2W,
                               unsigned short* __restrict__ A16, unsigned short* __restrict__ B16)
{
  int r = blockIdx.x, t = threadIdx.x, o = t & 127;
  const float* src = (t < 128) ? gsel : gsum;
  const float* Wm  = (t < 128) ? g1W : g2W;
  float acc = 0.f;
  for (int k = 0; k < 128; ++k) acc += src[r * 128 + k] * Wm[o * 128 + k];
  unsigned short* dst = (t < 128) ? A16 : B16;
  dst[r * 128 + o] = f2b(acc);
}

extern "C" void kernel_launch(void* const* d_in, const int* in_sizes, int n_in,
                              void* d_out, int out_size, void* d_ws, size_t ws_size,
                              hipStream_t stream)
{
  const int N = 50000, F = 128, E = 800000, G = 16, T = 3;
  const float* x      = (const float*)d_in[0];
  const int*   ei     = (const int*)d_in[1];
  const int*   s0     = ei;
  const int*   s1     = ei + E;
  const float* ew     = (const float*)d_in[2];
  const int*   batch  = (const int*)d_in[3];
  const float* states = (const float*)d_in[4];
  const float* p_a0[2]   = {(const float*)d_in[5],  (const float*)d_in[10]};
  const float* p_a1W[2]  = {(const float*)d_in[6],  (const float*)d_in[11]};
  const float* p_a1b[2]  = {(const float*)d_in[7],  (const float*)d_in[12]};
  const float* p_linW[2] = {(const float*)d_in[8],  (const float*)d_in[13]};
  const float* p_linb[2] = {(const float*)d_in[9],  (const float*)d_in[14]};
  const float* beta0W = (const float*)d_in[15];
  const float* beta1W = (const float*)d_in[16];
  const float* beta2W = (const float*)d_in[17];
  const float* beta2b = (const float*)d_in[18];
  const float* g0W = (const float*)d_in[19];
  const float* g1W = (const float*)d_in[20];
  const float* g2W = (const float*)d_in[21];
  const float* g3W = (const float*)d_in[22];
  const float* g4W = (const float*)d_in[23];
  const float* g4b = (const float*)d_in[24];
  float* out = (float*)d_out;

  char* p = (char*)d_ws;
  auto alloc = [&](size_t bytes) {
    char* r = p;
    p += (bytes + 255) & ~(size_t)255;
    return r;
  };
  const size_t NFb2 = (size_t)N * F * sizeof(unsigned short);  // 12.8 MB
  unsigned short* X1[3] = {(unsigned short*)alloc(NFb2), (unsigned short*)alloc(NFb2),
                           (unsigned short*)alloc(NFb2)};
  unsigned short* X2[3] = {(unsigned short*)alloc(NFb2), (unsigned short*)alloc(NFb2),
                           (unsigned short*)alloc(NFb2)};
  unsigned short* TMP0 = (unsigned short*)alloc(NFb2);
  unsigned short* TMP1 = (unsigned short*)alloc(NFb2);
  unsigned short* HH0  = (unsigned short*)alloc(NFb2);
  unsigned short* HH1  = (unsigned short*)alloc(NFb2);
  int*   row0 = (int*)alloc((size_t)(N + 1) * 4);
  int*   row1 = (int*)alloc((size_t)(N + 1) * 4);
  int*   cnt0 = (int*)alloc((size_t)N * 4);
  int*   cnt1 = (int*)alloc((size_t)N * 4);
  int*   bcur0 = (int*)alloc((size_t)NBK * 4);
  int*   bcur1 = (int*)alloc((size_t)NBK * 4);
  int*   bsum  = (int*)alloc((size_t)2 * NSB * 4);
  unsigned long long* bin0 = (unsigned long long*)alloc((size_t)E * 8);
  unsigned long long* bin1 = (unsigned long long*)alloc((size_t)E * 8);
  unsigned int* comb0 = (unsigned int*)alloc((size_t)E * 4);
  unsigned int* comb1 = (unsigned int*)alloc((size_t)E * 4);
  float* gsel = (float*)alloc((size_t)G * F * 4);
  float* gsum = (float*)alloc((size_t)G * F * 4);
  unsigned short* A16b = (unsigned short*)alloc((size_t)G * F * 2);
  unsigned short* B16b = (unsigned short*)alloc((size_t)G * F * 2);
  unsigned short* wreg = (unsigned short*)alloc((size_t)352256 * 2);
  float* rs = (float*)alloc((size_t)6 * 128 * 4);

  unsigned short* a1Wb[2]  = {wreg + 0,      wreg + 49152};
  unsigned short* linWb[2] = {wreg + 98304,  wreg + 147456};
  unsigned short* b0b = wreg + 196608;
  unsigned short* b1b = wreg + 212992;
  unsigned short* b2b = wreg + 229376;
  unsigned short* g0b = wreg + 262144;
  unsigned short* g3b = wreg + 278528;

  const dim3 blk256(256);
  const dim3 edge_grid((E + 255) / 256);
  const int GX = (N + 127) / 128;
  const int KBIG = 1 << 30;

  // ---- CSR build (hist -> 3-phase scan -> bin -> reorder) ----
  hipMemsetAsync(cnt0, 0, (size_t)N * 4, stream);
  hipMemsetAsync(cnt1, 0, (size_t)N * 4, stream);
  hist_kernel<<<edge_grid, blk256, 0, stream>>>(s0, s1, cnt0, cnt1, E);
  Scan1Args s1a;
  s1a.cnt[0] = cnt0; s1a.cnt[1] = cnt1; s1a.bsum = bsum; s1a.n = N;
  scan1_kernel<<<dim3(NSB, 2), blk256, 0, stream>>>(s1a);
  scan2_kernel<<<1, 64, 0, stream>>>(bsum);
  Scan3Args s3a;
  s3a.cnt[0] = cnt0; s3a.cnt[1] = cnt1; s3a.bsum = bsum;
  s3a.row[0] = row0; s3a.row[1] = row1;
  s3a.bcur[0] = bcur0; s3a.bcur[1] = bcur1;
  s3a.n = N;
  scan3_kernel<<<dim3(NSB, 2), blk256, 0, stream>>>(s3a);
  BinArgs bna;
  bna.s0 = s0; bna.s1 = s1; bna.ew = ew;
  bna.bcur0 = bcur0; bna.bcur1 = bcur1;
  bna.bin0 = bin0; bna.bin1 = bin1;
  bna.E = E;
  bin_kernel<<<(E + TILE - 1) / TILE, blk256, 0, stream>>>(bna);
  RArgs ra;
  ra.row[0] = row0; ra.row[1] = row1;
  ra.bin[0] = bin0; ra.bin[1] = bin1;
  ra.comb[0] = comb0; ra.comb[1] = comb1;
  ra.n = N;
  reorder_kernel<<<dim3(NBK, 2), blk256, 0, stream>>>(ra);

  // ---- weight conversion + rowsums + init ----
  CJobs jb;
  jb.s[0] = p_a1W[0];  jb.d[0] = a1Wb[0];  jb.n[0] = 49152;
  jb.s[1] = p_a1W[1];  jb.d[1] = a1Wb[1];  jb.n[1] = 49152;
  jb.s[2] = p_linW[0]; jb.d[2] = linWb[0]; jb.n[2] = 49152;
  jb.s[3] = p_linW[1]; jb.d[3] = linWb[1]; jb.n[3] = 49152;
  jb.s[4] = beta0W;    jb.d[4] = b0b;      jb.n[4] = 16384;
  jb.s[5] = beta1W;    jb.d[5] = b1b;      jb.n[5] = 16384;
  jb.s[6] = beta2W;    jb.d[6] = b2b;      jb.n[6] = 32768;
  jb.s[7] = g0W;       jb.d[7] = g0b;      jb.n[7] = 16384;
  jb.s[8] = g3W;       jb.d[8] = g3b;      jb.n[8] = 73728;
  convert_kernel<<<dim3(36, 9), blk256, 0, stream>>>(jb);
  rowsum_kernel<<<6, 128, 0, stream>>>(p_a1W[0], p_a1W[1], rs);
  init_kernel<<<3125, blk256, 0, stream>>>(x, X1[0], X2[0], N);

  // ---- T-loop (x-version rotation: read t%3, write (t+1)%3) ----
  for (int t = 0; t < T; ++t) {
    int rv = t % 3, wv = (t + 1) % 3;

    BArgs g1;
    g1.A1[0] = X1[rv]; g1.A2[0] = X1[rv]; g1.A1[1] = X2[rv]; g1.A2[1] = X2[rv];
    g1.ldA1 = 128; g1.ldA2 = 128; g1.K1 = KBIG;
    g1.W[0] = a1Wb[0] + t * 16384; g1.W[1] = a1Wb[1] + t * 16384;
    g1.bias[0] = p_a1b[0] + t * F; g1.bias[1] = p_a1b[1] + t * F;
    g1.a0p[0] = p_a0[0] + t;       g1.a0p[1] = p_a0[1] + t;
    g1.rowsum[0] = rs + t * 128;   g1.rowsum[1] = rs + (3 + t) * 128;
    g1.C[0] = TMP0; g1.C[1] = TMP1;
    g1.states = states; g1.N = N; g1.K = 128;
    bgemm<128, 1, true, true><<<dim3(GX, 2), blk256, 0, stream>>>(g1);

    BArgs g2;
    g2.A1[0] = TMP0; g2.A2[0] = TMP0; g2.A1[1] = TMP1; g2.A2[1] = TMP1;
    g2.ldA1 = 128; g2.ldA2 = 128; g2.K1 = KBIG;
    g2.W[0] = linWb[0] + t * 16384; g2.W[1] = linWb[1] + t * 16384;
    g2.bias[0] = p_linb[0] + t * F; g2.bias[1] = p_linb[1] + t * F;
    g2.a0p[0] = nullptr; g2.a0p[1] = nullptr;
    g2.rowsum[0] = nullptr; g2.rowsum[1] = nullptr;
    g2.C[0] = HH0; g2.C[1] = HH1;
    g2.states = nullptr; g2.N = N; g2.K = 128;
    bgemm<128, 0, true, false><<<dim3(GX, 2), blk256, 0, stream>>>(g2);

    GArgs ga;
    ga.rowstart[0] = row0; ga.rowstart[1] = row1;
    ga.comb[0] = comb0;    ga.comb[1] = comb1;
    ga.h[0] = HH0;         ga.h[1] = HH1;
    ga.xout[0] = X1[wv];   ga.xout[1] = X2[wv];
    ga.n = N;
    gather_kernel<<<(2 * N + 3) / 4, blk256, 0, stream>>>(ga);
  }

  // ---- x1s/x2s = sum of the 3 versions ----
  S3Args s3;
  s3.a[0] = (const unsigned int*)X1[0]; s3.b[0] = (const unsigned int*)X1[1];
  s3.c[0] = (const unsigned int*)X1[2]; s3.o[0] = (unsigned int*)TMP0;
  s3.a[1] = (const unsigned int*)X2[0]; s3.b[1] = (const unsigned int*)X2[1];
  s3.c[1] = (const unsigned int*)X2[2]; s3.o[1] = (unsigned int*)TMP1;
  s3.n = N * 64;
  sum3_kernel<<<dim3(2048, 2), blk256, 0, stream>>>(s3);

  // ---- beta stage: u = x1s@b0^T, v = x2s@b1^T (pair), then xc ----
  BArgs bu;
  bu.A1[0] = TMP0; bu.A2[0] = TMP0; bu.A1[1] = TMP1; bu.A2[1] = TMP1;
  bu.ldA1 = 128; bu.ldA2 = 128; bu.K1 = KBIG;
  bu.W[0] = b0b; bu.W[1] = b1b;
  bu.bias[0] = nullptr; bu.bias[1] = nullptr;
  bu.a0p[0] = nullptr; bu.a0p[1] = nullptr;
  bu.rowsum[0] = nullptr; bu.rowsum[1] = nullptr;
  bu.C[0] = HH0; bu.C[1] = HH1;
  bu.states = nullptr; bu.N = N; bu.K = 128;
  bgemm<128, 0, false, false><<<dim3(GX, 2), blk256, 0, stream>>>(bu);

  BArgs b2a;
  b2a.A1[0] = HH0; b2a.A2[0] = HH1; b2a.A1[1] = nullptr; b2a.A2[1] = nullptr;
  b2a.ldA1 = 128; b2a.ldA2 = 128; b2a.K1 = 128;
  b2a.W[0] = b2b; b2a.W[1] = nullptr;
  b2a.bias[0] = beta2b; b2a.bias[1] = nullptr;
  b2a.a0p[0] = nullptr; b2a.a0p[1] = nullptr;
  b2a.rowsum[0] = nullptr; b2a.rowsum[1] = nullptr;
  b2a.C[0] = TMP0; b2a.C[1] = nullptr;
  b2a.states = nullptr; b2a.N = N; b2a.K = 256;
  bgemm<128, 1, true, false><<<dim3(GX, 1), blk256, 0, stream>>>(b2a);

  // ---- per-graph sums + 16-row GEMMs ----
  hipMemsetAsync(gsel, 0, (size_t)G * F * 4, stream);
  hipMemsetAsync(gsum, 0, (size_t)G * F * 4, stream);
  segsum_kernel<<<(N + 255) / 256, dim3(128), 0, stream>>>(TMP0, batch, states, gsel, gsum, N);
  small16_kernel<<<G, blk256, 0, stream>>>(gsel, gsum, g1W, g2W, A16b, B16b);

  // ---- gamma stage ----
  BArgs g0a;
  g0a.A1[0] = TMP0; g0a.A2[0] = TMP0; g0a.A1[1] = nullptr; g0a.A2[1] = nullptr;
  g0a.ldA1 = 128; g0a.ldA2 = 128; g0a.K1 = KBIG;
  g0a.W[0] = g0b; g0a.W[1] = nullptr;
  g0a.bias[0] = nullptr; g0a.bias[1] = nullptr;
  g0a.a0p[0] = nullptr; g0a.a0p[1] = nullptr;
  g0a.rowsum[0] = nullptr; g0a.rowsum[1] = nullptr;
  g0a.C[0] = TMP1; g0a.C[1] = nullptr;
  g0a.states = nullptr; g0a.N = N; g0a.K = 128;
  bgemm<128, 0, false, false><<<dim3(GX, 1), blk256, 0, stream>>>(g0a);

  g3_kernel<<<GX, blk256, 0, stream>>>(TMP1, A16b, B16b, batch, g3b, g4W, g4b, out, N);
}

// Round 7
// 482.275 us; speedup vs baseline: 3.8503x; 1.2363x over previous
//
#include <hip/hip_runtime.h>

typedef short s8v __attribute__((ext_vector_type(8)));
typedef float f32x4 __attribute__((ext_vector_type(4)));

#define LRELU(v) ((v) > 0.f ? (v) : 0.2f * (v))

constexpr int NBK = 391;   // (50000+127)/128 node buckets
constexpr int TILE = 8192; // edges per bin-pass block

__device__ __forceinline__ float b2f(unsigned short b) {
  return __uint_as_float(((unsigned int)b) << 16);
}
__device__ __forceinline__ unsigned short f2b(float f) {
  unsigned int x = __float_as_uint(f);
  x += 0x7fffu + ((x >> 16) & 1u);
  return (unsigned short)(x >> 16);
}
__device__ __forceinline__ unsigned int pack2(float lo, float hi) {
  return ((unsigned int)f2b(hi) << 16) | (unsigned int)f2b(lo);
}

// ---------------- batched bf16 MFMA GEMM ----------------
struct BArgs {
  const unsigned short* A1[2];
  const unsigned short* A2[2];
  int ldA1, ldA2, K1;
  const unsigned short* W[2];
  const float* bias[2];
  const float* a0p[2];
  const float* rowsum[2];
  unsigned short* C[2];
  const float* states;
  int N, K;
};

template<int FOUT, int ACT, bool HAS_BIAS, bool HAS_STATES>
__global__ __launch_bounds__(256) void bgemm(BArgs ba)
{
  constexpr int NF = FOUT / 16;
  __shared__ __align__(16) unsigned short Ws[FOUT * 128];
  const int d = blockIdx.y;
  const unsigned short* __restrict__ A1 = ba.A1[d];
  const unsigned short* __restrict__ A2 = ba.A2[d];
  const unsigned short* __restrict__ W  = ba.W[d];
  unsigned short* __restrict__ C = ba.C[d];
  const int N = ba.N, K = ba.K, K1 = ba.K1, ldA1 = ba.ldA1, ldA2 = ba.ldA2;

  const int tid = threadIdx.x;
  const int lane = tid & 63;
  const int w = tid >> 6;
  const int l15 = lane & 15;
  const int g = lane >> 4;
  const int m0 = blockIdx.x * 128;

  f32x4 zero4 = {0.f, 0.f, 0.f, 0.f};
  f32x4 acc[2][NF];
#pragma unroll
  for (int mf = 0; mf < 2; ++mf)
#pragma unroll
    for (int nf = 0; nf < NF; ++nf) acc[mf][nf] = zero4;

  for (int kk = 0; kk < K; kk += 128) {
#pragma unroll
    for (int j = 0; j < NF; ++j) {
      int idx = tid + j * 256;
      int o = idx >> 4, c = idx & 15;
      uint4 v = *(const uint4*)(W + (size_t)o * K + kk + c * 8);
      *(uint4*)&Ws[o * 128 + (c ^ (o & 15)) * 8] = v;
    }
    const unsigned short* Ap; int ldA, koff;
    if (kk < K1) { Ap = A1; ldA = ldA1; koff = kk; }
    else         { Ap = A2; ldA = ldA2; koff = kk - K1; }
    s8v a[2][4];
#pragma unroll
    for (int mf = 0; mf < 2; ++mf) {
      int row = m0 + w * 32 + mf * 16 + l15;
      const unsigned short* ar = Ap + (size_t)row * ldA + koff + g * 8;
#pragma unroll
      for (int ks = 0; ks < 4; ++ks) {
        s8v t = {};
        if (row < N) t = *(const s8v*)(ar + ks * 32);
        a[mf][ks] = t;
      }
    }
    __syncthreads();
#pragma unroll
    for (int ks = 0; ks < 4; ++ks) {
#pragma unroll
      for (int nf = 0; nf < NF; ++nf) {
        int c = ks * 4 + g;
        s8v b = *(const s8v*)&Ws[(nf * 16 + l15) * 128 + (c ^ l15) * 8];
        acc[0][nf] = __builtin_amdgcn_mfma_f32_16x16x32_bf16(a[0][ks], b, acc[0][nf], 0, 0, 0);
        acc[1][nf] = __builtin_amdgcn_mfma_f32_16x16x32_bf16(a[1][ks], b, acc[1][nf], 0, 0, 0);
      }
    }
    if (kk + 128 < K) __syncthreads();
  }

  const float a0 = HAS_STATES ? ba.a0p[d][0] : 0.f;
#pragma unroll
  for (int mf = 0; mf < 2; ++mf) {
#pragma unroll
    for (int r = 0; r < 4; ++r) {
      int row = m0 + w * 32 + mf * 16 + g * 4 + r;
      if (row >= N) continue;
      float sa = HAS_STATES ? ba.states[row] * a0 : 0.f;
      unsigned short* crow = C + (size_t)row * FOUT;
#pragma unroll
      for (int nf = 0; nf < NF; ++nf) {
        int col = nf * 16 + l15;
        float v = acc[mf][nf][r];
        if (HAS_BIAS) v += ba.bias[d][col];
        if (HAS_STATES) v += sa * ba.rowsum[d][col];
        if (ACT) v = LRELU(v);
        crow[col] = f2b(v);
      }
    }
  }
}

// ---------------- g3 GEMM: A = [wbuf | A16[batch] | B16[batch]], fused final dot ----------------
__global__ __launch_bounds__(256) void g3_kernel(
    const unsigned short* __restrict__ wbuf,
    const unsigned short* __restrict__ A16,
    const unsigned short* __restrict__ B16,
    const int* __restrict__ batch,
    const unsigned short* __restrict__ W,   // g3W bf16 [192][384]
    const float* __restrict__ g4W,          // [192]
    const float* __restrict__ g4b,
    float* __restrict__ out, int N)
{
  constexpr int NF = 12;
  __shared__ __align__(16) unsigned short Ws[192 * 128];
  const int tid = threadIdx.x;
  const int lane = tid & 63;
  const int w = tid >> 6;
  const int l15 = lane & 15;
  const int g = lane >> 4;
  const int m0 = blockIdx.x * 128;

  f32x4 zero4 = {0.f, 0.f, 0.f, 0.f};
  f32x4 acc[2][NF];
#pragma unroll
  for (int mf = 0; mf < 2; ++mf)
#pragma unroll
    for (int nf = 0; nf < NF; ++nf) acc[mf][nf] = zero4;

  int brow[2];
#pragma unroll
  for (int mf = 0; mf < 2; ++mf) {
    int row = m0 + w * 32 + mf * 16 + l15;
    brow[mf] = (row < N) ? batch[row] : 0;
  }

  for (int kk = 0; kk < 384; kk += 128) {
#pragma unroll
    for (int j = 0; j < NF; ++j) {
      int idx = tid + j * 256;
      int o = idx >> 4, c = idx & 15;
      uint4 v = *(const uint4*)(W + (size_t)o * 384 + kk + c * 8);
      *(uint4*)&Ws[o * 128 + (c ^ (o & 15)) * 8] = v;
    }
    s8v a[2][4];
#pragma unroll
    for (int mf = 0; mf < 2; ++mf) {
      int row = m0 + w * 32 + mf * 16 + l15;
      const unsigned short* ar;
      if (kk == 0)        ar = wbuf + (size_t)row * 128 + g * 8;
      else if (kk == 128) ar = A16 + (size_t)brow[mf] * 128 + g * 8;
      else                ar = B16 + (size_t)brow[mf] * 128 + g * 8;
#pragma unroll
      for (int ks = 0; ks < 4; ++ks) {
        s8v t = {};
        if (row < N) t = *(const s8v*)(ar + ks * 32);
        a[mf][ks] = t;
      }
    }
    __syncthreads();
#pragma unroll
    for (int ks = 0; ks < 4; ++ks) {
#pragma unroll
      for (int nf = 0; nf < NF; ++nf) {
        int c = ks * 4 + g;
        s8v b = *(const s8v*)&Ws[(nf * 16 + l15) * 128 + (c ^ l15) * 8];
        acc[0][nf] = __builtin_amdgcn_mfma_f32_16x16x32_bf16(a[0][ks], b, acc[0][nf], 0, 0, 0);
        acc[1][nf] = __builtin_amdgcn_mfma_f32_16x16x32_bf16(a[1][ks], b, acc[1][nf], 0, 0, 0);
      }
    }
    if (kk < 256) __syncthreads();
  }

  float w4[NF];
#pragma unroll
  for (int nf = 0; nf < NF; ++nf) w4[nf] = g4W[nf * 16 + l15];
  const float gb = g4b[0];

#pragma unroll
  for (int mf = 0; mf < 2; ++mf) {
#pragma unroll
    for (int r = 0; r < 4; ++r) {
      int row = m0 + w * 32 + mf * 16 + g * 4 + r;
      float dot = 0.f;
#pragma unroll
      for (int nf = 0; nf < NF; ++nf) {
        float v = acc[mf][nf][r];
        v = LRELU(v);
        dot += v * w4[nf];
      }
#pragma unroll
      for (int m = 1; m < 16; m <<= 1) dot += __shfl_xor(dot, m, 16);
      if (l15 == 0 && row < N) out[row] = dot + gb;
    }
  }
}

// ---------------- weight fp32 -> bf16 conversion ----------------
struct CJobs { const float* s[9]; unsigned short* d[9]; int n[9]; };
__global__ void convert_kernel(CJobs jb) {
  int j = blockIdx.y;
  int idx = (blockIdx.x * 256 + threadIdx.x) * 8;
  if (idx >= jb.n[j]) return;
  const float* s = jb.s[j] + idx;
  float4 p0 = *(const float4*)s;
  float4 p1 = *(const float4*)(s + 4);
  uint4 u;
  u.x = pack2(p0.x, p0.y); u.y = pack2(p0.z, p0.w);
  u.z = pack2(p1.x, p1.y); u.w = pack2(p1.z, p1.w);
  *(uint4*)(jb.d[j] + idx) = u;
}

__global__ void rowsum_kernel(const float* __restrict__ a1,
                              const float* __restrict__ a2, float* __restrict__ rs) {
  int j = blockIdx.x;
  const float* src = (j < 3) ? (a1 + (size_t)j * 16384) : (a2 + (size_t)(j - 3) * 16384);
  int o = threadIdx.x;
  float s = 0.f;
  for (int k = 0; k < 128; ++k) s += src[o * 128 + k];
  rs[j * 128 + o] = s;
}

// split x into x1/x2 (bf16)
__global__ void init_kernel(const float* __restrict__ x,
                            unsigned short* __restrict__ x1, unsigned short* __restrict__ x2,
                            int n)
{
  int idx = blockIdx.x * blockDim.x + threadIdx.x;
  int total = n * 16;
  for (; idx < total; idx += gridDim.x * blockDim.x) {
    int r = idx >> 4, c = idx & 15;
    const float* xr = x + (size_t)r * 256 + c * 8;
    float4 p0 = *(const float4*)xr;
    float4 p1 = *(const float4*)(xr + 4);
    uint4 u1;
    u1.x = pack2(p0.x, p0.y); u1.y = pack2(p0.z, p0.w);
    u1.z = pack2(p1.x, p1.y); u1.w = pack2(p1.z, p1.w);
    float4 q0 = *(const float4*)(xr + 128);
    float4 q1 = *(const float4*)(xr + 132);
    uint4 u2;
    u2.x = pack2(q0.x, q0.y); u2.y = pack2(q0.z, q0.w);
    u2.z = pack2(q1.x, q1.y); u2.w = pack2(q1.z, q1.w);
    ((uint4*)(x1 + (size_t)r * 128))[c] = u1;
    ((uint4*)(x2 + (size_t)r * 128))[c] = u2;
  }
}

// sum of three bf16 buffers (fp32 math), both directions via blockIdx.y
struct S3Args { const unsigned int* a[2]; const unsigned int* b[2]; const unsigned int* c[2];
                unsigned int* o[2]; int n; };
__global__ void sum3_kernel(S3Args s)
{
  int d = blockIdx.y;
  const unsigned int* __restrict__ pa = s.a[d];
  const unsigned int* __restrict__ pb = s.b[d];
  const unsigned int* __restrict__ pc = s.c[d];
  unsigned int* __restrict__ po = s.o[d];
  for (int i = blockIdx.x * 256 + threadIdx.x; i < s.n; i += gridDim.x * 256) {
    unsigned int ua = pa[i], ub = pb[i], uc = pc[i];
    float lo = b2f((unsigned short)ua) + b2f((unsigned short)ub) + b2f((unsigned short)uc);
    float hi = b2f((unsigned short)(ua >> 16)) + b2f((unsigned short)(ub >> 16))
             + b2f((unsigned short)(uc >> 16));
    po[i] = pack2(lo, hi);
  }
}

// ---------------- bucket-level histogram (LDS aggregated) ----------------
struct BHArgs { const int* s0; const int* s1; int* bh0; int* bh1; int E; };
__global__ __launch_bounds__(256) void bhist_kernel(BHArgs a)
{
  __shared__ int h0[NBK], h1[NBK];
  const int t = threadIdx.x;
  for (int i = t; i < NBK; i += 256) { h0[i] = 0; h1[i] = 0; }
  __syncthreads();
  const int e0 = blockIdx.x * TILE;
  const int e1 = min(e0 + TILE, a.E);
  for (int e = e0 + t; e < e1; e += 256) {
    atomicAdd(&h0[a.s0[e] >> 7], 1);
    atomicAdd(&h1[a.s1[e] >> 7], 1);
  }
  __syncthreads();
  for (int i = t; i < NBK; i += 256) {
    if (h0[i]) atomicAdd(&a.bh0[i], h0[i]);
    if (h1[i]) atomicAdd(&a.bh1[i], h1[i]);
  }
}

// ---------------- bucket scan (391 entries x 2 dirs, single block) ----------------
struct BScanArgs { const int* bh[2]; int* bbase[2]; int* bcur[2]; };
__global__ __launch_bounds__(128) void bscan_kernel(BScanArgs a)
{
  __shared__ int ld[2][NBK];
  int wid = threadIdx.x >> 6, lane = threadIdx.x & 63;
  for (int i = lane; i < NBK; i += 64) ld[wid][i] = a.bh[wid][i];
  __syncthreads();
  if (lane == 0) {
    int acc = 0;
    for (int i = 0; i < NBK; ++i) { int v = ld[wid][i]; ld[wid][i] = acc; acc += v; }
    a.bbase[wid][NBK] = acc;
  }
  __syncthreads();
  for (int i = lane; i < NBK; i += 64) {
    int v = ld[wid][i];
    a.bbase[wid][i] = v;
    a.bcur[wid][i] = v;
  }
}

// ---------------- multi-split bin pass ----------------
// record: [w fp32 | d_low7<<16 | other16]
struct BinArgs {
  const int* s0; const int* s1; const float* ew;
  int* bcur0; int* bcur1;
  unsigned long long* bin0; unsigned long long* bin1;
  int E;
};
__global__ __launch_bounds__(256) void bin_kernel(BinArgs ba)
{
  __shared__ int hist0[NBK], hist1[NBK];
  __shared__ int base0[NBK], base1[NBK];
  const int t = threadIdx.x;
  const int e0 = blockIdx.x * TILE;
  const int e1 = min(e0 + TILE, ba.E);
  for (int i = t; i < NBK; i += 256) { hist0[i] = 0; hist1[i] = 0; }
  __syncthreads();
  for (int e = e0 + t; e < e1; e += 256) {
    atomicAdd(&hist0[ba.s0[e] >> 7], 1);
    atomicAdd(&hist1[ba.s1[e] >> 7], 1);
  }
  __syncthreads();
  for (int i = t; i < NBK; i += 256) {
    int c0 = hist0[i];
    base0[i] = c0 ? atomicAdd(&ba.bcur0[i], c0) : 0;
    int c1 = hist1[i];
    base1[i] = c1 ? atomicAdd(&ba.bcur1[i], c1) : 0;
  }
  __syncthreads();
  for (int i = t; i < NBK; i += 256) { hist0[i] = 0; hist1[i] = 0; }
  __syncthreads();
  for (int e = e0 + t; e < e1; e += 256) {
    int d0 = ba.s0[e], d1 = ba.s1[e];
    unsigned long long wb = (unsigned long long)__float_as_uint(ba.ew[e]) << 32;
    int r0 = atomicAdd(&hist0[d0 >> 7], 1);
    ba.bin0[base0[d0 >> 7] + r0] = wb | (unsigned int)((d0 & 127) << 16) | (unsigned int)d1;
    int r1 = atomicAdd(&hist1[d1 >> 7], 1);
    ba.bin1[base1[d1 >> 7] + r1] = wb | (unsigned int)((d1 & 127) << 16) | (unsigned int)d0;
  }
}

// ---------------- reorder: bucket span -> per-node CSR slots + row[] build ----------------
struct RArgs {
  const int* bbase[2];
  const unsigned long long* bin[2];
  unsigned int* comb[2];
  int* row[2];
  int n;
};
__global__ __launch_bounds__(256) void reorder_kernel(RArgs ra)
{
  const int d = blockIdx.y;
  const int b = blockIdx.x;
  const unsigned long long* __restrict__ bin = ra.bin[d];
  unsigned int* __restrict__ comb = ra.comb[d];
  int* __restrict__ row = ra.row[d];
  const int nb = b * 128;
  const int ne = min(nb + 128, ra.n);
  const int t = threadIdx.x;
  __shared__ int lcnt[128];
  __shared__ int lcur[128];
  __shared__ int wtot[4];
  if (t < 128) lcnt[t] = 0;
  const int span_beg = ra.bbase[d][b];
  const int span_end = ra.bbase[d][b + 1];
  __syncthreads();
  for (int i = span_beg + t; i < span_end; i += 256) {
    int nl = ((unsigned int)bin[i] >> 16) & 127;
    atomicAdd(&lcnt[nl], 1);
  }
  __syncthreads();
  // exclusive scan of the 128 counters (waves 0,1 carry data)
  int lane = t & 63, wv = t >> 6;
  int v = (t < 128) ? lcnt[t] : 0;
  int sc = v;
#pragma unroll
  for (int off = 1; off < 64; off <<= 1) {
    int u = __shfl_up(sc, off, 64);
    if (lane >= off) sc += u;
  }
  if (lane == 63) wtot[wv] = sc;
  __syncthreads();
  int excl = sc - v + ((wv == 1) ? wtot[0] : 0);
  if (t < 128) {
    lcur[t] = excl;
    if (nb + t < ne) row[nb + t] = span_beg + excl;
  }
  if (b == NBK - 1 && t == 0) row[ra.n] = span_end;
  __syncthreads();
  for (int i = span_beg + t; i < span_end; i += 256) {
    unsigned long long r = bin[i];
    unsigned int lo = (unsigned int)r;
    float w = __uint_as_float((unsigned int)(r >> 32));
    int nl = (lo >> 16) & 127;
    int slot = atomicAdd(&lcur[nl], 1);
    comb[span_beg + slot] = (lo & 0xffffu) | ((unsigned int)f2b(w) << 16);
  }
}

// merged dual-direction gather; wave per node; 16-deep MLP unroll; 4B records
struct GArgs {
  const int* rowstart[2];
  const unsigned int* comb[2];
  const unsigned short* h[2];
  unsigned short* xout[2];
  int n;
};
__global__ void gather_kernel(GArgs ga)
{
  int gw = blockIdx.x * (blockDim.x >> 6) + (threadIdx.x >> 6);
  int lane = threadIdx.x & 63;
  if (gw >= 2 * ga.n) return;
  int dir = (gw >= ga.n) ? 1 : 0;
  int node = gw - dir * ga.n;
  const int* __restrict__ rowstart = ga.rowstart[dir];
  const unsigned int* __restrict__ comb = ga.comb[dir];
  const unsigned int* __restrict__ h = (const unsigned int*)ga.h[dir];
  int beg = rowstart[node], end = rowstart[node + 1];
  float a0 = 0.f, a1 = 0.f;
  for (int p = beg; p < end; p += 16) {
    unsigned int cc[16];
    unsigned int uu[16];
#pragma unroll
    for (int i = 0; i < 16; ++i) {
      int pi = p + i;
      cc[i] = (pi < end) ? comb[pi] : 0u;   // rec 0 -> node 0, weight +0.0f
    }
#pragma unroll
    for (int i = 0; i < 16; ++i)
      uu[i] = h[(size_t)(cc[i] & 0xffffu) * 64 + lane];
#pragma unroll
    for (int i = 0; i < 16; ++i) {
      float wv = b2f((unsigned short)(cc[i] >> 16));
      a0 += wv * b2f((unsigned short)uu[i]);
      a1 += wv * b2f((unsigned short)(uu[i] >> 16));
    }
  }
  float v0 = LRELU(a0), v1 = LRELU(a1);
  unsigned int* xo = (unsigned int*)(ga.xout[dir] + (size_t)node * 128);
  xo[lane] = pack2(v0, v1);
}

// ---------------- parallel segment sum (4 row-slots/block, uint loads, 4-ahead) ----------------
__global__ __launch_bounds__(256) void segsum_kernel(
    const unsigned short* __restrict__ xc, const int* __restrict__ batch,
    const float* __restrict__ states,
    float* __restrict__ gsel, float* __restrict__ gsum, int n)
{
  int slot = threadIdx.x >> 6;
  int lane = threadIdx.x & 63;
  int r0 = blockIdx.x * 128 + slot * 32;
  if (r0 >= n) return;
  int r1 = min(r0 + 32, n);
  const unsigned int* __restrict__ xcu = (const unsigned int*)xc;
  float sel0 = 0.f, sel1 = 0.f, sum0 = 0.f, sum1 = 0.f;
  int cur = batch[r0];
  for (int r = r0; r < r1; r += 4) {
    unsigned int u[4]; int bb[4]; float st[4];
#pragma unroll
    for (int i = 0; i < 4; ++i) {
      int ri = min(r + i, r1 - 1);
      u[i] = xcu[(size_t)ri * 64 + lane];
      bb[i] = batch[ri];
      st[i] = states[ri];
    }
    int m = min(4, r1 - r);
#pragma unroll
    for (int i = 0; i < 4; ++i) {
      if (i >= m) break;
      if (bb[i] != cur) {
        atomicAdd(&gsel[cur * 128 + lane * 2], sel0);
        atomicAdd(&gsel[cur * 128 + lane * 2 + 1], sel1);
        atomicAdd(&gsum[cur * 128 + lane * 2], sum0);
        atomicAdd(&gsum[cur * 128 + lane * 2 + 1], sum1);
        sel0 = sel1 = sum0 = sum1 = 0.f;
        cur = bb[i];
      }
      float lo = b2f((unsigned short)u[i]);
      float hi = b2f((unsigned short)(u[i] >> 16));
      sum0 += lo; sum1 += hi;
      if (st[i] == 1.0f) { sel0 += lo; sel1 += hi; }
    }
  }
  atomicAdd(&gsel[cur * 128 + lane * 2], sel0);
  atomicAdd(&gsel[cur * 128 + lane * 2 + 1], sel1);
  atomicAdd(&gsum[cur * 128 + lane * 2], sum0);
  atomicAdd(&gsum[cur * 128 + lane * 2 + 1], sum1);
}

__global__ void small16_kernel(const float* __restrict__ gsel, const float* __restrict__ gsum,
                               const float* __restrict__ g1W, const float* __restrict__ g2W,
                               unsigned short* __restrict__ A16, unsigned short* __restrict__ B16)
{
  int r = blockIdx.x, t = threadIdx.x, o = t & 127;
  const float* src = (t < 128) ? gsel : gsum;
  const float* Wm  = (t < 128) ? g1W : g2W;
  float acc = 0.f;
  for (int k = 0; k < 128; ++k) acc += src[r * 128 + k] * Wm[o * 128 + k];
  unsigned short* dst = (t < 128) ? A16 : B16;
  dst[r * 128 + o] = f2b(acc);
}

extern "C" void kernel_launch(void* const* d_in, const int* in_sizes, int n_in,
                              void* d_out, int out_size, void* d_ws, size_t ws_size,
                              hipStream_t stream)
{
  const int N = 50000, F = 128, E = 800000, G = 16, T = 3;
  const float* x      = (const float*)d_in[0];
  const int*   ei     = (const int*)d_in[1];
  const int*   s0     = ei;
  const int*   s1     = ei + E;
  const float* ew     = (const float*)d_in[2];
  const int*   batch  = (const int*)d_in[3];
  const float* states = (const float*)d_in[4];
  const float* p_a0[2]   = {(const float*)d_in[5],  (const float*)d_in[10]};
  const float* p_a1W[2]  = {(const float*)d_in[6],  (const float*)d_in[11]};
  const float* p_a1b[2]  = {(const float*)d_in[7],  (const float*)d_in[12]};
  const float* p_linW[2] = {(const float*)d_in[8],  (const float*)d_in[13]};
  const float* p_linb[2] = {(const float*)d_in[9],  (const float*)d_in[14]};
  const float* beta0W = (const float*)d_in[15];
  const float* beta1W = (const float*)d_in[16];
  const float* beta2W = (const float*)d_in[17];
  const float* beta2b = (const float*)d_in[18];
  const float* g0W = (const float*)d_in[19];
  const float* g1W = (const float*)d_in[20];
  const float* g2W = (const float*)d_in[21];
  const float* g3W = (const float*)d_in[22];
  const float* g4W = (const float*)d_in[23];
  const float* g4b = (const float*)d_in[24];
  float* out = (float*)d_out;

  char* p = (char*)d_ws;
  auto alloc = [&](size_t bytes) {
    char* r = p;
    p += (bytes + 255) & ~(size_t)255;
    return r;
  };
  const size_t NFb2 = (size_t)N * F * sizeof(unsigned short);  // 12.8 MB
  unsigned short* X1[3] = {(unsigned short*)alloc(NFb2), (unsigned short*)alloc(NFb2),
                           (unsigned short*)alloc(NFb2)};
  unsigned short* X2[3] = {(unsigned short*)alloc(NFb2), (unsigned short*)alloc(NFb2),
                           (unsigned short*)alloc(NFb2)};
  unsigned short* TMP0 = (unsigned short*)alloc(NFb2);
  unsigned short* TMP1 = (unsigned short*)alloc(NFb2);
  unsigned short* HH0  = (unsigned short*)alloc(NFb2);
  unsigned short* HH1  = (unsigned short*)alloc(NFb2);
  int*   row0 = (int*)alloc((size_t)(N + 1) * 4);
  int*   row1 = (int*)alloc((size_t)(N + 1) * 4);
  int*   bh0  = (int*)alloc((size_t)NBK * 4);
  int*   bh1  = (int*)alloc((size_t)NBK * 4);
  int*   bbase0 = (int*)alloc((size_t)(NBK + 1) * 4);
  int*   bbase1 = (int*)alloc((size_t)(NBK + 1) * 4);
  int*   bcur0 = (int*)alloc((size_t)NBK * 4);
  int*   bcur1 = (int*)alloc((size_t)NBK * 4);
  unsigned long long* bin0 = (unsigned long long*)alloc((size_t)E * 8);
  unsigned long long* bin1 = (unsigned long long*)alloc((size_t)E * 8);
  unsigned int* comb0 = (unsigned int*)alloc((size_t)E * 4);
  unsigned int* comb1 = (unsigned int*)alloc((size_t)E * 4);
  float* gsel = (float*)alloc((size_t)G * F * 4);
  float* gsum = (float*)alloc((size_t)G * F * 4);
  unsigned short* A16b = (unsigned short*)alloc((size_t)G * F * 2);
  unsigned short* B16b = (unsigned short*)alloc((size_t)G * F * 2);
  unsigned short* wreg = (unsigned short*)alloc((size_t)352256 * 2);
  float* rs = (float*)alloc((size_t)6 * 128 * 4);

  unsigned short* a1Wb[2]  = {wreg + 0,      wreg + 49152};
  unsigned short* linWb[2] = {wreg + 98304,  wreg + 147456};
  unsigned short* b0b = wreg + 196608;
  unsigned short* b1b = wreg + 212992;
  unsigned short* b2b = wreg + 229376;
  unsigned short* g0b = wreg + 262144;
  unsigned short* g3b = wreg + 278528;

  const dim3 blk256(256);
  const int GX = (N + 127) / 128;
  const int KBIG = 1 << 30;
  const int EB = (E + TILE - 1) / TILE;

  // ---- CSR build (bucket hist -> bucket scan -> bin -> reorder+rowbuild) ----
  hipMemsetAsync(bh0, 0, (size_t)NBK * 4, stream);
  hipMemsetAsync(bh1, 0, (size_t)NBK * 4, stream);
  BHArgs bha;
  bha.s0 = s0; bha.s1 = s1; bha.bh0 = bh0; bha.bh1 = bh1; bha.E = E;
  bhist_kernel<<<EB, blk256, 0, stream>>>(bha);
  BScanArgs bsa;
  bsa.bh[0] = bh0; bsa.bh[1] = bh1;
  bsa.bbase[0] = bbase0; bsa.bbase[1] = bbase1;
  bsa.bcur[0] = bcur0; bsa.bcur[1] = bcur1;
  bscan_kernel<<<1, 128, 0, stream>>>(bsa);
  BinArgs bna;
  bna.s0 = s0; bna.s1 = s1; bna.ew = ew;
  bna.bcur0 = bcur0; bna.bcur1 = bcur1;
  bna.bin0 = bin0; bna.bin1 = bin1;
  bna.E = E;
  bin_kernel<<<EB, blk256, 0, stream>>>(bna);
  RArgs ra;
  ra.bbase[0] = bbase0; ra.bbase[1] = bbase1;
  ra.bin[0] = bin0; ra.bin[1] = bin1;
  ra.comb[0] = comb0; ra.comb[1] = comb1;
  ra.row[0] = row0; ra.row[1] = row1;
  ra.n = N;
  reorder_kernel<<<dim3(NBK, 2), blk256, 0, stream>>>(ra);

  // ---- weight conversion + rowsums + init ----
  CJobs jb;
  jb.s[0] = p_a1W[0];  jb.d[0] = a1Wb[0];  jb.n[0] = 49152;
  jb.s[1] = p_a1W[1];  jb.d[1] = a1Wb[1];  jb.n[1] = 49152;
  jb.s[2] = p_linW[0]; jb.d[2] = linWb[0]; jb.n[2] = 49152;
  jb.s[3] = p_linW[1]; jb.d[3] = linWb[1]; jb.n[3] = 49152;
  jb.s[4] = beta0W;    jb.d[4] = b0b;      jb.n[4] = 16384;
  jb.s[5] = beta1W;    jb.d[5] = b1b;      jb.n[5] = 16384;
  jb.s[6] = beta2W;    jb.d[6] = b2b;      jb.n[6] = 32768;
  jb.s[7] = g0W;       jb.d[7] = g0b;      jb.n[7] = 16384;
  jb.s[8] = g3W;       jb.d[8] = g3b;      jb.n[8] = 73728;
  convert_kernel<<<dim3(36, 9), blk256, 0, stream>>>(jb);
  rowsum_kernel<<<6, 128, 0, stream>>>(p_a1W[0], p_a1W[1], rs);
  init_kernel<<<3125, blk256, 0, stream>>>(x, X1[0], X2[0], N);

  // ---- T-loop (x-version rotation: read t%3, write (t+1)%3) ----
  for (int t = 0; t < T; ++t) {
    int rv = t % 3, wv = (t + 1) % 3;

    BArgs g1;
    g1.A1[0] = X1[rv]; g1.A2[0] = X1[rv]; g1.A1[1] = X2[rv]; g1.A2[1] = X2[rv];
    g1.ldA1 = 128; g1.ldA2 = 128; g1.K1 = KBIG;
    g1.W[0] = a1Wb[0] + t * 16384; g1.W[1] = a1Wb[1] + t * 16384;
    g1.bias[0] = p_a1b[0] + t * F; g1.bias[1] = p_a1b[1] + t * F;
    g1.a0p[0] = p_a0[0] + t;       g1.a0p[1] = p_a0[1] + t;
    g1.rowsum[0] = rs + t * 128;   g1.rowsum[1] = rs + (3 + t) * 128;
    g1.C[0] = TMP0; g1.C[1] = TMP1;
    g1.states = states; g1.N = N; g1.K = 128;
    bgemm<128, 1, true, true><<<dim3(GX, 2), blk256, 0, stream>>>(g1);

    BArgs g2;
    g2.A1[0] = TMP0; g2.A2[0] = TMP0; g2.A1[1] = TMP1; g2.A2[1] = TMP1;
    g2.ldA1 = 128; g2.ldA2 = 128; g2.K1 = KBIG;
    g2.W[0] = linWb[0] + t * 16384; g2.W[1] = linWb[1] + t * 16384;
    g2.bias[0] = p_linb[0] + t * F; g2.bias[1] = p_linb[1] + t * F;
    g2.a0p[0] = nullptr; g2.a0p[1] = nullptr;
    g2.rowsum[0] = nullptr; g2.rowsum[1] = nullptr;
    g2.C[0] = HH0; g2.C[1] = HH1;
    g2.states = nullptr; g2.N = N; g2.K = 128;
    bgemm<128, 0, true, false><<<dim3(GX, 2), blk256, 0, stream>>>(g2);

    GArgs ga;
    ga.rowstart[0] = row0; ga.rowstart[1] = row1;
    ga.comb[0] = comb0;    ga.comb[1] = comb1;
    ga.h[0] = HH0;         ga.h[1] = HH1;
    ga.xout[0] = X1[wv];   ga.xout[1] = X2[wv];
    ga.n = N;
    gather_kernel<<<(2 * N + 3) / 4, blk256, 0, stream>>>(ga);
  }

  // ---- x1s/x2s = sum of the 3 versions ----
  S3Args s3;
  s3.a[0] = (const unsigned int*)X1[0]; s3.b[0] = (const unsigned int*)X1[1];
  s3.c[0] = (const unsigned int*)X1[2]; s3.o[0] = (unsigned int*)TMP0;
  s3.a[1] = (const unsigned int*)X2[0]; s3.b[1] = (const unsigned int*)X2[1];
  s3.c[1] = (const unsigned int*)X2[2]; s3.o[1] = (unsigned int*)TMP1;
  s3.n = N * 64;
  sum3_kernel<<<dim3(2048, 2), blk256, 0, stream>>>(s3);

  // ---- beta stage: u = x1s@b0^T, v = x2s@b1^T (pair), then xc ----
  BArgs bu;
  bu.A1[0] = TMP0; bu.A2[0] = TMP0; bu.A1[1] = TMP1; bu.A2[1] = TMP1;
  bu.ldA1 = 128; bu.ldA2 = 128; bu.K1 = KBIG;
  bu.W[0] = b0b; bu.W[1] = b1b;
  bu.bias[0] = nullptr; bu.bias[1] = nullptr;
  bu.a0p[0] = nullptr; bu.a0p[1] = nullptr;
  bu.rowsum[0] = nullptr; bu.rowsum[1] = nullptr;
  bu.C[0] = HH0; bu.C[1] = HH1;
  bu.states = nullptr; bu.N = N; bu.K = 128;
  bgemm<128, 0, false, false><<<dim3(GX, 2), blk256, 0, stream>>>(bu);

  BArgs b2a;
  b2a.A1[0] = HH0; b2a.A2[0] = HH1; b2a.A1[1] = nullptr; b2a.A2[1] = nullptr;
  b2a.ldA1 = 128; b2a.ldA2 = 128; b2a.K1 = 128;
  b2a.W[0] = b2b; b2a.W[1] = nullptr;
  b2a.bias[0] = beta2b; b2a.bias[1] = nullptr;
  b2a.a0p[0] = nullptr; b2a.a0p[1] = nullptr;
  b2a.rowsum[0] = nullptr; b2a.rowsum[1] = nullptr;
  b2a.C[0] = TMP0; b2a.C[1] = nullptr;
  b2a.states = nullptr; b2a.N = N; b2a.K = 256;
  bgemm<128, 1, true, false><<<dim3(GX, 1), blk256, 0, stream>>>(b2a);

  // ---- per-graph sums + 16-row GEMMs ----
  hipMemsetAsync(gsel, 0, (size_t)G * F * 4, stream);
  hipMemsetAsync(gsum, 0, (size_t)G * F * 4, stream);
  segsum_kernel<<<GX, blk256, 0, stream>>>(TMP0, batch, states, gsel, gsum, N);
  small16_kernel<<<G, blk256, 0, stream>>>(gsel, gsum, g1W, g2W, A16b, B16b);

  // ---- gamma stage ----
  BArgs g0a;
  g0a.A1[0] = TMP0; g0a.A2[0] = TMP0; g0a.A1[1] = nullptr; g0a.A2[1] = nullptr;
  g0a.ldA1 = 128; g0a.ldA2 = 128; g0a.K1 = KBIG;
  g0a.W[0] = g0b; g0a.W[1] = nullptr;
  g0a.bias[0] = nullptr; g0a.bias[1] = nullptr;
  g0a.a0p[0] = nullptr; g0a.a0p[1] = nullptr;
  g0a.rowsum[0] = nullptr; g0a.rowsum[1] = nullptr;
  g0a.C[0] = TMP1; g0a.C[1] = nullptr;
  g0a.states = nullptr; g0a.N = N; g0a.K = 128;
  bgemm<128, 0, false, false><<<dim3(GX, 1), blk256, 0, stream>>>(g0a);

  g3_kernel<<<GX, blk256, 0, stream>>>(TMP1, A16b, B16b, batch, g3b, g4W, g4b, out, N);
}